// Round 5
// baseline (741.820 us; speedup 1.0000x reference)
//
#include <hip/hip_runtime.h>
#include <hip/hip_bf16.h>
#include <math.h>

// ---------------- problem constants ----------------
#define B_    2
#define S_    2048
#define D_    1024
#define DI    2048      // D_INNER
#define NH    32        // NHEADS (mamba)
#define HD    64        // HEADDIM
#define DS    128       // D_STATE
#define CH    64        // CHUNK
#define NC    32        // S_/CH
#define DP    4384      // D_PROJ
#define HATT  16        // attention heads
#define KVH   4         // kv heads
#define RD    16        // rope dims
#define MLP   3072
#define ROWS  (B_*S_)   // 4096

typedef __bf16 bf16;
typedef __bf16 bf16x8 __attribute__((ext_vector_type(8)));
typedef __bf16 bf16x4 __attribute__((ext_vector_type(4)));
typedef float  f32x4  __attribute__((ext_vector_type(4)));

__device__ __forceinline__ void async_copy16(const void* g, void* l) {
  __builtin_amdgcn_global_load_lds(
      (const __attribute__((address_space(1))) unsigned int*)g,
      (__attribute__((address_space(3))) unsigned int*)l, 16, 0, 0);
}

// ---------------- reductions ----------------
__device__ __forceinline__ float waveReduceSum(float v) {
#pragma unroll
  for (int off = 32; off > 0; off >>= 1) v += __shfl_down(v, off, 64);
  return v;
}

template<int NW>
__device__ __forceinline__ float blockReduceSum(float v, float* sh) {
  v = waveReduceSum(v);
  int lane = threadIdx.x & 63, wid = threadIdx.x >> 6;
  if (lane == 0) sh[wid] = v;
  __syncthreads();
  float s = 0.f;
#pragma unroll
  for (int i = 0; i < NW; i++) s += sh[i];
  __syncthreads();
  return s;
}

// ---------------- merged weight cast f32 -> bf16 ----------------
struct CastSeg { const float* src; bf16* dst; int nval; int ntot; int blk0; };
struct CastArgs { CastSeg seg[8]; };

__global__ __launch_bounds__(256) void castw_all(CastArgs a) {
  int blk = blockIdx.x;
  int si = 0;
#pragma unroll
  for (int i = 1; i < 8; i++) if (blk >= a.seg[i].blk0) si = i;
  CastSeg s = a.seg[si];
  int i = ((blk - s.blk0) * 256 + threadIdx.x) * 4;
  if (i >= s.ntot) return;
  float4 v = {0.f, 0.f, 0.f, 0.f};
  if (i < s.nval) v = *(const float4*)(s.src + i);
  bf16x4 o;
  o[0] = (bf16)v.x; o[1] = (bf16)v.y; o[2] = (bf16)v.z; o[3] = (bf16)v.w;
  *(bf16x4*)(s.dst + i) = o;
}

// ---------------- rmsnorm (f32 in, bf16 out) ----------------
__global__ __launch_bounds__(256) void rmsnorm_k(const float* __restrict__ x,
                                                 const float* __restrict__ w,
                                                 bf16* __restrict__ y, int n) {
  __shared__ float sh[4];
  size_t row = blockIdx.x;
  const float* xr = x + row * n;
  bf16* yr = y + row * n;
  float ss = 0.f;
  for (int i = threadIdx.x; i < n; i += 256) { float v = xr[i]; ss += v * v; }
  ss = blockReduceSum<4>(ss, sh);
  float inv = rsqrtf(ss / n + 1e-5f);
  for (int i = threadIdx.x; i < n; i += 256) yr[i] = (bf16)(xr[i] * inv * w[i]);
}

// ---------------- generic bf16 MFMA GEMM: C = act(A @ W^T) ----------------
template<int ACT, typename OT>
__global__ __launch_bounds__(256) void gemm_mfma(const bf16* __restrict__ A,
                                                 const bf16* __restrict__ W,
                                                 const float* __restrict__ R,
                                                 OT* __restrict__ C,
                                                 int M, int N, int K) {
  __shared__ bf16 As[128 * 32];
  __shared__ bf16 Ws[128 * 32];
  int tid = threadIdx.x, lane = tid & 63, wave = tid >> 6;
  int bm = blockIdx.y * 128, bn = blockIdx.x * 128;
  const bf16* gA0 = A + (size_t)(bm + wave * 32 + (lane >> 2)) * K + (lane & 3) * 8;
  const bf16* gA1 = gA0 + (size_t)16 * K;
  const bf16* gW0 = W + (size_t)(bn + wave * 32 + (lane >> 2)) * K + (lane & 3) * 8;
  const bf16* gW1 = gW0 + (size_t)16 * K;
  bf16* lA0 = As + wave * 32 * 32;
  bf16* lA1 = lA0 + 16 * 32;
  bf16* lW0 = Ws + wave * 32 * 32;
  bf16* lW1 = lW0 + 16 * 32;
  int fr = lane & 15, fq = lane >> 4;
  int wm = wave >> 1, wn = wave & 1;
  const bf16* pA = As + (wm * 64 + fr) * 32 + fq * 8;
  const bf16* pW = Ws + (wn * 64 + fr) * 32 + fq * 8;
  f32x4 acc[4][4] = {};
  for (int k0 = 0; k0 < K; k0 += 32) {
    async_copy16(gA0, lA0);
    async_copy16(gA1, lA1);
    async_copy16(gW0, lW0);
    async_copy16(gW1, lW1);
    gA0 += 32; gA1 += 32; gW0 += 32; gW1 += 32;
    __syncthreads();
    bf16x8 af[4], bfr[4];
#pragma unroll
    for (int mi = 0; mi < 4; mi++) af[mi] = *(const bf16x8*)(pA + mi * 16 * 32);
#pragma unroll
    for (int ni = 0; ni < 4; ni++) bfr[ni] = *(const bf16x8*)(pW + ni * 16 * 32);
#pragma unroll
    for (int mi = 0; mi < 4; mi++)
#pragma unroll
      for (int ni = 0; ni < 4; ni++)
        acc[mi][ni] = __builtin_amdgcn_mfma_f32_16x16x32_bf16(af[mi], bfr[ni], acc[mi][ni], 0, 0, 0);
    __syncthreads();
  }
#pragma unroll
  for (int mi = 0; mi < 4; mi++) {
    int row = bm + wm * 64 + mi * 16 + fq * 4;
#pragma unroll
    for (int ni = 0; ni < 4; ni++) {
      int col = bn + wn * 64 + ni * 16 + fr;
      if (col < N) {
#pragma unroll
        for (int r = 0; r < 4; r++) {
          float v = acc[mi][ni][r];
          if (ACT == 1) v = v / (1.f + __expf(-v));
          if (R) v += R[(size_t)(row + r) * N + col];
          C[(size_t)(row + r) * N + col] = (OT)v;
        }
      }
    }
  }
}

// ---------------- split-K bf16 MFMA GEMM: P[ks] = A @ W^T (partial over K slice) ----------------
__global__ __launch_bounds__(256) void gemm_sk(const bf16* __restrict__ A,
                                               const bf16* __restrict__ W,
                                               float* __restrict__ P,
                                               int M, int N, int K, int kchunk) {
  __shared__ bf16 As[128 * 32];
  __shared__ bf16 Ws[128 * 32];
  int tid = threadIdx.x, lane = tid & 63, wave = tid >> 6;
  int bm = blockIdx.y * 128, bn = blockIdx.x * 128;
  int ks = blockIdx.z;
  int kbeg = ks * kchunk;
  const bf16* gA0 = A + (size_t)(bm + wave * 32 + (lane >> 2)) * K + kbeg + (lane & 3) * 8;
  const bf16* gA1 = gA0 + (size_t)16 * K;
  const bf16* gW0 = W + (size_t)(bn + wave * 32 + (lane >> 2)) * K + kbeg + (lane & 3) * 8;
  const bf16* gW1 = gW0 + (size_t)16 * K;
  bf16* lA0 = As + wave * 32 * 32;
  bf16* lA1 = lA0 + 16 * 32;
  bf16* lW0 = Ws + wave * 32 * 32;
  bf16* lW1 = lW0 + 16 * 32;
  int fr = lane & 15, fq = lane >> 4;
  int wm = wave >> 1, wn = wave & 1;
  const bf16* pA = As + (wm * 64 + fr) * 32 + fq * 8;
  const bf16* pW = Ws + (wn * 64 + fr) * 32 + fq * 8;
  f32x4 acc[4][4] = {};
  for (int k0 = 0; k0 < kchunk; k0 += 32) {
    async_copy16(gA0, lA0);
    async_copy16(gA1, lA1);
    async_copy16(gW0, lW0);
    async_copy16(gW1, lW1);
    gA0 += 32; gA1 += 32; gW0 += 32; gW1 += 32;
    __syncthreads();
    bf16x8 af[4], bfr[4];
#pragma unroll
    for (int mi = 0; mi < 4; mi++) af[mi] = *(const bf16x8*)(pA + mi * 16 * 32);
#pragma unroll
    for (int ni = 0; ni < 4; ni++) bfr[ni] = *(const bf16x8*)(pW + ni * 16 * 32);
#pragma unroll
    for (int mi = 0; mi < 4; mi++)
#pragma unroll
      for (int ni = 0; ni < 4; ni++)
        acc[mi][ni] = __builtin_amdgcn_mfma_f32_16x16x32_bf16(af[mi], bfr[ni], acc[mi][ni], 0, 0, 0);
    __syncthreads();
  }
  float* Pp = P + (size_t)ks * M * N;
#pragma unroll
  for (int mi = 0; mi < 4; mi++) {
    int row = bm + wm * 64 + mi * 16 + fq * 4;
#pragma unroll
    for (int ni = 0; ni < 4; ni++) {
      int col = bn + wn * 64 + ni * 16 + fr;
#pragma unroll
      for (int r = 0; r < 4; r++)
        Pp[(size_t)(row + r) * N + col] = acc[mi][ni][r];
    }
  }
}

// ---------------- reduce 2 partials + residual + layernorm -> x_out f32, h bf16 ----------------
__global__ __launch_bounds__(256) void reduce_ln2(const float* __restrict__ p0,
                                                  const float* __restrict__ p1,
                                                  const float* __restrict__ res,
                                                  const float* __restrict__ w,
                                                  const float* __restrict__ b,
                                                  float* __restrict__ xo,
                                                  bf16* __restrict__ ho) {
  __shared__ float buf[1024];
  __shared__ float sh[4];
  size_t o = (size_t)blockIdx.x * 1024;
  float s = 0.f, s2 = 0.f;
  for (int i = threadIdx.x; i < 1024; i += 256) {
    float v = p0[o + i] + p1[o + i] + res[o + i];
    buf[i] = v; s += v; s2 += v * v;
  }
  s  = blockReduceSum<4>(s,  sh);
  s2 = blockReduceSum<4>(s2, sh);
  float mean = s / 1024.f;
  float var  = s2 / 1024.f - mean * mean;
  float inv  = rsqrtf(var + 1e-5f);
  for (int i = threadIdx.x; i < 1024; i += 256) {
    float v = buf[i];
    xo[o + i] = v;
    ho[o + i] = (bf16)((v - mean) * inv * w[i] + b[i]);
  }
}

// ---------------- reduce 3 partials + residual -> out f32 ----------------
__global__ __launch_bounds__(256) void reduce_out3(const float* __restrict__ p0,
                                                   const float* __restrict__ p1,
                                                   const float* __restrict__ p2,
                                                   const float* __restrict__ res,
                                                   float* __restrict__ out) {
  int i = (blockIdx.x * 256 + threadIdx.x) * 4;
  f32x4 v = *(const f32x4*)(p0 + i);
  v += *(const f32x4*)(p1 + i);
  v += *(const f32x4*)(p2 + i);
  v += *(const f32x4*)(res + i);
  *(f32x4*)(out + i) = v;
}

// ---------------- reduce qkv partials + q/k rmsnorm + rope + gain -> bf16 ----------------
__global__ __launch_bounds__(256) void reduce_qkv(const float* __restrict__ P,
                                                  const float* __restrict__ q_gain,
                                                  bf16* __restrict__ q,
                                                  bf16* __restrict__ k,
                                                  bf16* __restrict__ v) {
  __shared__ float buf[1536];
  size_t row = blockIdx.x;
  size_t o = row * 1536;
  const float* p0 = P + o;
  const float* p1 = P + (size_t)ROWS * 1536 + o;
  int tid = threadIdx.x;
  for (int i = tid; i < 384; i += 256) {
    f32x4 a = *(const f32x4*)(p0 + i * 4);
    f32x4 c = *(const f32x4*)(p1 + i * 4);
    *(f32x4*)(buf + i * 4) = a + c;
  }
  __syncthreads();
  int lane = tid & 63, w = tid >> 6;
  int s = (int)(row & (S_ - 1));
  int ri = lane & 7;
  float rinv = __expf(-(float)ri * (0.125f * 9.210340371976184f)); // 10000^(-i/8)
  float ang = (float)s * rinv;
  float cs = cosf(ang), sn = sinf(ang);
#pragma unroll
  for (int j = 0; j < 6; j++) {
    int hh = w * 6 + j;
    float val = buf[hh * 64 + lane];
    if (hh < 20) {
      float ss = val * val;
#pragma unroll
      for (int off = 32; off > 0; off >>= 1) ss += __shfl_xor(ss, off, 64);
      val *= rsqrtf(ss / 64.f + 1.1920929e-7f);
      float other = __shfl_xor(val, 8, 64);
      float res = val;
      if (lane < RD) res = (lane < 8) ? (val * cs + other * sn) : (val * cs - other * sn);
      if (hh < 16) {
        res *= q_gain[hh];
        q[row * (HATT * HD) + hh * HD + lane] = (bf16)res;
      } else {
        k[row * (KVH * HD) + (hh - 16) * HD + lane] = (bf16)res;
      }
    } else {
      v[row * (KVH * HD) + (hh - 20) * HD + lane] = (bf16)val;
    }
  }
}

// ---------------- in_proj GEMM: writes Zt/Xt transposed + compact bcdt ----------------
__global__ __launch_bounds__(256) void gemm_inproj(const bf16* __restrict__ A,
                                                   const bf16* __restrict__ W,
                                                   bf16* __restrict__ zt,
                                                   bf16* __restrict__ xt,
                                                   bf16* __restrict__ bcdt) {
  const int K = 1024;
  __shared__ bf16 As[128 * 32];
  __shared__ bf16 Ws[128 * 32];
  int tid = threadIdx.x, lane = tid & 63, wave = tid >> 6;
  int bm = blockIdx.y * 128, bn = blockIdx.x * 128;
  const bf16* gA0 = A + (size_t)(bm + wave * 32 + (lane >> 2)) * K + (lane & 3) * 8;
  const bf16* gA1 = gA0 + (size_t)16 * K;
  const bf16* gW0 = W + (size_t)(bn + wave * 32 + (lane >> 2)) * K + (lane & 3) * 8;
  const bf16* gW1 = gW0 + (size_t)16 * K;
  bf16* lA0 = As + wave * 32 * 32;
  bf16* lA1 = lA0 + 16 * 32;
  bf16* lW0 = Ws + wave * 32 * 32;
  bf16* lW1 = lW0 + 16 * 32;
  int fr = lane & 15, fq = lane >> 4;
  int wm = wave >> 1, wn = wave & 1;
  const bf16* pA = As + (wm * 64 + fr) * 32 + fq * 8;
  const bf16* pW = Ws + (wn * 64 + fr) * 32 + fq * 8;
  f32x4 acc[4][4] = {};
  for (int k0 = 0; k0 < K; k0 += 32) {
    async_copy16(gA0, lA0);
    async_copy16(gA1, lA1);
    async_copy16(gW0, lW0);
    async_copy16(gW1, lW1);
    gA0 += 32; gA1 += 32; gW0 += 32; gW1 += 32;
    __syncthreads();
    bf16x8 af[4], bfr[4];
#pragma unroll
    for (int mi = 0; mi < 4; mi++) af[mi] = *(const bf16x8*)(pA + mi * 16 * 32);
#pragma unroll
    for (int ni = 0; ni < 4; ni++) bfr[ni] = *(const bf16x8*)(pW + ni * 16 * 32);
#pragma unroll
    for (int mi = 0; mi < 4; mi++)
#pragma unroll
      for (int ni = 0; ni < 4; ni++)
        acc[mi][ni] = __builtin_amdgcn_mfma_f32_16x16x32_bf16(af[mi], bfr[ni], acc[mi][ni], 0, 0, 0);
    __syncthreads();
  }
#pragma unroll
  for (int mi = 0; mi < 4; mi++) {
    int row0m = bm + wm * 64 + mi * 16 + fq * 4;
    int b = row0m >> 11, sg = row0m & 2047;
#pragma unroll
    for (int ni = 0; ni < 4; ni++) {
      int col = bn + wn * 64 + ni * 16 + fr;
      bf16x4 o;
#pragma unroll
      for (int r = 0; r < 4; r++) o[r] = (bf16)acc[mi][ni][r];
      if (col < 2048) {
        *(bf16x4*)(zt + ((size_t)(b * NH + (col >> 6)) * HD + (col & 63)) * S_ + sg) = o;
      } else if (col < 4096) {
        int xc = col - 2048;
        *(bf16x4*)(xt + ((size_t)(b * NH + (xc >> 6)) * HD + (xc & 63)) * S_ + sg) = o;
      } else if (col < 4384) {
#pragma unroll
        for (int r = 0; r < 4; r++)
          bcdt[(size_t)(row0m + r) * 288 + (col - 4096)] = o[r];
      }
    }
  }
}

// ---------------- generic 64x64 tiled transpose (bf16), out row stride 2048 ----------------
__global__ __launch_bounds__(256) void t64(const bf16* __restrict__ in, bf16* __restrict__ out,
                                           int istr, size_t io, size_t oo, int n_nt) {
  __shared__ bf16 T[64 * 72];
  int bid = blockIdx.x;
  int st = bid & 31;
  int nt = (bid >> 5) % n_nt;
  int outer = bid / (32 * n_nt);
  const bf16* ip = in + outer * io + (size_t)st * 64 * istr + nt * 64;
  int tid = threadIdx.x;
#pragma unroll
  for (int i = 0; i < 2; i++) {
    int cid = tid + i * 256; int s = cid >> 3, pc = (cid & 7) * 8;
    *(bf16x8*)(T + s * 72 + pc) = *(const bf16x8*)(ip + (size_t)s * istr + pc);
  }
  __syncthreads();
  bf16* op = out + outer * oo + (size_t)nt * 64 * 2048 + st * 64;
#pragma unroll
  for (int i = 0; i < 2; i++) {
    int cid = tid + i * 256; int p = cid >> 3, sc = (cid & 7) * 8;
    bf16x8 o;
#pragma unroll
    for (int j = 0; j < 8; j++) o[j] = T[(sc + j) * 72 + p];
    *(bf16x8*)(op + (size_t)p * 2048 + sc) = o;
  }
}

// ---------------- SSD prep: dt softplus, per-chunk cumsum, decay factors ----------------
__global__ __launch_bounds__(64) void ssd_prep(const bf16* __restrict__ bcdt,
                                               const float* __restrict__ dt_bias,
                                               const float* __restrict__ A_log,
                                               float* __restrict__ dt_c,
                                               float* __restrict__ ddc,
                                               float* __restrict__ ac_c,
                                               float* __restrict__ T_out) {
  int bid = blockIdx.x;
  int c = bid % NC, hh = (bid / NC) % NH, b = bid / (NC * NH);
  int l = threadIdx.x;
  size_t row = (size_t)b * S_ + c * 64 + l;
  float raw = (float)bcdt[row * 288 + 256 + hh] + dt_bias[hh];
  float dtv = (raw > 20.f) ? raw : log1pf(__expf(raw));
  float a = -__expf(A_log[hh]) * dtv;
  float ps = a;
#pragma unroll
  for (int off = 1; off < 64; off <<= 1) {
    float t = __shfl_up(ps, off, 64);
    if (l >= off) ps += t;
  }
  float a63 = __shfl(ps, 63, 64);
  size_t o = ((size_t)b * NH + hh) * S_ + c * 64 + l;
  dt_c[o] = dtv;
  ac_c[o] = ps;
  ddc[o] = __expf(a63 - ps) * dtv;
  if (l == 63) T_out[(b * NH + hh) * NC + c] = ps;
}

// ---------------- B/C rmsnorm (bf16 out) ----------------
__global__ __launch_bounds__(128) void bc_norm(const bf16* __restrict__ bcdt,
                                               const float* __restrict__ Bw,
                                               const float* __restrict__ Cw,
                                               bf16* __restrict__ Bn,
                                               bf16* __restrict__ Cn) {
  __shared__ float shb[2], shc[2];
  size_t row = blockIdx.x;
  int i = threadIdx.x;
  float bv = (float)bcdt[row * 288 + i];
  float cv = (float)bcdt[row * 288 + 128 + i];
  float sb = waveReduceSum(bv * bv);
  float sc = waveReduceSum(cv * cv);
  int lane = threadIdx.x & 63, wid = threadIdx.x >> 6;
  if (lane == 0) { shb[wid] = sb; shc[wid] = sc; }
  __syncthreads();
  float tb = shb[0] + shb[1];
  float tc = shc[0] + shc[1];
  Bn[row * DS + i] = (bf16)(bv * rsqrtf(tb / DS + 1e-5f) * Bw[i]);
  Cn[row * DS + i] = (bf16)(cv * rsqrtf(tc / DS + 1e-5f) * Cw[i]);
}

// ---------------- chunk states via MFMA ----------------
__global__ __launch_bounds__(256) void ssd_states(const bf16* __restrict__ Xt,
                                                  const bf16* __restrict__ Btr,
                                                  const float* __restrict__ ddc,
                                                  float* __restrict__ states) {
  __shared__ bf16 Xs[64 * 72];    // [p][s]
  __shared__ bf16 Bs[128 * 72];   // [n][s]
  int bid = blockIdx.x;           // (b*NC + c)*NH + h
  int h = bid % NH;
  int c = (bid / NH) % NC;
  int b = bid / (NH * NC);
  int tid = threadIdx.x, lane = tid & 63, w = tid >> 6;
  int fr = lane & 15, fq = lane >> 4;
  const size_t xbase = (size_t)(b * NH + h) * HD * S_ + c * 64;
  const size_t dbase = (size_t)(b * NH + h) * S_ + c * 64;
#pragma unroll
  for (int i = 0; i < 2; i++) {
    int cid = tid + i * 256; int p = cid >> 3, sc = (cid & 7) * 8;
    bf16x8 xv = *(const bf16x8*)(Xt + xbase + (size_t)p * S_ + sc);
    f32x4 d0 = *(const f32x4*)(ddc + dbase + sc);
    f32x4 d1 = *(const f32x4*)(ddc + dbase + sc + 4);
    bf16x8 o;
#pragma unroll
    for (int j = 0; j < 4; j++) { o[j] = (bf16)((float)xv[j] * d0[j]); o[4 + j] = (bf16)((float)xv[4 + j] * d1[j]); }
    *(bf16x8*)(Xs + p * 72 + sc) = o;
  }
  const size_t bbase = (size_t)b * 128 * S_ + c * 64;
#pragma unroll
  for (int i = 0; i < 4; i++) {
    int cid = tid + i * 256; int n = cid >> 3, sc = (cid & 7) * 8;
    *(bf16x8*)(Bs + n * 72 + sc) = *(const bf16x8*)(Btr + bbase + (size_t)n * S_ + sc);
  }
  __syncthreads();
  f32x4 acc[4][2] = {};
#pragma unroll
  for (int ks = 0; ks < 2; ks++) {
    bf16x8 a[4], bb[2];
#pragma unroll
    for (int pt = 0; pt < 4; pt++) a[pt] = *(const bf16x8*)(Xs + (pt * 16 + fr) * 72 + ks * 32 + fq * 8);
#pragma unroll
    for (int n2 = 0; n2 < 2; n2++) bb[n2] = *(const bf16x8*)(Bs + ((2 * w + n2) * 16 + fr) * 72 + ks * 32 + fq * 8);
#pragma unroll
    for (int pt = 0; pt < 4; pt++)
#pragma unroll
      for (int n2 = 0; n2 < 2; n2++)
        acc[pt][n2] = __builtin_amdgcn_mfma_f32_16x16x32_bf16(a[pt], bb[n2], acc[pt][n2], 0, 0, 0);
  }
  float* outp = states + (size_t)bid * 8192;
#pragma unroll
  for (int pt = 0; pt < 4; pt++)
#pragma unroll
    for (int n2 = 0; n2 < 2; n2++) {
      int n = (2 * w + n2) * 16 + fr;
#pragma unroll
      for (int r = 0; r < 4; r++)
        outp[(size_t)(pt * 16 + fq * 4 + r) * 128 + n] = acc[pt][n2][r];
    }
}

// ---------------- inter-chunk scan (in place) ----------------
__global__ __launch_bounds__(256) void ssd_scan(float* __restrict__ states,
                                                const float* __restrict__ T) {
  __shared__ float eT[NC];
  int part = blockIdx.x & 7;
  int bh = blockIdx.x >> 3;
  int b = bh / NH, h = bh % NH;
  if (threadIdx.x < NC) eT[threadIdx.x] = __expf(T[(size_t)(b * NH + h) * NC + threadIdx.x]);
  __syncthreads();
  const size_t cstride = (size_t)NH * HD * DS;
  size_t base = ((size_t)b * NC * NH + h) * (HD * DS);
#pragma unroll
  for (int j = 0; j < 4; j++) {
    int e = part * 1024 + threadIdx.x + j * 256;
    float carry = 0.f;
    size_t idx = base + e;
    for (int c = 0; c < NC; c++) {
      float sv = states[idx];
      states[idx] = carry;
      carry = sv + eT[c] * carry;
      idx += cstride;
    }
  }
}

// ---------------- fused SSD output: Ydiag + Yoff + D-skip + gate (all MFMA) ----------------
__global__ __launch_bounds__(256) void ssd_out(const bf16* __restrict__ Cn,
                                               const bf16* __restrict__ Bn,
                                               const bf16* __restrict__ Xt,
                                               const bf16* __restrict__ Zt,
                                               const float* __restrict__ dt_c,
                                               const float* __restrict__ ac_c,
                                               const float* __restrict__ states,
                                               const float* __restrict__ Dp,
                                               bf16* __restrict__ ybf) {
  __shared__ bf16 Cs[64 * 136];
  __shared__ bf16 BNs[64 * 136];
  __shared__ bf16 Xs[64 * 72];
  __shared__ bf16 G[64 * 72];
  __shared__ float acs[64];
  int bid = blockIdx.x;
  int h = bid % NH;
  int c = (bid / NH) % NC;
  int b = bid / (NH * NC);
  int tid = threadIdx.x, lane = tid & 63, w = tid >> 6;
  int fr = lane & 15, fq = lane >> 4;
  size_t row0 = (size_t)b * S_ + c * 64;
  const size_t abase = (size_t)(b * NH + h) * S_ + c * 64;
  if (tid < 64) acs[tid] = ac_c[abase + tid];
#pragma unroll
  for (int i = 0; i < 4; i++) {
    int cid = tid + i * 256; int l = cid >> 4, nc = (cid & 15) * 8;
    float e = __expf(ac_c[abase + l]);
    bf16x8 cv = *(const bf16x8*)(Cn + (row0 + l) * DS + nc);
    bf16x8 o;
#pragma unroll
    for (int j = 0; j < 8; j++) o[j] = (bf16)((float)cv[j] * e);
    *(bf16x8*)(Cs + l * 136 + nc) = o;
    *(bf16x8*)(BNs + l * 136 + nc) = *(const bf16x8*)(Bn + (row0 + l) * DS + nc);
  }
  const size_t xbase = (size_t)(b * NH + h) * HD * S_ + c * 64;
#pragma unroll
  for (int i = 0; i < 2; i++) {
    int cid = tid + i * 256; int p = cid >> 3, sc = (cid & 7) * 8;
    bf16x8 xv = *(const bf16x8*)(Xt + xbase + (size_t)p * S_ + sc);
    f32x4 d0 = *(const f32x4*)(dt_c + abase + sc);
    f32x4 d1 = *(const f32x4*)(dt_c + abase + sc + 4);
    bf16x8 o;
#pragma unroll
    for (int j = 0; j < 4; j++) { o[j] = (bf16)((float)xv[j] * d0[j]); o[4 + j] = (bf16)((float)xv[4 + j] * d1[j]); }
    *(bf16x8*)(Xs + p * 72 + sc) = o;
  }
  __syncthreads();
  bf16x8 ca[4];
#pragma unroll
  for (int ks = 0; ks < 4; ks++) ca[ks] = *(const bf16x8*)(Cs + (w * 16 + fr) * 136 + ks * 32 + fq * 8);
  f32x4 cb[4] = {};
  for (int st = 0; st <= w; st++)
#pragma unroll
    for (int ks = 0; ks < 4; ks++)
      cb[st] = __builtin_amdgcn_mfma_f32_16x16x32_bf16(ca[ks],
                 *(const bf16x8*)(BNs + (st * 16 + fr) * 136 + ks * 32 + fq * 8), cb[st], 0, 0, 0);
#pragma unroll
  for (int st = 0; st < 4; st++) {
    float es = (st <= w) ? __expf(-acs[st * 16 + fr]) : 0.f;
#pragma unroll
    for (int r = 0; r < 4; r++) {
      int lloc = fq * 4 + r;
      float g = 0.f;
      if (st < w) g = cb[st][r] * es;
      else if (st == w) g = (lloc >= fr) ? cb[st][r] * es : 0.f;
      G[(w * 16 + lloc) * 72 + st * 16 + fr] = (bf16)g;
    }
  }
  f32x4 acc[4] = {};
  {
    bf16x8 ga0 = *(const bf16x8*)(G + (w * 16 + fr) * 72 + fq * 8);
    bf16x8 ga1 = *(const bf16x8*)(G + (w * 16 + fr) * 72 + 32 + fq * 8);
#pragma unroll
    for (int pt = 0; pt < 4; pt++) {
      acc[pt] = __builtin_amdgcn_mfma_f32_16x16x32_bf16(ga0,
                  *(const bf16x8*)(Xs + (pt * 16 + fr) * 72 + fq * 8), acc[pt], 0, 0, 0);
      acc[pt] = __builtin_amdgcn_mfma_f32_16x16x32_bf16(ga1,
                  *(const bf16x8*)(Xs + (pt * 16 + fr) * 72 + 32 + fq * 8), acc[pt], 0, 0, 0);
    }
  }
  __syncthreads();
  const float* stp = states + (size_t)bid * 8192;
#pragma unroll
  for (int i = 0; i < 4; i++) {
    int cid = tid + i * 256; int p = cid >> 4, nc = (cid & 15) * 8;
    f32x4 s0 = *(const f32x4*)(stp + (size_t)p * 128 + nc);
    f32x4 s1 = *(const f32x4*)(stp + (size_t)p * 128 + nc + 4);
    bf16x8 o;
#pragma unroll
    for (int j = 0; j < 4; j++) { o[j] = (bf16)s0[j]; o[4 + j] = (bf16)s1[j]; }
    *(bf16x8*)(BNs + p * 136 + nc) = o;
  }
  __syncthreads();
#pragma unroll
  for (int pt = 0; pt < 4; pt++)
#pragma unroll
    for (int ks = 0; ks < 4; ks++)
      acc[pt] = __builtin_amdgcn_mfma_f32_16x16x32_bf16(ca[ks],
                  *(const bf16x8*)(BNs + (pt * 16 + fr) * 136 + ks * 32 + fq * 8), acc[pt], 0, 0, 0);
  float dph = Dp[h];
#pragma unroll
  for (int pt = 0; pt < 4; pt++) {
    int p = pt * 16 + fr;
    size_t tb = (xbase + (size_t)p * S_) + w * 16 + fq * 4;
    bf16x4 xs4 = *(const bf16x4*)(Xt + tb);
    bf16x4 z4  = *(const bf16x4*)(Zt + tb);
#pragma unroll
    for (int r = 0; r < 4; r++) {
      int l = w * 16 + fq * 4 + r;
      float yv = acc[pt][r] + (float)xs4[r] * dph;
      float z = (float)z4[r];
      yv *= z / (1.f + __expf(-z));
      ybf[((row0 + l) * NH + h) * HD + p] = (bf16)yv;
    }
  }
}

// ---------------- barrier-free MFMA flash attention, fixed-max softmax ----------------
// S^T = K·Q^T and Y^T = V^T·P^T; all MFMA fragments loaded directly from global
// (16B contiguous per lane). Only P round-trips through wave-private LDS.
// |score| <= gain*8*8/8 = 42 hard bound -> fixed max in exp2 space (M2=62).
#define PSTR 80
__global__ __launch_bounds__(256) void attn_mfma(const bf16* __restrict__ q,
                                                 const bf16* __restrict__ k,
                                                 const bf16* __restrict__ vtr,
                                                 bf16* __restrict__ o) {
  __shared__ bf16 Pl[4 * 16 * PSTR];
  int qt = (gridDim.x - 1) - blockIdx.x;   // long rows first
  int h = blockIdx.y, b = blockIdx.z;
  int kvh = h >> 2;
  int tid = threadIdx.x, lane = tid & 63, w = tid >> 6;
  int fr = lane & 15, fq = lane >> 4;
  const float SC = 0.18033688011112042f;   // 0.125 * log2(e)
  const float M2 = 62.0f;
  const bf16* qp = q + (size_t)(b * S_ + qt * 64 + w * 16 + fr) * (HATT * HD) + h * HD + fq * 8;
  bf16x8 bq0 = *(const bf16x8*)(qp);
  bf16x8 bq1 = *(const bf16x8*)(qp + 32);
  const bf16* kbase = k + (size_t)(b * S_) * (KVH * HD) + kvh * HD + fq * 8;
  const bf16* vbase = vtr + ((size_t)(b * KVH + kvh) * HD) * S_ + fq * 8;
  float lsum = 0.f;
  f32x4 yacc[4] = {};
  bf16* Plw = Pl + w * 16 * PSTR;
  for (int kt = 0; kt <= qt; kt++) {
    bool diag = (kt == qt);
    if (!diag) {
      // ---- full tile: no masking ----
#pragma unroll
      for (int mi = 0; mi < 4; mi++) {
        const bf16* kr = kbase + (size_t)(kt * 64 + mi * 16 + fr) * (KVH * HD);
        bf16x8 ak0 = *(const bf16x8*)(kr);
        bf16x8 ak1 = *(const bf16x8*)(kr + 32);
        f32x4 s = {};
        s = __builtin_amdgcn_mfma_f32_16x16x32_bf16(ak0, bq0, s, 0, 0, 0);
        s = __builtin_amdgcn_mfma_f32_16x16x32_bf16(ak1, bq1, s, 0, 0, 0);
        bf16x4 pk;
#pragma unroll
        for (int r = 0; r < 4; r++) {
          float p = __builtin_amdgcn_exp2f(s[r] * SC - M2);
          lsum += p;
          pk[r] = (bf16)p;
        }
        *(bf16x4*)(Plw + fr * PSTR + mi * 16 + fq * 4) = pk;
      }
    } else {
      // ---- diagonal tile: mask, skip fully-masked sub-tiles ----
#pragma unroll
      for (int mi = 0; mi < 4; mi++) {
        bf16x4 pk = {};
        if (mi <= w) {
          const bf16* kr = kbase + (size_t)(kt * 64 + mi * 16 + fr) * (KVH * HD);
          bf16x8 ak0 = *(const bf16x8*)(kr);
          bf16x8 ak1 = *(const bf16x8*)(kr + 32);
          f32x4 s = {};
          s = __builtin_amdgcn_mfma_f32_16x16x32_bf16(ak0, bq0, s, 0, 0, 0);
          s = __builtin_amdgcn_mfma_f32_16x16x32_bf16(ak1, bq1, s, 0, 0, 0);
#pragma unroll
          for (int r = 0; r < 4; r++) {
            bool ok = (mi < w) || (fq * 4 + r <= fr);
            float p = ok ? __builtin_amdgcn_exp2f(s[r] * SC - M2) : 0.f;
            lsum += p;
            pk[r] = (bf16)p;
          }
        }
        *(bf16x4*)(Plw + fr * PSTR + mi * 16 + fq * 4) = pk;
      }
    }
    // ---- PV: Y^T += V^T · P^T ----
    bf16x8 bp0 = *(const bf16x8*)(Plw + fr * PSTR + fq * 8);
    bool hi = !diag || (w >= 2);
    bf16x8 bp1;
    if (hi) bp1 = *(const bf16x8*)(Plw + fr * PSTR + 32 + fq * 8);
#pragma unroll
    for (int pi = 0; pi < 4; pi++) {
      const bf16* vr = vbase + (size_t)(pi * 16 + fr) * S_ + kt * 64;
      bf16x8 av0 = *(const bf16x8*)(vr);
      yacc[pi] = __builtin_amdgcn_mfma_f32_16x16x32_bf16(av0, bp0, yacc[pi], 0, 0, 0);
      if (hi) {
        bf16x8 av1 = *(const bf16x8*)(vr + 32);
        yacc[pi] = __builtin_amdgcn_mfma_f32_16x16x32_bf16(av1, bp1, yacc[pi], 0, 0, 0);
      }
    }
  }
  lsum += __shfl_xor(lsum, 16, 64);
  lsum += __shfl_xor(lsum, 32, 64);
  float inv = 1.f / lsum;
  bf16* op = o + (size_t)(b * S_ + qt * 64 + w * 16 + fr) * (HATT * HD) + h * HD + fq * 4;
#pragma unroll
  for (int pi = 0; pi < 4; pi++) {
    bf16x4 ov;
#pragma unroll
    for (int r = 0; r < 4; r++) ov[r] = (bf16)(yacc[pi][r] * inv);
    *(bf16x4*)(op + pi * 16) = ov;
  }
}

// ---------------- workspace layout (byte offsets) ----------------
constexpr size_t OFF_WIN  = 0;                   // bf16 4480x1024
constexpr size_t OFF_WOUT = 9175040;             // bf16 1024x2048
constexpr size_t OFF_WQKV = 13369344;            // bf16 1536x1024 (q|k|v rows)
constexpr size_t OFF_WCP  = 16515072;            // bf16 1024x1024
constexpr size_t OFF_WFC  = 18612224;            // bf16 3072x1024
constexpr size_t OFF_WPR  = 24903680;            // bf16 1024x3072
constexpr size_t OFF_HBF  = 31195136;            // bf16 4096x1024
constexpr size_t OFF_BCDT = 39583744;            // bf16 4096x288
constexpr size_t OFF_XT   = 41943040;            // bf16 [b][h][p][sg]
constexpr size_t OFF_ZT   = 58720256;            // bf16 [b][h][p][sg]
constexpr size_t OFF_DTC  = 75497472;            // f32 [b][h][sg]
constexpr size_t OFF_DDC  = 76546048;            // f32
constexpr size_t OFF_ACC  = 77594624;            // f32
constexpr size_t OFF_T    = 78643200;            // f32 2048
constexpr size_t OFF_BN   = 78651392;            // bf16 4096x128
constexpr size_t OFF_CN   = 79699968;            // bf16 4096x128
constexpr size_t OFF_BTR  = 80748544;            // bf16 [b][n][sg]
constexpr size_t OFF_ST   = 81797120;            // f32 2048x64x128 (67.1 MB)
constexpr size_t OFF_YBF  = 148905984;           // bf16 4096x2048
constexpr size_t OFF_X1   = 165683200;           // f32 4096x1024 (end 182,460,416)
// aliases (st region dead after ssd_out; Xt/Zt dead after ssd_out; ybf dead after out_proj)
constexpr size_t OFF_P    = OFF_ST;              // f32 split-K partials (up to 50.3 MB)
constexpr size_t OFF_QB   = OFF_ST + 50331648;   // bf16 4096x1024
constexpr size_t OFF_KB   = OFF_ST + 58720256;   // bf16 4096x256
constexpr size_t OFF_VB   = OFF_ST + 60817408;   // bf16 4096x256
constexpr size_t OFF_VTR  = OFF_ST + 62914560;   // bf16 [b][kvh][p][sg] (end 146,821,120)
constexpr size_t OFF_Y2   = OFF_XT;              // bf16 4096x1024
constexpr size_t OFF_X2   = 50331648;            // f32 4096x1024 (in dead Xt/Zt space)
constexpr size_t OFF_MLP  = 132128768;           // bf16 4096x3072 (over dead regions)

extern "C" void kernel_launch(void* const* d_in, const int* in_sizes, int n_in,
                              void* d_out, int out_size, void* d_ws, size_t ws_size,
                              hipStream_t stream) {
  (void)in_sizes; (void)n_in; (void)out_size; (void)ws_size;
  const float* x        = (const float*)d_in[0];
  const float* mnorm_w  = (const float*)d_in[1];
  const float* in_w     = (const float*)d_in[2];
  const float* out_w    = (const float*)d_in[3];
  const float* Dp       = (const float*)d_in[4];
  const float* dt_bias  = (const float*)d_in[5];
  const float* A_log    = (const float*)d_in[6];
  const float* Bn_w     = (const float*)d_in[7];
  const float* Cn_w     = (const float*)d_in[8];
  const float* ln1_w    = (const float*)d_in[9];
  const float* ln1_b    = (const float*)d_in[10];
  const float* cq_w     = (const float*)d_in[11];
  const float* ck_w     = (const float*)d_in[12];
  const float* cv_w     = (const float*)d_in[13];
  const float* cproj_w  = (const float*)d_in[14];
  const float* q_gain   = (const float*)d_in[15];
  const float* ln2_w    = (const float*)d_in[16];
  const float* ln2_b    = (const float*)d_in[17];
  const float* fc_w     = (const float*)d_in[18];
  const float* proj_w   = (const float*)d_in[19];
  float* out = (float*)d_out;
  char* W8 = (char*)d_ws;

  bf16* w_in   = (bf16*)(W8 + OFF_WIN);
  bf16* w_out  = (bf16*)(W8 + OFF_WOUT);
  bf16* w_qkv  = (bf16*)(W8 + OFF_WQKV);
  bf16* w_cp   = (bf16*)(W8 + OFF_WCP);
  bf16* w_fc   = (bf16*)(W8 + OFF_WFC);
  bf16* w_pr   = (bf16*)(W8 + OFF_WPR);
  bf16* h_bf   = (bf16*)(W8 + OFF_HBF);
  bf16* bcdt   = (bf16*)(W8 + OFF_BCDT);
  bf16* Xt     = (bf16*)(W8 + OFF_XT);
  bf16* Zt     = (bf16*)(W8 + OFF_ZT);
  float* dt_c  = (float*)(W8 + OFF_DTC);
  float* ddc   = (float*)(W8 + OFF_DDC);
  float* ac_c  = (float*)(W8 + OFF_ACC);
  float* Tb    = (float*)(W8 + OFF_T);
  bf16* Bn     = (bf16*)(W8 + OFF_BN);
  bf16* Cn     = (bf16*)(W8 + OFF_CN);
  bf16* Btr    = (bf16*)(W8 + OFF_BTR);
  float* st    = (float*)(W8 + OFF_ST);
  bf16* ybf    = (bf16*)(W8 + OFF_YBF);
  float* x1    = (float*)(W8 + OFF_X1);
  float* Pbuf  = (float*)(W8 + OFF_P);
  bf16* qbf    = (bf16*)(W8 + OFF_QB);
  bf16* kbf    = (bf16*)(W8 + OFF_KB);
  bf16* vbf    = (bf16*)(W8 + OFF_VB);
  bf16* vtr    = (bf16*)(W8 + OFF_VTR);
  bf16* y2     = (bf16*)(W8 + OFF_Y2);
  float* x2    = (float*)(W8 + OFF_X2);
  bf16* mlp    = (bf16*)(W8 + OFF_MLP);

  // ---- weight casts (single launch; q/k/v cast into adjacent rows of w_qkv) ----
  CastArgs ca;
  ca.seg[0] = { in_w,    w_in,            4489216, 4587520, 0     };
  ca.seg[1] = { out_w,   w_out,           2097152, 2097152, 4480  };
  ca.seg[2] = { cq_w,    w_qkv,           1048576, 1048576, 6528  };
  ca.seg[3] = { ck_w,    w_qkv + 1048576,  262144,  262144, 7552  };
  ca.seg[4] = { cv_w,    w_qkv + 1310720,  262144,  262144, 7808  };
  ca.seg[5] = { cproj_w, w_cp,            1048576, 1048576, 8064  };
  ca.seg[6] = { fc_w,    w_fc,            3145728, 3145728, 9088  };
  ca.seg[7] = { proj_w,  w_pr,            3145728, 3145728, 12160 };
  castw_all<<<15232, 256, 0, stream>>>(ca);

  const size_t PS = (size_t)ROWS * 1024;   // partial stride for N=1024 GEMMs

  // ---- mamba block ----
  rmsnorm_k<<<ROWS, 256, 0, stream>>>(x, mnorm_w, h_bf, D_);
  gemm_inproj<<<dim3(35, 32), 256, 0, stream>>>(h_bf, w_in, Zt, Xt, bcdt);
  ssd_prep<<<B_ * NH * NC, 64, 0, stream>>>(bcdt, dt_bias, A_log, dt_c, ddc, ac_c, Tb);
  bc_norm<<<ROWS, 128, 0, stream>>>(bcdt, Bn_w, Cn_w, Bn, Cn);
  t64<<<2 * 2 * 32, 256, 0, stream>>>(Bn, Btr, 128, (size_t)2048 * 128, (size_t)128 * 2048, 2);
  ssd_states<<<B_ * NC * NH, 256, 0, stream>>>(Xt, Btr, ddc, st);
  ssd_scan<<<B_ * NH * 8, 256, 0, stream>>>(st, Tb);
  ssd_out<<<B_ * NC * NH, 256, 0, stream>>>(Cn, Bn, Xt, Zt, dt_c, ac_c, st, Dp, ybf);
  // out_proj: split-K=2 then fused reduce+residual+LN1
  gemm_sk<<<dim3(8, 32, 2), 256, 0, stream>>>(ybf, w_out, Pbuf, ROWS, D_, DI, 1024);
  reduce_ln2<<<ROWS, 256, 0, stream>>>(Pbuf, Pbuf + PS, x, ln1_w, ln1_b, x1, h_bf);

  // ---- attention block ----
  gemm_sk<<<dim3(12, 32, 2), 256, 0, stream>>>(h_bf, w_qkv, Pbuf, ROWS, 1536, D_, 512);
  reduce_qkv<<<ROWS, 256, 0, stream>>>(Pbuf, q_gain, qbf, kbf, vbf);
  t64<<<2 * 4 * 32, 256, 0, stream>>>(vbf, vtr, 256, (size_t)2048 * 256, (size_t)256 * 2048, 4);
  attn_mfma<<<dim3(S_ / 64, HATT, B_), 256, 0, stream>>>(qbf, kbf, vtr, y2);
  gemm_sk<<<dim3(8, 32, 2), 256, 0, stream>>>(y2, w_cp, Pbuf, ROWS, D_, D_, 512);
  reduce_ln2<<<ROWS, 256, 0, stream>>>(Pbuf, Pbuf + PS, x1, ln2_w, ln2_b, x2, h_bf);

  // ---- MLP ----
  gemm_mfma<1, bf16><<<dim3(24, 32), 256, 0, stream>>>(h_bf, w_fc, nullptr, mlp, ROWS, MLP, D_);
  gemm_sk<<<dim3(8, 32, 3), 256, 0, stream>>>(mlp, w_pr, Pbuf, ROWS, D_, MLP, 1024);
  reduce_out3<<<ROWS, 256, 0, stream>>>(Pbuf, Pbuf + PS, Pbuf + 2 * PS, x2, out);
}

// Round 6
// 609.597 us; speedup vs baseline: 1.2169x; 1.2169x over previous
//
#include <hip/hip_runtime.h>
#include <hip/hip_bf16.h>
#include <math.h>

// ---------------- problem constants ----------------
#define B_    2
#define S_    2048
#define D_    1024
#define DI    2048      // D_INNER
#define NH    32        // NHEADS (mamba)
#define HD    64        // HEADDIM
#define DS    128       // D_STATE
#define CH    64        // CHUNK
#define NC    32        // S_/CH
#define DP    4384      // D_PROJ
#define HATT  16        // attention heads
#define KVH   4         // kv heads
#define RD    16        // rope dims
#define MLP   3072
#define ROWS  (B_*S_)   // 4096

typedef __bf16 bf16;
typedef __bf16 bf16x8 __attribute__((ext_vector_type(8)));
typedef __bf16 bf16x4 __attribute__((ext_vector_type(4)));
typedef float  f32x4  __attribute__((ext_vector_type(4)));

__device__ __forceinline__ void async_copy16(const void* g, void* l) {
  __builtin_amdgcn_global_load_lds(
      (const __attribute__((address_space(1))) unsigned int*)g,
      (__attribute__((address_space(3))) unsigned int*)l, 16, 0, 0);
}

// ---------------- reductions ----------------
__device__ __forceinline__ float waveReduceSum(float v) {
#pragma unroll
  for (int off = 32; off > 0; off >>= 1) v += __shfl_down(v, off, 64);
  return v;
}

template<int NW>
__device__ __forceinline__ float blockReduceSum(float v, float* sh) {
  v = waveReduceSum(v);
  int lane = threadIdx.x & 63, wid = threadIdx.x >> 6;
  if (lane == 0) sh[wid] = v;
  __syncthreads();
  float s = 0.f;
#pragma unroll
  for (int i = 0; i < NW; i++) s += sh[i];
  __syncthreads();
  return s;
}

// ---------------- merged weight cast f32 -> bf16 ----------------
struct CastSeg { const float* src; bf16* dst; int nval; int ntot; int blk0; };
struct CastArgs { CastSeg seg[8]; };

__global__ __launch_bounds__(256) void castw_all(CastArgs a) {
  int blk = blockIdx.x;
  int si = 0;
#pragma unroll
  for (int i = 1; i < 8; i++) if (blk >= a.seg[i].blk0) si = i;
  CastSeg s = a.seg[si];
  int i = ((blk - s.blk0) * 256 + threadIdx.x) * 4;
  if (i >= s.ntot) return;
  float4 v = {0.f, 0.f, 0.f, 0.f};
  if (i < s.nval) v = *(const float4*)(s.src + i);
  bf16x4 o;
  o[0] = (bf16)v.x; o[1] = (bf16)v.y; o[2] = (bf16)v.z; o[3] = (bf16)v.w;
  *(bf16x4*)(s.dst + i) = o;
}

// ---------------- rmsnorm (f32 in, bf16 out) ----------------
__global__ __launch_bounds__(256) void rmsnorm_k(const float* __restrict__ x,
                                                 const float* __restrict__ w,
                                                 bf16* __restrict__ y, int n) {
  __shared__ float sh[4];
  size_t row = blockIdx.x;
  const float* xr = x + row * n;
  bf16* yr = y + row * n;
  float ss = 0.f;
  for (int i = threadIdx.x; i < n; i += 256) { float v = xr[i]; ss += v * v; }
  ss = blockReduceSum<4>(ss, sh);
  float inv = rsqrtf(ss / n + 1e-5f);
  for (int i = threadIdx.x; i < n; i += 256) yr[i] = (bf16)(xr[i] * inv * w[i]);
}

// ---------------- generic bf16 MFMA GEMM: C = act(A @ W^T) ----------------
template<int ACT, typename OT>
__global__ __launch_bounds__(256) void gemm_mfma(const bf16* __restrict__ A,
                                                 const bf16* __restrict__ W,
                                                 const float* __restrict__ R,
                                                 OT* __restrict__ C,
                                                 int M, int N, int K) {
  __shared__ bf16 As[128 * 32];
  __shared__ bf16 Ws[128 * 32];
  int tid = threadIdx.x, lane = tid & 63, wave = tid >> 6;
  int bm = blockIdx.y * 128, bn = blockIdx.x * 128;
  const bf16* gA0 = A + (size_t)(bm + wave * 32 + (lane >> 2)) * K + (lane & 3) * 8;
  const bf16* gA1 = gA0 + (size_t)16 * K;
  const bf16* gW0 = W + (size_t)(bn + wave * 32 + (lane >> 2)) * K + (lane & 3) * 8;
  const bf16* gW1 = gW0 + (size_t)16 * K;
  bf16* lA0 = As + wave * 32 * 32;
  bf16* lA1 = lA0 + 16 * 32;
  bf16* lW0 = Ws + wave * 32 * 32;
  bf16* lW1 = lW0 + 16 * 32;
  int fr = lane & 15, fq = lane >> 4;
  int wm = wave >> 1, wn = wave & 1;
  const bf16* pA = As + (wm * 64 + fr) * 32 + fq * 8;
  const bf16* pW = Ws + (wn * 64 + fr) * 32 + fq * 8;
  f32x4 acc[4][4] = {};
  for (int k0 = 0; k0 < K; k0 += 32) {
    async_copy16(gA0, lA0);
    async_copy16(gA1, lA1);
    async_copy16(gW0, lW0);
    async_copy16(gW1, lW1);
    gA0 += 32; gA1 += 32; gW0 += 32; gW1 += 32;
    __syncthreads();
    bf16x8 af[4], bfr[4];
#pragma unroll
    for (int mi = 0; mi < 4; mi++) af[mi] = *(const bf16x8*)(pA + mi * 16 * 32);
#pragma unroll
    for (int ni = 0; ni < 4; ni++) bfr[ni] = *(const bf16x8*)(pW + ni * 16 * 32);
#pragma unroll
    for (int mi = 0; mi < 4; mi++)
#pragma unroll
      for (int ni = 0; ni < 4; ni++)
        acc[mi][ni] = __builtin_amdgcn_mfma_f32_16x16x32_bf16(af[mi], bfr[ni], acc[mi][ni], 0, 0, 0);
    __syncthreads();
  }
#pragma unroll
  for (int mi = 0; mi < 4; mi++) {
    int row = bm + wm * 64 + mi * 16 + fq * 4;
#pragma unroll
    for (int ni = 0; ni < 4; ni++) {
      int col = bn + wn * 64 + ni * 16 + fr;
      if (col < N) {
#pragma unroll
        for (int r = 0; r < 4; r++) {
          float v = acc[mi][ni][r];
          if (ACT == 1) v = v / (1.f + __expf(-v));
          if (R) v += R[(size_t)(row + r) * N + col];
          C[(size_t)(row + r) * N + col] = (OT)v;
        }
      }
    }
  }
}

// ---------------- split-K bf16 MFMA GEMM: P[ks] = A @ W^T (partial over K slice) ----------------
__global__ __launch_bounds__(256) void gemm_sk(const bf16* __restrict__ A,
                                               const bf16* __restrict__ W,
                                               float* __restrict__ P,
                                               int M, int N, int K, int kchunk) {
  __shared__ bf16 As[128 * 32];
  __shared__ bf16 Ws[128 * 32];
  int tid = threadIdx.x, lane = tid & 63, wave = tid >> 6;
  int bm = blockIdx.y * 128, bn = blockIdx.x * 128;
  int ks = blockIdx.z;
  int kbeg = ks * kchunk;
  const bf16* gA0 = A + (size_t)(bm + wave * 32 + (lane >> 2)) * K + kbeg + (lane & 3) * 8;
  const bf16* gA1 = gA0 + (size_t)16 * K;
  const bf16* gW0 = W + (size_t)(bn + wave * 32 + (lane >> 2)) * K + kbeg + (lane & 3) * 8;
  const bf16* gW1 = gW0 + (size_t)16 * K;
  bf16* lA0 = As + wave * 32 * 32;
  bf16* lA1 = lA0 + 16 * 32;
  bf16* lW0 = Ws + wave * 32 * 32;
  bf16* lW1 = lW0 + 16 * 32;
  int fr = lane & 15, fq = lane >> 4;
  int wm = wave >> 1, wn = wave & 1;
  const bf16* pA = As + (wm * 64 + fr) * 32 + fq * 8;
  const bf16* pW = Ws + (wn * 64 + fr) * 32 + fq * 8;
  f32x4 acc[4][4] = {};
  for (int k0 = 0; k0 < kchunk; k0 += 32) {
    async_copy16(gA0, lA0);
    async_copy16(gA1, lA1);
    async_copy16(gW0, lW0);
    async_copy16(gW1, lW1);
    gA0 += 32; gA1 += 32; gW0 += 32; gW1 += 32;
    __syncthreads();
    bf16x8 af[4], bfr[4];
#pragma unroll
    for (int mi = 0; mi < 4; mi++) af[mi] = *(const bf16x8*)(pA + mi * 16 * 32);
#pragma unroll
    for (int ni = 0; ni < 4; ni++) bfr[ni] = *(const bf16x8*)(pW + ni * 16 * 32);
#pragma unroll
    for (int mi = 0; mi < 4; mi++)
#pragma unroll
      for (int ni = 0; ni < 4; ni++)
        acc[mi][ni] = __builtin_amdgcn_mfma_f32_16x16x32_bf16(af[mi], bfr[ni], acc[mi][ni], 0, 0, 0);
    __syncthreads();
  }
  float* Pp = P + (size_t)ks * M * N;
#pragma unroll
  for (int mi = 0; mi < 4; mi++) {
    int row = bm + wm * 64 + mi * 16 + fq * 4;
#pragma unroll
    for (int ni = 0; ni < 4; ni++) {
      int col = bn + wn * 64 + ni * 16 + fr;
#pragma unroll
      for (int r = 0; r < 4; r++)
        Pp[(size_t)(row + r) * N + col] = acc[mi][ni][r];
    }
  }
}

// ---------------- reduce 2 partials + residual + layernorm -> x_out f32, h bf16 ----------------
__global__ __launch_bounds__(256) void reduce_ln2(const float* __restrict__ p0,
                                                  const float* __restrict__ p1,
                                                  const float* __restrict__ res,
                                                  const float* __restrict__ w,
                                                  const float* __restrict__ b,
                                                  float* __restrict__ xo,
                                                  bf16* __restrict__ ho) {
  __shared__ float buf[1024];
  __shared__ float sh[4];
  size_t o = (size_t)blockIdx.x * 1024;
  float s = 0.f, s2 = 0.f;
  for (int i = threadIdx.x; i < 1024; i += 256) {
    float v = p0[o + i] + p1[o + i] + res[o + i];
    buf[i] = v; s += v; s2 += v * v;
  }
  s  = blockReduceSum<4>(s,  sh);
  s2 = blockReduceSum<4>(s2, sh);
  float mean = s / 1024.f;
  float var  = s2 / 1024.f - mean * mean;
  float inv  = rsqrtf(var + 1e-5f);
  for (int i = threadIdx.x; i < 1024; i += 256) {
    float v = buf[i];
    xo[o + i] = v;
    ho[o + i] = (bf16)((v - mean) * inv * w[i] + b[i]);
  }
}

// ---------------- reduce 3 partials + residual -> out f32 ----------------
__global__ __launch_bounds__(256) void reduce_out3(const float* __restrict__ p0,
                                                   const float* __restrict__ p1,
                                                   const float* __restrict__ p2,
                                                   const float* __restrict__ res,
                                                   float* __restrict__ out) {
  int i = (blockIdx.x * 256 + threadIdx.x) * 4;
  f32x4 v = *(const f32x4*)(p0 + i);
  v += *(const f32x4*)(p1 + i);
  v += *(const f32x4*)(p2 + i);
  v += *(const f32x4*)(res + i);
  *(f32x4*)(out + i) = v;
}

// ---------------- reduce qkv partials + q/k rmsnorm + rope + gain -> bf16 ----------------
__global__ __launch_bounds__(256) void reduce_qkv(const float* __restrict__ P,
                                                  const float* __restrict__ q_gain,
                                                  bf16* __restrict__ q,
                                                  bf16* __restrict__ k,
                                                  bf16* __restrict__ v) {
  __shared__ float buf[1536];
  size_t row = blockIdx.x;
  size_t o = row * 1536;
  const float* p0 = P + o;
  const float* p1 = P + (size_t)ROWS * 1536 + o;
  int tid = threadIdx.x;
  for (int i = tid; i < 384; i += 256) {
    f32x4 a = *(const f32x4*)(p0 + i * 4);
    f32x4 c = *(const f32x4*)(p1 + i * 4);
    *(f32x4*)(buf + i * 4) = a + c;
  }
  __syncthreads();
  int lane = tid & 63, w = tid >> 6;
  int s = (int)(row & (S_ - 1));
  int ri = lane & 7;
  float rinv = __expf(-(float)ri * (0.125f * 9.210340371976184f)); // 10000^(-i/8)
  float ang = (float)s * rinv;
  float cs = cosf(ang), sn = sinf(ang);
#pragma unroll
  for (int j = 0; j < 6; j++) {
    int hh = w * 6 + j;
    float val = buf[hh * 64 + lane];
    if (hh < 20) {
      float ss = val * val;
#pragma unroll
      for (int off = 32; off > 0; off >>= 1) ss += __shfl_xor(ss, off, 64);
      val *= rsqrtf(ss / 64.f + 1.1920929e-7f);
      float other = __shfl_xor(val, 8, 64);
      float res = val;
      if (lane < RD) res = (lane < 8) ? (val * cs + other * sn) : (val * cs - other * sn);
      if (hh < 16) {
        res *= q_gain[hh];
        q[row * (HATT * HD) + hh * HD + lane] = (bf16)res;
      } else {
        k[row * (KVH * HD) + (hh - 16) * HD + lane] = (bf16)res;
      }
    } else {
      v[row * (KVH * HD) + (hh - 20) * HD + lane] = (bf16)val;
    }
  }
}

// ---------------- in_proj GEMM: writes Zt/Xt transposed + compact bcdt ----------------
__global__ __launch_bounds__(256) void gemm_inproj(const bf16* __restrict__ A,
                                                   const bf16* __restrict__ W,
                                                   bf16* __restrict__ zt,
                                                   bf16* __restrict__ xt,
                                                   bf16* __restrict__ bcdt) {
  const int K = 1024;
  __shared__ bf16 As[128 * 32];
  __shared__ bf16 Ws[128 * 32];
  int tid = threadIdx.x, lane = tid & 63, wave = tid >> 6;
  int bm = blockIdx.y * 128, bn = blockIdx.x * 128;
  const bf16* gA0 = A + (size_t)(bm + wave * 32 + (lane >> 2)) * K + (lane & 3) * 8;
  const bf16* gA1 = gA0 + (size_t)16 * K;
  const bf16* gW0 = W + (size_t)(bn + wave * 32 + (lane >> 2)) * K + (lane & 3) * 8;
  const bf16* gW1 = gW0 + (size_t)16 * K;
  bf16* lA0 = As + wave * 32 * 32;
  bf16* lA1 = lA0 + 16 * 32;
  bf16* lW0 = Ws + wave * 32 * 32;
  bf16* lW1 = lW0 + 16 * 32;
  int fr = lane & 15, fq = lane >> 4;
  int wm = wave >> 1, wn = wave & 1;
  const bf16* pA = As + (wm * 64 + fr) * 32 + fq * 8;
  const bf16* pW = Ws + (wn * 64 + fr) * 32 + fq * 8;
  f32x4 acc[4][4] = {};
  for (int k0 = 0; k0 < K; k0 += 32) {
    async_copy16(gA0, lA0);
    async_copy16(gA1, lA1);
    async_copy16(gW0, lW0);
    async_copy16(gW1, lW1);
    gA0 += 32; gA1 += 32; gW0 += 32; gW1 += 32;
    __syncthreads();
    bf16x8 af[4], bfr[4];
#pragma unroll
    for (int mi = 0; mi < 4; mi++) af[mi] = *(const bf16x8*)(pA + mi * 16 * 32);
#pragma unroll
    for (int ni = 0; ni < 4; ni++) bfr[ni] = *(const bf16x8*)(pW + ni * 16 * 32);
#pragma unroll
    for (int mi = 0; mi < 4; mi++)
#pragma unroll
      for (int ni = 0; ni < 4; ni++)
        acc[mi][ni] = __builtin_amdgcn_mfma_f32_16x16x32_bf16(af[mi], bfr[ni], acc[mi][ni], 0, 0, 0);
    __syncthreads();
  }
#pragma unroll
  for (int mi = 0; mi < 4; mi++) {
    int row0m = bm + wm * 64 + mi * 16 + fq * 4;
    int b = row0m >> 11, sg = row0m & 2047;
#pragma unroll
    for (int ni = 0; ni < 4; ni++) {
      int col = bn + wn * 64 + ni * 16 + fr;
      bf16x4 o;
#pragma unroll
      for (int r = 0; r < 4; r++) o[r] = (bf16)acc[mi][ni][r];
      if (col < 2048) {
        *(bf16x4*)(zt + ((size_t)(b * NH + (col >> 6)) * HD + (col & 63)) * S_ + sg) = o;
      } else if (col < 4096) {
        int xc = col - 2048;
        *(bf16x4*)(xt + ((size_t)(b * NH + (xc >> 6)) * HD + (xc & 63)) * S_ + sg) = o;
      } else if (col < 4384) {
#pragma unroll
        for (int r = 0; r < 4; r++)
          bcdt[(size_t)(row0m + r) * 288 + (col - 4096)] = o[r];
      }
    }
  }
}

// ---------------- generic 64x64 tiled transpose (bf16), out row stride 2048 ----------------
__global__ __launch_bounds__(256) void t64(const bf16* __restrict__ in, bf16* __restrict__ out,
                                           int istr, size_t io, size_t oo, int n_nt) {
  __shared__ bf16 T[64 * 72];
  int bid = blockIdx.x;
  int st = bid & 31;
  int nt = (bid >> 5) % n_nt;
  int outer = bid / (32 * n_nt);
  const bf16* ip = in + outer * io + (size_t)st * 64 * istr + nt * 64;
  int tid = threadIdx.x;
#pragma unroll
  for (int i = 0; i < 2; i++) {
    int cid = tid + i * 256; int s = cid >> 3, pc = (cid & 7) * 8;
    *(bf16x8*)(T + s * 72 + pc) = *(const bf16x8*)(ip + (size_t)s * istr + pc);
  }
  __syncthreads();
  bf16* op = out + outer * oo + (size_t)nt * 64 * 2048 + st * 64;
#pragma unroll
  for (int i = 0; i < 2; i++) {
    int cid = tid + i * 256; int p = cid >> 3, sc = (cid & 7) * 8;
    bf16x8 o;
#pragma unroll
    for (int j = 0; j < 8; j++) o[j] = T[(sc + j) * 72 + p];
    *(bf16x8*)(op + (size_t)p * 2048 + sc) = o;
  }
}

// ---------------- SSD prep: dt softplus, per-chunk cumsum, decay factors ----------------
__global__ __launch_bounds__(64) void ssd_prep(const bf16* __restrict__ bcdt,
                                               const float* __restrict__ dt_bias,
                                               const float* __restrict__ A_log,
                                               float* __restrict__ dt_c,
                                               float* __restrict__ ddc,
                                               float* __restrict__ ac_c,
                                               float* __restrict__ T_out) {
  int bid = blockIdx.x;
  int c = bid % NC, hh = (bid / NC) % NH, b = bid / (NC * NH);
  int l = threadIdx.x;
  size_t row = (size_t)b * S_ + c * 64 + l;
  float raw = (float)bcdt[row * 288 + 256 + hh] + dt_bias[hh];
  float dtv = (raw > 20.f) ? raw : log1pf(__expf(raw));
  float a = -__expf(A_log[hh]) * dtv;
  float ps = a;
#pragma unroll
  for (int off = 1; off < 64; off <<= 1) {
    float t = __shfl_up(ps, off, 64);
    if (l >= off) ps += t;
  }
  float a63 = __shfl(ps, 63, 64);
  size_t o = ((size_t)b * NH + hh) * S_ + c * 64 + l;
  dt_c[o] = dtv;
  ac_c[o] = ps;
  ddc[o] = __expf(a63 - ps) * dtv;
  if (l == 63) T_out[(b * NH + hh) * NC + c] = ps;
}

// ---------------- B/C rmsnorm (bf16 out) ----------------
__global__ __launch_bounds__(128) void bc_norm(const bf16* __restrict__ bcdt,
                                               const float* __restrict__ Bw,
                                               const float* __restrict__ Cw,
                                               bf16* __restrict__ Bn,
                                               bf16* __restrict__ Cn) {
  __shared__ float shb[2], shc[2];
  size_t row = blockIdx.x;
  int i = threadIdx.x;
  float bv = (float)bcdt[row * 288 + i];
  float cv = (float)bcdt[row * 288 + 128 + i];
  float sb = waveReduceSum(bv * bv);
  float sc = waveReduceSum(cv * cv);
  int lane = threadIdx.x & 63, wid = threadIdx.x >> 6;
  if (lane == 0) { shb[wid] = sb; shc[wid] = sc; }
  __syncthreads();
  float tb = shb[0] + shb[1];
  float tc = shc[0] + shc[1];
  Bn[row * DS + i] = (bf16)(bv * rsqrtf(tb / DS + 1e-5f) * Bw[i]);
  Cn[row * DS + i] = (bf16)(cv * rsqrtf(tc / DS + 1e-5f) * Cw[i]);
}

// ---------------- chunk states via MFMA ----------------
__global__ __launch_bounds__(256) void ssd_states(const bf16* __restrict__ Xt,
                                                  const bf16* __restrict__ Btr,
                                                  const float* __restrict__ ddc,
                                                  float* __restrict__ states) {
  __shared__ bf16 Xs[64 * 72];    // [p][s]
  __shared__ bf16 Bs[128 * 72];   // [n][s]
  int bid = blockIdx.x;           // (b*NC + c)*NH + h
  int h = bid % NH;
  int c = (bid / NH) % NC;
  int b = bid / (NH * NC);
  int tid = threadIdx.x, lane = tid & 63, w = tid >> 6;
  int fr = lane & 15, fq = lane >> 4;
  const size_t xbase = (size_t)(b * NH + h) * HD * S_ + c * 64;
  const size_t dbase = (size_t)(b * NH + h) * S_ + c * 64;
#pragma unroll
  for (int i = 0; i < 2; i++) {
    int cid = tid + i * 256; int p = cid >> 3, sc = (cid & 7) * 8;
    bf16x8 xv = *(const bf16x8*)(Xt + xbase + (size_t)p * S_ + sc);
    f32x4 d0 = *(const f32x4*)(ddc + dbase + sc);
    f32x4 d1 = *(const f32x4*)(ddc + dbase + sc + 4);
    bf16x8 o;
#pragma unroll
    for (int j = 0; j < 4; j++) { o[j] = (bf16)((float)xv[j] * d0[j]); o[4 + j] = (bf16)((float)xv[4 + j] * d1[j]); }
    *(bf16x8*)(Xs + p * 72 + sc) = o;
  }
  const size_t bbase = (size_t)b * 128 * S_ + c * 64;
#pragma unroll
  for (int i = 0; i < 4; i++) {
    int cid = tid + i * 256; int n = cid >> 3, sc = (cid & 7) * 8;
    *(bf16x8*)(Bs + n * 72 + sc) = *(const bf16x8*)(Btr + bbase + (size_t)n * S_ + sc);
  }
  __syncthreads();
  f32x4 acc[4][2] = {};
#pragma unroll
  for (int ks = 0; ks < 2; ks++) {
    bf16x8 a[4], bb[2];
#pragma unroll
    for (int pt = 0; pt < 4; pt++) a[pt] = *(const bf16x8*)(Xs + (pt * 16 + fr) * 72 + ks * 32 + fq * 8);
#pragma unroll
    for (int n2 = 0; n2 < 2; n2++) bb[n2] = *(const bf16x8*)(Bs + ((2 * w + n2) * 16 + fr) * 72 + ks * 32 + fq * 8);
#pragma unroll
    for (int pt = 0; pt < 4; pt++)
#pragma unroll
      for (int n2 = 0; n2 < 2; n2++)
        acc[pt][n2] = __builtin_amdgcn_mfma_f32_16x16x32_bf16(a[pt], bb[n2], acc[pt][n2], 0, 0, 0);
  }
  float* outp = states + (size_t)bid * 8192;
#pragma unroll
  for (int pt = 0; pt < 4; pt++)
#pragma unroll
    for (int n2 = 0; n2 < 2; n2++) {
      int n = (2 * w + n2) * 16 + fr;
#pragma unroll
      for (int r = 0; r < 4; r++)
        outp[(size_t)(pt * 16 + fq * 4 + r) * 128 + n] = acc[pt][n2][r];
    }
}

// ---------------- inter-chunk scan (in place) ----------------
__global__ __launch_bounds__(256) void ssd_scan(float* __restrict__ states,
                                                const float* __restrict__ T) {
  __shared__ float eT[NC];
  int part = blockIdx.x & 7;
  int bh = blockIdx.x >> 3;
  int b = bh / NH, h = bh % NH;
  if (threadIdx.x < NC) eT[threadIdx.x] = __expf(T[(size_t)(b * NH + h) * NC + threadIdx.x]);
  __syncthreads();
  const size_t cstride = (size_t)NH * HD * DS;
  size_t base = ((size_t)b * NC * NH + h) * (HD * DS);
#pragma unroll
  for (int j = 0; j < 4; j++) {
    int e = part * 1024 + threadIdx.x + j * 256;
    float carry = 0.f;
    size_t idx = base + e;
    for (int c = 0; c < NC; c++) {
      float sv = states[idx];
      states[idx] = carry;
      carry = sv + eT[c] * carry;
      idx += cstride;
    }
  }
}

// ---------------- fused SSD output: Ydiag + Yoff + D-skip + gate (all MFMA) ----------------
__global__ __launch_bounds__(256) void ssd_out(const bf16* __restrict__ Cn,
                                               const bf16* __restrict__ Bn,
                                               const bf16* __restrict__ Xt,
                                               const bf16* __restrict__ Zt,
                                               const float* __restrict__ dt_c,
                                               const float* __restrict__ ac_c,
                                               const float* __restrict__ states,
                                               const float* __restrict__ Dp,
                                               bf16* __restrict__ ybf) {
  __shared__ bf16 Cs[64 * 136];
  __shared__ bf16 BNs[64 * 136];
  __shared__ bf16 Xs[64 * 72];
  __shared__ bf16 G[64 * 72];
  __shared__ float acs[64];
  int bid = blockIdx.x;
  int h = bid % NH;
  int c = (bid / NH) % NC;
  int b = bid / (NH * NC);
  int tid = threadIdx.x, lane = tid & 63, w = tid >> 6;
  int fr = lane & 15, fq = lane >> 4;
  size_t row0 = (size_t)b * S_ + c * 64;
  const size_t abase = (size_t)(b * NH + h) * S_ + c * 64;
  if (tid < 64) acs[tid] = ac_c[abase + tid];
#pragma unroll
  for (int i = 0; i < 4; i++) {
    int cid = tid + i * 256; int l = cid >> 4, nc = (cid & 15) * 8;
    float e = __expf(ac_c[abase + l]);
    bf16x8 cv = *(const bf16x8*)(Cn + (row0 + l) * DS + nc);
    bf16x8 o;
#pragma unroll
    for (int j = 0; j < 8; j++) o[j] = (bf16)((float)cv[j] * e);
    *(bf16x8*)(Cs + l * 136 + nc) = o;
    *(bf16x8*)(BNs + l * 136 + nc) = *(const bf16x8*)(Bn + (row0 + l) * DS + nc);
  }
  const size_t xbase = (size_t)(b * NH + h) * HD * S_ + c * 64;
#pragma unroll
  for (int i = 0; i < 2; i++) {
    int cid = tid + i * 256; int p = cid >> 3, sc = (cid & 7) * 8;
    bf16x8 xv = *(const bf16x8*)(Xt + xbase + (size_t)p * S_ + sc);
    f32x4 d0 = *(const f32x4*)(dt_c + abase + sc);
    f32x4 d1 = *(const f32x4*)(dt_c + abase + sc + 4);
    bf16x8 o;
#pragma unroll
    for (int j = 0; j < 4; j++) { o[j] = (bf16)((float)xv[j] * d0[j]); o[4 + j] = (bf16)((float)xv[4 + j] * d1[j]); }
    *(bf16x8*)(Xs + p * 72 + sc) = o;
  }
  __syncthreads();
  bf16x8 ca[4];
#pragma unroll
  for (int ks = 0; ks < 4; ks++) ca[ks] = *(const bf16x8*)(Cs + (w * 16 + fr) * 136 + ks * 32 + fq * 8);
  f32x4 cb[4] = {};
  for (int st = 0; st <= w; st++)
#pragma unroll
    for (int ks = 0; ks < 4; ks++)
      cb[st] = __builtin_amdgcn_mfma_f32_16x16x32_bf16(ca[ks],
                 *(const bf16x8*)(BNs + (st * 16 + fr) * 136 + ks * 32 + fq * 8), cb[st], 0, 0, 0);
#pragma unroll
  for (int st = 0; st < 4; st++) {
    float es = (st <= w) ? __expf(-acs[st * 16 + fr]) : 0.f;
#pragma unroll
    for (int r = 0; r < 4; r++) {
      int lloc = fq * 4 + r;
      float g = 0.f;
      if (st < w) g = cb[st][r] * es;
      else if (st == w) g = (lloc >= fr) ? cb[st][r] * es : 0.f;
      G[(w * 16 + lloc) * 72 + st * 16 + fr] = (bf16)g;
    }
  }
  f32x4 acc[4] = {};
  {
    bf16x8 ga0 = *(const bf16x8*)(G + (w * 16 + fr) * 72 + fq * 8);
    bf16x8 ga1 = *(const bf16x8*)(G + (w * 16 + fr) * 72 + 32 + fq * 8);
#pragma unroll
    for (int pt = 0; pt < 4; pt++) {
      acc[pt] = __builtin_amdgcn_mfma_f32_16x16x32_bf16(ga0,
                  *(const bf16x8*)(Xs + (pt * 16 + fr) * 72 + fq * 8), acc[pt], 0, 0, 0);
      acc[pt] = __builtin_amdgcn_mfma_f32_16x16x32_bf16(ga1,
                  *(const bf16x8*)(Xs + (pt * 16 + fr) * 72 + 32 + fq * 8), acc[pt], 0, 0, 0);
    }
  }
  __syncthreads();
  const float* stp = states + (size_t)bid * 8192;
#pragma unroll
  for (int i = 0; i < 4; i++) {
    int cid = tid + i * 256; int p = cid >> 4, nc = (cid & 15) * 8;
    f32x4 s0 = *(const f32x4*)(stp + (size_t)p * 128 + nc);
    f32x4 s1 = *(const f32x4*)(stp + (size_t)p * 128 + nc + 4);
    bf16x8 o;
#pragma unroll
    for (int j = 0; j < 4; j++) { o[j] = (bf16)s0[j]; o[4 + j] = (bf16)s1[j]; }
    *(bf16x8*)(BNs + p * 136 + nc) = o;
  }
  __syncthreads();
#pragma unroll
  for (int pt = 0; pt < 4; pt++)
#pragma unroll
    for (int ks = 0; ks < 4; ks++)
      acc[pt] = __builtin_amdgcn_mfma_f32_16x16x32_bf16(ca[ks],
                  *(const bf16x8*)(BNs + (pt * 16 + fr) * 136 + ks * 32 + fq * 8), acc[pt], 0, 0, 0);
  float dph = Dp[h];
#pragma unroll
  for (int pt = 0; pt < 4; pt++) {
    int p = pt * 16 + fr;
    size_t tb = (xbase + (size_t)p * S_) + w * 16 + fq * 4;
    bf16x4 xs4 = *(const bf16x4*)(Xt + tb);
    bf16x4 z4  = *(const bf16x4*)(Zt + tb);
#pragma unroll
    for (int r = 0; r < 4; r++) {
      int l = w * 16 + fq * 4 + r;
      float yv = acc[pt][r] + (float)xs4[r] * dph;
      float z = (float)z4[r];
      yv *= z / (1.f + __expf(-z));
      ybf[((row0 + l) * NH + h) * HD + p] = (bf16)yv;
    }
  }
}

// ---------------- MFMA flash attention: LDS-staged K/V, double-buffered, ----------------
// fixed-max softmax (|score| <= 42 -> exp2(s*SC - 62)), one barrier per K tile.
#define KSTR 72
#define PSTR 80
__global__ __launch_bounds__(256) void attn_mfma(const bf16* __restrict__ q,
                                                 const bf16* __restrict__ k,
                                                 const bf16* __restrict__ vtr,
                                                 bf16* __restrict__ o) {
  __shared__ bf16 Ks[2][64 * KSTR];
  __shared__ bf16 Vs[2][64 * KSTR];
  __shared__ bf16 Pl[4 * 16 * PSTR];
  int qt = (gridDim.x - 1) - blockIdx.x;   // long rows first
  int h = blockIdx.y, b = blockIdx.z;
  int kvh = h >> 2;
  int tid = threadIdx.x, lane = tid & 63, w = tid >> 6;
  int fr = lane & 15, fq = lane >> 4;
  const float SC = 0.18033688011112042f;   // 0.125 * log2(e)
  const float M2 = 62.0f;
  // Q fragments direct from global (once per block)
  const bf16* qp = q + (size_t)(b * S_ + qt * 64 + w * 16 + fr) * (HATT * HD) + h * HD + fq * 8;
  bf16x8 bq0 = *(const bf16x8*)(qp);
  bf16x8 bq1 = *(const bf16x8*)(qp + 32);
  // staging mapping: thread -> rows (tid>>3, tid>>3 + 32), 16B chunk (tid&7)*8
  int sr = tid >> 3, sc8 = (tid & 7) * 8;
  const bf16* kg = k + ((size_t)(b * S_) + sr) * (KVH * HD) + kvh * HD + sc8;
  const bf16* vg = vtr + ((size_t)(b * KVH + kvh) * HD + sr) * S_ + sc8;
  bf16x8 krg0, krg1, vrg0, vrg1;
  // tile 0
  {
    const bf16* kp = kg;
    const bf16* vp = vg;
    krg0 = *(const bf16x8*)(kp);
    krg1 = *(const bf16x8*)(kp + (size_t)32 * (KVH * HD));
    vrg0 = *(const bf16x8*)(vp);
    vrg1 = *(const bf16x8*)(vp + (size_t)32 * S_);
    *(bf16x8*)(&Ks[0][sr * KSTR + sc8]) = krg0;
    *(bf16x8*)(&Ks[0][(sr + 32) * KSTR + sc8]) = krg1;
    *(bf16x8*)(&Vs[0][sr * KSTR + sc8]) = vrg0;
    *(bf16x8*)(&Vs[0][(sr + 32) * KSTR + sc8]) = vrg1;
  }
  float lsum = 0.f;
  f32x4 yacc[4] = {};
  bf16* Plw = Pl + w * 16 * PSTR;
  for (int kt = 0; kt <= qt; kt++) {
    int cur = kt & 1;
    bool more = kt < qt;
    if (more) {
      const bf16* kp = kg + (size_t)(kt + 1) * 64 * (KVH * HD);
      const bf16* vp = vg + (size_t)(kt + 1) * 64;
      krg0 = *(const bf16x8*)(kp);
      krg1 = *(const bf16x8*)(kp + (size_t)32 * (KVH * HD));
      vrg0 = *(const bf16x8*)(vp);
      vrg1 = *(const bf16x8*)(vp + (size_t)32 * S_);
    }
    __syncthreads();   // buf[cur] staged (by iter kt-1 or prologue); buf[!cur] readers done
    bool diag = (kt == qt);
    // ---- S^T = K · Q^T, softmax (fixed max) ----
#pragma unroll
    for (int mi = 0; mi < 4; mi++) {
      bf16x4 pk = {};
      if (!diag || mi <= w) {
        const bf16* krow = &Ks[cur][(mi * 16 + fr) * KSTR + fq * 8];
        bf16x8 ak0 = *(const bf16x8*)(krow);
        bf16x8 ak1 = *(const bf16x8*)(krow + 32);
        f32x4 s = {};
        s = __builtin_amdgcn_mfma_f32_16x16x32_bf16(ak0, bq0, s, 0, 0, 0);
        s = __builtin_amdgcn_mfma_f32_16x16x32_bf16(ak1, bq1, s, 0, 0, 0);
#pragma unroll
        for (int r = 0; r < 4; r++) {
          bool ok = !diag || (mi < w) || (fq * 4 + r <= fr);
          float p = ok ? __builtin_amdgcn_exp2f(s[r] * SC - M2) : 0.f;
          lsum += p;
          pk[r] = (bf16)p;
        }
      }
      *(bf16x4*)(Plw + fr * PSTR + mi * 16 + fq * 4) = pk;
    }
    // ---- PV: Y^T += V^T · P^T ----
    bf16x8 bp0 = *(const bf16x8*)(Plw + fr * PSTR + fq * 8);
    bool hi = !diag || (w >= 2);
    bf16x8 bp1 = {};
    if (hi) bp1 = *(const bf16x8*)(Plw + fr * PSTR + 32 + fq * 8);
#pragma unroll
    for (int pi = 0; pi < 4; pi++) {
      const bf16* vrow = &Vs[cur][(pi * 16 + fr) * KSTR + fq * 8];
      bf16x8 av0 = *(const bf16x8*)(vrow);
      yacc[pi] = __builtin_amdgcn_mfma_f32_16x16x32_bf16(av0, bp0, yacc[pi], 0, 0, 0);
      if (hi) {
        bf16x8 av1 = *(const bf16x8*)(vrow + 32);
        yacc[pi] = __builtin_amdgcn_mfma_f32_16x16x32_bf16(av1, bp1, yacc[pi], 0, 0, 0);
      }
    }
    // ---- commit next tile into buf[!cur] (its last readers finished before this iter's barrier) ----
    if (more) {
      int nxt = cur ^ 1;
      *(bf16x8*)(&Ks[nxt][sr * KSTR + sc8]) = krg0;
      *(bf16x8*)(&Ks[nxt][(sr + 32) * KSTR + sc8]) = krg1;
      *(bf16x8*)(&Vs[nxt][sr * KSTR + sc8]) = vrg0;
      *(bf16x8*)(&Vs[nxt][(sr + 32) * KSTR + sc8]) = vrg1;
    }
  }
  lsum += __shfl_xor(lsum, 16, 64);
  lsum += __shfl_xor(lsum, 32, 64);
  float inv = 1.f / lsum;
  bf16* op = o + (size_t)(b * S_ + qt * 64 + w * 16 + fr) * (HATT * HD) + h * HD + fq * 4;
#pragma unroll
  for (int pi = 0; pi < 4; pi++) {
    bf16x4 ov;
#pragma unroll
    for (int r = 0; r < 4; r++) ov[r] = (bf16)(yacc[pi][r] * inv);
    *(bf16x4*)(op + pi * 16) = ov;
  }
}

// ---------------- workspace layout (byte offsets) ----------------
constexpr size_t OFF_WIN  = 0;                   // bf16 4480x1024
constexpr size_t OFF_WOUT = 9175040;             // bf16 1024x2048
constexpr size_t OFF_WQKV = 13369344;            // bf16 1536x1024 (q|k|v rows)
constexpr size_t OFF_WCP  = 16515072;            // bf16 1024x1024
constexpr size_t OFF_WFC  = 18612224;            // bf16 3072x1024
constexpr size_t OFF_WPR  = 24903680;            // bf16 1024x3072
constexpr size_t OFF_HBF  = 31195136;            // bf16 4096x1024
constexpr size_t OFF_BCDT = 39583744;            // bf16 4096x288
constexpr size_t OFF_XT   = 41943040;            // bf16 [b][h][p][sg]
constexpr size_t OFF_ZT   = 58720256;            // bf16 [b][h][p][sg]
constexpr size_t OFF_DTC  = 75497472;            // f32 [b][h][sg]
constexpr size_t OFF_DDC  = 76546048;            // f32
constexpr size_t OFF_ACC  = 77594624;            // f32
constexpr size_t OFF_T    = 78643200;            // f32 2048
constexpr size_t OFF_BN   = 78651392;            // bf16 4096x128
constexpr size_t OFF_CN   = 79699968;            // bf16 4096x128
constexpr size_t OFF_BTR  = 80748544;            // bf16 [b][n][sg]
constexpr size_t OFF_ST   = 81797120;            // f32 2048x64x128 (67.1 MB)
constexpr size_t OFF_YBF  = 148905984;           // bf16 4096x2048
constexpr size_t OFF_X1   = 165683200;           // f32 4096x1024 (end 182,460,416)
// aliases (st region dead after ssd_out; Xt/Zt dead after ssd_out; ybf dead after out_proj)
constexpr size_t OFF_P    = OFF_ST;              // f32 split-K partials (up to 50.3 MB)
constexpr size_t OFF_QB   = OFF_ST + 50331648;   // bf16 4096x1024
constexpr size_t OFF_KB   = OFF_ST + 58720256;   // bf16 4096x256
constexpr size_t OFF_VB   = OFF_ST + 60817408;   // bf16 4096x256
constexpr size_t OFF_VTR  = OFF_ST + 62914560;   // bf16 [b][kvh][p][sg] (end 146,821,120)
constexpr size_t OFF_Y2   = OFF_XT;              // bf16 4096x1024
constexpr size_t OFF_X2   = 50331648;            // f32 4096x1024 (in dead Xt/Zt space)
constexpr size_t OFF_MLP  = 132128768;           // bf16 4096x3072 (over dead regions)

extern "C" void kernel_launch(void* const* d_in, const int* in_sizes, int n_in,
                              void* d_out, int out_size, void* d_ws, size_t ws_size,
                              hipStream_t stream) {
  (void)in_sizes; (void)n_in; (void)out_size; (void)ws_size;
  const float* x        = (const float*)d_in[0];
  const float* mnorm_w  = (const float*)d_in[1];
  const float* in_w     = (const float*)d_in[2];
  const float* out_w    = (const float*)d_in[3];
  const float* Dp       = (const float*)d_in[4];
  const float* dt_bias  = (const float*)d_in[5];
  const float* A_log    = (const float*)d_in[6];
  const float* Bn_w     = (const float*)d_in[7];
  const float* Cn_w     = (const float*)d_in[8];
  const float* ln1_w    = (const float*)d_in[9];
  const float* ln1_b    = (const float*)d_in[10];
  const float* cq_w     = (const float*)d_in[11];
  const float* ck_w     = (const float*)d_in[12];
  const float* cv_w     = (const float*)d_in[13];
  const float* cproj_w  = (const float*)d_in[14];
  const float* q_gain   = (const float*)d_in[15];
  const float* ln2_w    = (const float*)d_in[16];
  const float* ln2_b    = (const float*)d_in[17];
  const float* fc_w     = (const float*)d_in[18];
  const float* proj_w   = (const float*)d_in[19];
  float* out = (float*)d_out;
  char* W8 = (char*)d_ws;

  bf16* w_in   = (bf16*)(W8 + OFF_WIN);
  bf16* w_out  = (bf16*)(W8 + OFF_WOUT);
  bf16* w_qkv  = (bf16*)(W8 + OFF_WQKV);
  bf16* w_cp   = (bf16*)(W8 + OFF_WCP);
  bf16* w_fc   = (bf16*)(W8 + OFF_WFC);
  bf16* w_pr   = (bf16*)(W8 + OFF_WPR);
  bf16* h_bf   = (bf16*)(W8 + OFF_HBF);
  bf16* bcdt   = (bf16*)(W8 + OFF_BCDT);
  bf16* Xt     = (bf16*)(W8 + OFF_XT);
  bf16* Zt     = (bf16*)(W8 + OFF_ZT);
  float* dt_c  = (float*)(W8 + OFF_DTC);
  float* ddc   = (float*)(W8 + OFF_DDC);
  float* ac_c  = (float*)(W8 + OFF_ACC);
  float* Tb    = (float*)(W8 + OFF_T);
  bf16* Bn     = (bf16*)(W8 + OFF_BN);
  bf16* Cn     = (bf16*)(W8 + OFF_CN);
  bf16* Btr    = (bf16*)(W8 + OFF_BTR);
  float* st    = (float*)(W8 + OFF_ST);
  bf16* ybf    = (bf16*)(W8 + OFF_YBF);
  float* x1    = (float*)(W8 + OFF_X1);
  float* Pbuf  = (float*)(W8 + OFF_P);
  bf16* qbf    = (bf16*)(W8 + OFF_QB);
  bf16* kbf    = (bf16*)(W8 + OFF_KB);
  bf16* vbf    = (bf16*)(W8 + OFF_VB);
  bf16* vtr    = (bf16*)(W8 + OFF_VTR);
  bf16* y2     = (bf16*)(W8 + OFF_Y2);
  float* x2    = (float*)(W8 + OFF_X2);
  bf16* mlp    = (bf16*)(W8 + OFF_MLP);

  // ---- weight casts (single launch; q/k/v cast into adjacent rows of w_qkv) ----
  CastArgs ca;
  ca.seg[0] = { in_w,    w_in,            4489216, 4587520, 0     };
  ca.seg[1] = { out_w,   w_out,           2097152, 2097152, 4480  };
  ca.seg[2] = { cq_w,    w_qkv,           1048576, 1048576, 6528  };
  ca.seg[3] = { ck_w,    w_qkv + 1048576,  262144,  262144, 7552  };
  ca.seg[4] = { cv_w,    w_qkv + 1310720,  262144,  262144, 7808  };
  ca.seg[5] = { cproj_w, w_cp,            1048576, 1048576, 8064  };
  ca.seg[6] = { fc_w,    w_fc,            3145728, 3145728, 9088  };
  ca.seg[7] = { proj_w,  w_pr,            3145728, 3145728, 12160 };
  castw_all<<<15232, 256, 0, stream>>>(ca);

  const size_t PS = (size_t)ROWS * 1024;   // partial stride for N=1024 GEMMs

  // ---- mamba block ----
  rmsnorm_k<<<ROWS, 256, 0, stream>>>(x, mnorm_w, h_bf, D_);
  gemm_inproj<<<dim3(35, 32), 256, 0, stream>>>(h_bf, w_in, Zt, Xt, bcdt);
  ssd_prep<<<B_ * NH * NC, 64, 0, stream>>>(bcdt, dt_bias, A_log, dt_c, ddc, ac_c, Tb);
  bc_norm<<<ROWS, 128, 0, stream>>>(bcdt, Bn_w, Cn_w, Bn, Cn);
  t64<<<2 * 2 * 32, 256, 0, stream>>>(Bn, Btr, 128, (size_t)2048 * 128, (size_t)128 * 2048, 2);
  ssd_states<<<B_ * NC * NH, 256, 0, stream>>>(Xt, Btr, ddc, st);
  ssd_scan<<<B_ * NH * 8, 256, 0, stream>>>(st, Tb);
  ssd_out<<<B_ * NC * NH, 256, 0, stream>>>(Cn, Bn, Xt, Zt, dt_c, ac_c, st, Dp, ybf);
  // out_proj: split-K=2 then fused reduce+residual+LN1
  gemm_sk<<<dim3(8, 32, 2), 256, 0, stream>>>(ybf, w_out, Pbuf, ROWS, D_, DI, 1024);
  reduce_ln2<<<ROWS, 256, 0, stream>>>(Pbuf, Pbuf + PS, x, ln1_w, ln1_b, x1, h_bf);

  // ---- attention block ----
  gemm_sk<<<dim3(12, 32, 2), 256, 0, stream>>>(h_bf, w_qkv, Pbuf, ROWS, 1536, D_, 512);
  reduce_qkv<<<ROWS, 256, 0, stream>>>(Pbuf, q_gain, qbf, kbf, vbf);
  t64<<<2 * 4 * 32, 256, 0, stream>>>(vbf, vtr, 256, (size_t)2048 * 256, (size_t)256 * 2048, 4);
  attn_mfma<<<dim3(S_ / 64, HATT, B_), 256, 0, stream>>>(qbf, kbf, vtr, y2);
  gemm_sk<<<dim3(8, 32, 2), 256, 0, stream>>>(y2, w_cp, Pbuf, ROWS, D_, D_, 512);
  reduce_ln2<<<ROWS, 256, 0, stream>>>(Pbuf, Pbuf + PS, x1, ln2_w, ln2_b, x2, h_bf);

  // ---- MLP ----
  gemm_mfma<1, bf16><<<dim3(24, 32), 256, 0, stream>>>(h_bf, w_fc, nullptr, mlp, ROWS, MLP, D_);
  gemm_sk<<<dim3(8, 32, 3), 256, 0, stream>>>(mlp, w_pr, Pbuf, ROWS, D_, MLP, 1024);
  reduce_out3<<<ROWS, 256, 0, stream>>>(Pbuf, Pbuf + PS, Pbuf + 2 * PS, x2, out);
}

// Round 7
// 574.854 us; speedup vs baseline: 1.2904x; 1.0604x over previous
//
#include <hip/hip_runtime.h>
#include <hip/hip_bf16.h>
#include <math.h>

// ---------------- problem constants ----------------
#define B_    2
#define S_    2048
#define D_    1024
#define DI    2048      // D_INNER
#define NH    32        // NHEADS (mamba)
#define HD    64        // HEADDIM
#define DS    128       // D_STATE
#define CH    64        // CHUNK
#define NC    32        // S_/CH
#define DP    4384      // D_PROJ
#define HATT  16        // attention heads
#define KVH   4         // kv heads
#define RD    16        // rope dims
#define MLP   3072
#define ROWS  (B_*S_)   // 4096

typedef __bf16 bf16;
typedef __bf16 bf16x8 __attribute__((ext_vector_type(8)));
typedef __bf16 bf16x4 __attribute__((ext_vector_type(4)));
typedef float  f32x4  __attribute__((ext_vector_type(4)));

__device__ __forceinline__ void async_copy16(const void* g, void* l) {
  __builtin_amdgcn_global_load_lds(
      (const __attribute__((address_space(1))) unsigned int*)g,
      (__attribute__((address_space(3))) unsigned int*)l, 16, 0, 0);
}

// ---------------- reductions ----------------
__device__ __forceinline__ float waveReduceSum(float v) {
#pragma unroll
  for (int off = 32; off > 0; off >>= 1) v += __shfl_down(v, off, 64);
  return v;
}

template<int NW>
__device__ __forceinline__ float blockReduceSum(float v, float* sh) {
  v = waveReduceSum(v);
  int lane = threadIdx.x & 63, wid = threadIdx.x >> 6;
  if (lane == 0) sh[wid] = v;
  __syncthreads();
  float s = 0.f;
#pragma unroll
  for (int i = 0; i < NW; i++) s += sh[i];
  __syncthreads();
  return s;
}

// ---------------- merged weight cast f32 -> bf16 ----------------
struct CastSeg { const float* src; bf16* dst; int nval; int ntot; int blk0; };
struct CastArgs { CastSeg seg[8]; };

__global__ __launch_bounds__(256) void castw_all(CastArgs a) {
  int blk = blockIdx.x;
  int si = 0;
#pragma unroll
  for (int i = 1; i < 8; i++) if (blk >= a.seg[i].blk0) si = i;
  CastSeg s = a.seg[si];
  int i = ((blk - s.blk0) * 256 + threadIdx.x) * 4;
  if (i >= s.ntot) return;
  float4 v = {0.f, 0.f, 0.f, 0.f};
  if (i < s.nval) v = *(const float4*)(s.src + i);
  bf16x4 o;
  o[0] = (bf16)v.x; o[1] = (bf16)v.y; o[2] = (bf16)v.z; o[3] = (bf16)v.w;
  *(bf16x4*)(s.dst + i) = o;
}

// ---------------- rmsnorm (f32 in, bf16 out) ----------------
__global__ __launch_bounds__(256) void rmsnorm_k(const float* __restrict__ x,
                                                 const float* __restrict__ w,
                                                 bf16* __restrict__ y, int n) {
  __shared__ float sh[4];
  size_t row = blockIdx.x;
  const float* xr = x + row * n;
  bf16* yr = y + row * n;
  float ss = 0.f;
  for (int i = threadIdx.x; i < n; i += 256) { float v = xr[i]; ss += v * v; }
  ss = blockReduceSum<4>(ss, sh);
  float inv = rsqrtf(ss / n + 1e-5f);
  for (int i = threadIdx.x; i < n; i += 256) yr[i] = (bf16)(xr[i] * inv * w[i]);
}

// ---------------- generic bf16 MFMA GEMM: C = act(A @ W^T) ----------------
template<int ACT, typename OT>
__global__ __launch_bounds__(256) void gemm_mfma(const bf16* __restrict__ A,
                                                 const bf16* __restrict__ W,
                                                 const float* __restrict__ R,
                                                 OT* __restrict__ C,
                                                 int M, int N, int K) {
  __shared__ bf16 As[128 * 32];
  __shared__ bf16 Ws[128 * 32];
  int tid = threadIdx.x, lane = tid & 63, wave = tid >> 6;
  int bm = blockIdx.y * 128, bn = blockIdx.x * 128;
  const bf16* gA0 = A + (size_t)(bm + wave * 32 + (lane >> 2)) * K + (lane & 3) * 8;
  const bf16* gA1 = gA0 + (size_t)16 * K;
  const bf16* gW0 = W + (size_t)(bn + wave * 32 + (lane >> 2)) * K + (lane & 3) * 8;
  const bf16* gW1 = gW0 + (size_t)16 * K;
  bf16* lA0 = As + wave * 32 * 32;
  bf16* lA1 = lA0 + 16 * 32;
  bf16* lW0 = Ws + wave * 32 * 32;
  bf16* lW1 = lW0 + 16 * 32;
  int fr = lane & 15, fq = lane >> 4;
  int wm = wave >> 1, wn = wave & 1;
  const bf16* pA = As + (wm * 64 + fr) * 32 + fq * 8;
  const bf16* pW = Ws + (wn * 64 + fr) * 32 + fq * 8;
  f32x4 acc[4][4] = {};
  for (int k0 = 0; k0 < K; k0 += 32) {
    async_copy16(gA0, lA0);
    async_copy16(gA1, lA1);
    async_copy16(gW0, lW0);
    async_copy16(gW1, lW1);
    gA0 += 32; gA1 += 32; gW0 += 32; gW1 += 32;
    __syncthreads();
    bf16x8 af[4], bfr[4];
#pragma unroll
    for (int mi = 0; mi < 4; mi++) af[mi] = *(const bf16x8*)(pA + mi * 16 * 32);
#pragma unroll
    for (int ni = 0; ni < 4; ni++) bfr[ni] = *(const bf16x8*)(pW + ni * 16 * 32);
#pragma unroll
    for (int mi = 0; mi < 4; mi++)
#pragma unroll
      for (int ni = 0; ni < 4; ni++)
        acc[mi][ni] = __builtin_amdgcn_mfma_f32_16x16x32_bf16(af[mi], bfr[ni], acc[mi][ni], 0, 0, 0);
    __syncthreads();
  }
#pragma unroll
  for (int mi = 0; mi < 4; mi++) {
    int row = bm + wm * 64 + mi * 16 + fq * 4;
#pragma unroll
    for (int ni = 0; ni < 4; ni++) {
      int col = bn + wn * 64 + ni * 16 + fr;
      if (col < N) {
#pragma unroll
        for (int r = 0; r < 4; r++) {
          float v = acc[mi][ni][r];
          if (ACT == 1) v = v / (1.f + __expf(-v));
          if (R) v += R[(size_t)(row + r) * N + col];
          C[(size_t)(row + r) * N + col] = (OT)v;
        }
      }
    }
  }
}

// ---------------- split-K bf16 MFMA GEMM: P[ks] = A @ W^T (partial over K slice) ----------------
__global__ __launch_bounds__(256) void gemm_sk(const bf16* __restrict__ A,
                                               const bf16* __restrict__ W,
                                               float* __restrict__ P,
                                               int M, int N, int K, int kchunk) {
  __shared__ bf16 As[128 * 32];
  __shared__ bf16 Ws[128 * 32];
  int tid = threadIdx.x, lane = tid & 63, wave = tid >> 6;
  int bm = blockIdx.y * 128, bn = blockIdx.x * 128;
  int ks = blockIdx.z;
  int kbeg = ks * kchunk;
  const bf16* gA0 = A + (size_t)(bm + wave * 32 + (lane >> 2)) * K + kbeg + (lane & 3) * 8;
  const bf16* gA1 = gA0 + (size_t)16 * K;
  const bf16* gW0 = W + (size_t)(bn + wave * 32 + (lane >> 2)) * K + kbeg + (lane & 3) * 8;
  const bf16* gW1 = gW0 + (size_t)16 * K;
  bf16* lA0 = As + wave * 32 * 32;
  bf16* lA1 = lA0 + 16 * 32;
  bf16* lW0 = Ws + wave * 32 * 32;
  bf16* lW1 = lW0 + 16 * 32;
  int fr = lane & 15, fq = lane >> 4;
  int wm = wave >> 1, wn = wave & 1;
  const bf16* pA = As + (wm * 64 + fr) * 32 + fq * 8;
  const bf16* pW = Ws + (wn * 64 + fr) * 32 + fq * 8;
  f32x4 acc[4][4] = {};
  for (int k0 = 0; k0 < kchunk; k0 += 32) {
    async_copy16(gA0, lA0);
    async_copy16(gA1, lA1);
    async_copy16(gW0, lW0);
    async_copy16(gW1, lW1);
    gA0 += 32; gA1 += 32; gW0 += 32; gW1 += 32;
    __syncthreads();
    bf16x8 af[4], bfr[4];
#pragma unroll
    for (int mi = 0; mi < 4; mi++) af[mi] = *(const bf16x8*)(pA + mi * 16 * 32);
#pragma unroll
    for (int ni = 0; ni < 4; ni++) bfr[ni] = *(const bf16x8*)(pW + ni * 16 * 32);
#pragma unroll
    for (int mi = 0; mi < 4; mi++)
#pragma unroll
      for (int ni = 0; ni < 4; ni++)
        acc[mi][ni] = __builtin_amdgcn_mfma_f32_16x16x32_bf16(af[mi], bfr[ni], acc[mi][ni], 0, 0, 0);
    __syncthreads();
  }
  float* Pp = P + (size_t)ks * M * N;
#pragma unroll
  for (int mi = 0; mi < 4; mi++) {
    int row = bm + wm * 64 + mi * 16 + fq * 4;
#pragma unroll
    for (int ni = 0; ni < 4; ni++) {
      int col = bn + wn * 64 + ni * 16 + fr;
#pragma unroll
      for (int r = 0; r < 4; r++)
        Pp[(size_t)(row + r) * N + col] = acc[mi][ni][r];
    }
  }
}

// ---------------- reduce 2 partials + residual + layernorm -> x_out f32, h bf16 ----------------
__global__ __launch_bounds__(256) void reduce_ln2(const float* __restrict__ p0,
                                                  const float* __restrict__ p1,
                                                  const float* __restrict__ res,
                                                  const float* __restrict__ w,
                                                  const float* __restrict__ b,
                                                  float* __restrict__ xo,
                                                  bf16* __restrict__ ho) {
  __shared__ float buf[1024];
  __shared__ float sh[4];
  size_t o = (size_t)blockIdx.x * 1024;
  float s = 0.f, s2 = 0.f;
  for (int i = threadIdx.x; i < 1024; i += 256) {
    float v = p0[o + i] + p1[o + i] + res[o + i];
    buf[i] = v; s += v; s2 += v * v;
  }
  s  = blockReduceSum<4>(s,  sh);
  s2 = blockReduceSum<4>(s2, sh);
  float mean = s / 1024.f;
  float var  = s2 / 1024.f - mean * mean;
  float inv  = rsqrtf(var + 1e-5f);
  for (int i = threadIdx.x; i < 1024; i += 256) {
    float v = buf[i];
    xo[o + i] = v;
    ho[o + i] = (bf16)((v - mean) * inv * w[i] + b[i]);
  }
}

// ---------------- reduce 3 partials + residual -> out f32 ----------------
__global__ __launch_bounds__(256) void reduce_out3(const float* __restrict__ p0,
                                                   const float* __restrict__ p1,
                                                   const float* __restrict__ p2,
                                                   const float* __restrict__ res,
                                                   float* __restrict__ out) {
  int i = (blockIdx.x * 256 + threadIdx.x) * 4;
  f32x4 v = *(const f32x4*)(p0 + i);
  v += *(const f32x4*)(p1 + i);
  v += *(const f32x4*)(p2 + i);
  v += *(const f32x4*)(res + i);
  *(f32x4*)(out + i) = v;
}

// ---------------- reduce qkv partials + q/k rmsnorm + rope + gain -> bf16 ----------------
__global__ __launch_bounds__(256) void reduce_qkv(const float* __restrict__ P,
                                                  const float* __restrict__ q_gain,
                                                  bf16* __restrict__ q,
                                                  bf16* __restrict__ k,
                                                  bf16* __restrict__ v) {
  __shared__ float buf[1536];
  size_t row = blockIdx.x;
  size_t o = row * 1536;
  const float* p0 = P + o;
  const float* p1 = P + (size_t)ROWS * 1536 + o;
  int tid = threadIdx.x;
  for (int i = tid; i < 384; i += 256) {
    f32x4 a = *(const f32x4*)(p0 + i * 4);
    f32x4 c = *(const f32x4*)(p1 + i * 4);
    *(f32x4*)(buf + i * 4) = a + c;
  }
  __syncthreads();
  int lane = tid & 63, w = tid >> 6;
  int s = (int)(row & (S_ - 1));
  int ri = lane & 7;
  float rinv = __expf(-(float)ri * (0.125f * 9.210340371976184f)); // 10000^(-i/8)
  float ang = (float)s * rinv;
  float cs = cosf(ang), sn = sinf(ang);
#pragma unroll
  for (int j = 0; j < 6; j++) {
    int hh = w * 6 + j;
    float val = buf[hh * 64 + lane];
    if (hh < 20) {
      float ss = val * val;
#pragma unroll
      for (int off = 32; off > 0; off >>= 1) ss += __shfl_xor(ss, off, 64);
      val *= rsqrtf(ss / 64.f + 1.1920929e-7f);
      float other = __shfl_xor(val, 8, 64);
      float res = val;
      if (lane < RD) res = (lane < 8) ? (val * cs + other * sn) : (val * cs - other * sn);
      if (hh < 16) {
        res *= q_gain[hh];
        q[row * (HATT * HD) + hh * HD + lane] = (bf16)res;
      } else {
        k[row * (KVH * HD) + (hh - 16) * HD + lane] = (bf16)res;
      }
    } else {
      v[row * (KVH * HD) + (hh - 20) * HD + lane] = (bf16)val;
    }
  }
}

// ---------------- in_proj GEMM: writes Zt/Xt transposed + compact bcdt ----------------
__global__ __launch_bounds__(256) void gemm_inproj(const bf16* __restrict__ A,
                                                   const bf16* __restrict__ W,
                                                   bf16* __restrict__ zt,
                                                   bf16* __restrict__ xt,
                                                   bf16* __restrict__ bcdt) {
  const int K = 1024;
  __shared__ bf16 As[128 * 32];
  __shared__ bf16 Ws[128 * 32];
  int tid = threadIdx.x, lane = tid & 63, wave = tid >> 6;
  int bm = blockIdx.y * 128, bn = blockIdx.x * 128;
  const bf16* gA0 = A + (size_t)(bm + wave * 32 + (lane >> 2)) * K + (lane & 3) * 8;
  const bf16* gA1 = gA0 + (size_t)16 * K;
  const bf16* gW0 = W + (size_t)(bn + wave * 32 + (lane >> 2)) * K + (lane & 3) * 8;
  const bf16* gW1 = gW0 + (size_t)16 * K;
  bf16* lA0 = As + wave * 32 * 32;
  bf16* lA1 = lA0 + 16 * 32;
  bf16* lW0 = Ws + wave * 32 * 32;
  bf16* lW1 = lW0 + 16 * 32;
  int fr = lane & 15, fq = lane >> 4;
  int wm = wave >> 1, wn = wave & 1;
  const bf16* pA = As + (wm * 64 + fr) * 32 + fq * 8;
  const bf16* pW = Ws + (wn * 64 + fr) * 32 + fq * 8;
  f32x4 acc[4][4] = {};
  for (int k0 = 0; k0 < K; k0 += 32) {
    async_copy16(gA0, lA0);
    async_copy16(gA1, lA1);
    async_copy16(gW0, lW0);
    async_copy16(gW1, lW1);
    gA0 += 32; gA1 += 32; gW0 += 32; gW1 += 32;
    __syncthreads();
    bf16x8 af[4], bfr[4];
#pragma unroll
    for (int mi = 0; mi < 4; mi++) af[mi] = *(const bf16x8*)(pA + mi * 16 * 32);
#pragma unroll
    for (int ni = 0; ni < 4; ni++) bfr[ni] = *(const bf16x8*)(pW + ni * 16 * 32);
#pragma unroll
    for (int mi = 0; mi < 4; mi++)
#pragma unroll
      for (int ni = 0; ni < 4; ni++)
        acc[mi][ni] = __builtin_amdgcn_mfma_f32_16x16x32_bf16(af[mi], bfr[ni], acc[mi][ni], 0, 0, 0);
    __syncthreads();
  }
#pragma unroll
  for (int mi = 0; mi < 4; mi++) {
    int row0m = bm + wm * 64 + mi * 16 + fq * 4;
    int b = row0m >> 11, sg = row0m & 2047;
#pragma unroll
    for (int ni = 0; ni < 4; ni++) {
      int col = bn + wn * 64 + ni * 16 + fr;
      bf16x4 o;
#pragma unroll
      for (int r = 0; r < 4; r++) o[r] = (bf16)acc[mi][ni][r];
      if (col < 2048) {
        *(bf16x4*)(zt + ((size_t)(b * NH + (col >> 6)) * HD + (col & 63)) * S_ + sg) = o;
      } else if (col < 4096) {
        int xc = col - 2048;
        *(bf16x4*)(xt + ((size_t)(b * NH + (xc >> 6)) * HD + (xc & 63)) * S_ + sg) = o;
      } else if (col < 4384) {
#pragma unroll
        for (int r = 0; r < 4; r++)
          bcdt[(size_t)(row0m + r) * 288 + (col - 4096)] = o[r];
      }
    }
  }
}

// ---------------- generic 64x64 tiled transpose (bf16), out row stride 2048 ----------------
__global__ __launch_bounds__(256) void t64(const bf16* __restrict__ in, bf16* __restrict__ out,
                                           int istr, size_t io, size_t oo, int n_nt) {
  __shared__ bf16 T[64 * 72];
  int bid = blockIdx.x;
  int st = bid & 31;
  int nt = (bid >> 5) % n_nt;
  int outer = bid / (32 * n_nt);
  const bf16* ip = in + outer * io + (size_t)st * 64 * istr + nt * 64;
  int tid = threadIdx.x;
#pragma unroll
  for (int i = 0; i < 2; i++) {
    int cid = tid + i * 256; int s = cid >> 3, pc = (cid & 7) * 8;
    *(bf16x8*)(T + s * 72 + pc) = *(const bf16x8*)(ip + (size_t)s * istr + pc);
  }
  __syncthreads();
  bf16* op = out + outer * oo + (size_t)nt * 64 * 2048 + st * 64;
#pragma unroll
  for (int i = 0; i < 2; i++) {
    int cid = tid + i * 256; int p = cid >> 3, sc = (cid & 7) * 8;
    bf16x8 o;
#pragma unroll
    for (int j = 0; j < 8; j++) o[j] = T[(sc + j) * 72 + p];
    *(bf16x8*)(op + (size_t)p * 2048 + sc) = o;
  }
}

// ---------------- SSD prep: dt softplus, per-chunk cumsum, decay factors ----------------
__global__ __launch_bounds__(64) void ssd_prep(const bf16* __restrict__ bcdt,
                                               const float* __restrict__ dt_bias,
                                               const float* __restrict__ A_log,
                                               float* __restrict__ dt_c,
                                               float* __restrict__ ddc,
                                               float* __restrict__ ac_c,
                                               float* __restrict__ T_out) {
  int bid = blockIdx.x;
  int c = bid % NC, hh = (bid / NC) % NH, b = bid / (NC * NH);
  int l = threadIdx.x;
  size_t row = (size_t)b * S_ + c * 64 + l;
  float raw = (float)bcdt[row * 288 + 256 + hh] + dt_bias[hh];
  float dtv = (raw > 20.f) ? raw : log1pf(__expf(raw));
  float a = -__expf(A_log[hh]) * dtv;
  float ps = a;
#pragma unroll
  for (int off = 1; off < 64; off <<= 1) {
    float t = __shfl_up(ps, off, 64);
    if (l >= off) ps += t;
  }
  float a63 = __shfl(ps, 63, 64);
  size_t o = ((size_t)b * NH + hh) * S_ + c * 64 + l;
  dt_c[o] = dtv;
  ac_c[o] = ps;
  ddc[o] = __expf(a63 - ps) * dtv;
  if (l == 63) T_out[(b * NH + hh) * NC + c] = ps;
}

// ---------------- B/C rmsnorm (bf16 out) ----------------
__global__ __launch_bounds__(128) void bc_norm(const bf16* __restrict__ bcdt,
                                               const float* __restrict__ Bw,
                                               const float* __restrict__ Cw,
                                               bf16* __restrict__ Bn,
                                               bf16* __restrict__ Cn) {
  __shared__ float shb[2], shc[2];
  size_t row = blockIdx.x;
  int i = threadIdx.x;
  float bv = (float)bcdt[row * 288 + i];
  float cv = (float)bcdt[row * 288 + 128 + i];
  float sb = waveReduceSum(bv * bv);
  float sc = waveReduceSum(cv * cv);
  int lane = threadIdx.x & 63, wid = threadIdx.x >> 6;
  if (lane == 0) { shb[wid] = sb; shc[wid] = sc; }
  __syncthreads();
  float tb = shb[0] + shb[1];
  float tc = shc[0] + shc[1];
  Bn[row * DS + i] = (bf16)(bv * rsqrtf(tb / DS + 1e-5f) * Bw[i]);
  Cn[row * DS + i] = (bf16)(cv * rsqrtf(tc / DS + 1e-5f) * Cw[i]);
}

// ---------------- chunk states via MFMA (bf16 output) ----------------
__global__ __launch_bounds__(256) void ssd_states(const bf16* __restrict__ Xt,
                                                  const bf16* __restrict__ Btr,
                                                  const float* __restrict__ ddc,
                                                  bf16* __restrict__ states) {
  __shared__ bf16 Xs[64 * 72];    // [p][s]
  __shared__ bf16 Bs[128 * 72];   // [n][s]
  int bid = blockIdx.x;           // (b*NC + c)*NH + h
  int h = bid % NH;
  int c = (bid / NH) % NC;
  int b = bid / (NH * NC);
  int tid = threadIdx.x, lane = tid & 63, w = tid >> 6;
  int fr = lane & 15, fq = lane >> 4;
  const size_t xbase = (size_t)(b * NH + h) * HD * S_ + c * 64;
  const size_t dbase = (size_t)(b * NH + h) * S_ + c * 64;
#pragma unroll
  for (int i = 0; i < 2; i++) {
    int cid = tid + i * 256; int p = cid >> 3, sc = (cid & 7) * 8;
    bf16x8 xv = *(const bf16x8*)(Xt + xbase + (size_t)p * S_ + sc);
    f32x4 d0 = *(const f32x4*)(ddc + dbase + sc);
    f32x4 d1 = *(const f32x4*)(ddc + dbase + sc + 4);
    bf16x8 o;
#pragma unroll
    for (int j = 0; j < 4; j++) { o[j] = (bf16)((float)xv[j] * d0[j]); o[4 + j] = (bf16)((float)xv[4 + j] * d1[j]); }
    *(bf16x8*)(Xs + p * 72 + sc) = o;
  }
  const size_t bbase = (size_t)b * 128 * S_ + c * 64;
#pragma unroll
  for (int i = 0; i < 4; i++) {
    int cid = tid + i * 256; int n = cid >> 3, sc = (cid & 7) * 8;
    *(bf16x8*)(Bs + n * 72 + sc) = *(const bf16x8*)(Btr + bbase + (size_t)n * S_ + sc);
  }
  __syncthreads();
  f32x4 acc[4][2] = {};
#pragma unroll
  for (int ks = 0; ks < 2; ks++) {
    bf16x8 a[4], bb[2];
#pragma unroll
    for (int pt = 0; pt < 4; pt++) a[pt] = *(const bf16x8*)(Xs + (pt * 16 + fr) * 72 + ks * 32 + fq * 8);
#pragma unroll
    for (int n2 = 0; n2 < 2; n2++) bb[n2] = *(const bf16x8*)(Bs + ((2 * w + n2) * 16 + fr) * 72 + ks * 32 + fq * 8);
#pragma unroll
    for (int pt = 0; pt < 4; pt++)
#pragma unroll
      for (int n2 = 0; n2 < 2; n2++)
        acc[pt][n2] = __builtin_amdgcn_mfma_f32_16x16x32_bf16(a[pt], bb[n2], acc[pt][n2], 0, 0, 0);
  }
  bf16* outp = states + (size_t)bid * 8192;
#pragma unroll
  for (int pt = 0; pt < 4; pt++)
#pragma unroll
    for (int n2 = 0; n2 < 2; n2++) {
      int n = (2 * w + n2) * 16 + fr;
#pragma unroll
      for (int r = 0; r < 4; r++)
        outp[(size_t)(pt * 16 + fq * 4 + r) * 128 + n] = (bf16)acc[pt][n2][r];
    }
}

// ---------------- inter-chunk scan (in place, bf16 storage, f32 math) ----------------
__global__ __launch_bounds__(256) void ssd_scan(bf16* __restrict__ states,
                                                const float* __restrict__ T) {
  __shared__ float eT[NC];
  int part = blockIdx.x & 7;
  int bh = blockIdx.x >> 3;
  int b = bh / NH, h = bh % NH;
  if (threadIdx.x < NC) eT[threadIdx.x] = __expf(T[(size_t)(b * NH + h) * NC + threadIdx.x]);
  __syncthreads();
  const size_t cstride = (size_t)NH * HD * DS;
  size_t base = ((size_t)b * NC * NH + h) * (HD * DS);
#pragma unroll
  for (int j = 0; j < 4; j++) {
    int e = part * 1024 + threadIdx.x + j * 256;
    float carry = 0.f;
    size_t idx = base + e;
    for (int c = 0; c < NC; c++) {
      float sv = (float)states[idx];
      states[idx] = (bf16)carry;
      carry = sv + eT[c] * carry;
      idx += cstride;
    }
  }
}

// ---------------- fused SSD output: Ydiag + Yoff + D-skip + gate (all MFMA) ----------------
__global__ __launch_bounds__(256) void ssd_out(const bf16* __restrict__ Cn,
                                               const bf16* __restrict__ Bn,
                                               const bf16* __restrict__ Xt,
                                               const bf16* __restrict__ Zt,
                                               const float* __restrict__ dt_c,
                                               const float* __restrict__ ac_c,
                                               const bf16* __restrict__ states,
                                               const float* __restrict__ Dp,
                                               bf16* __restrict__ ybf) {
  __shared__ bf16 Cs[64 * 136];
  __shared__ bf16 BNs[64 * 136];
  __shared__ bf16 Xs[64 * 72];
  __shared__ bf16 G[64 * 72];
  __shared__ float acs[64];
  int bid = blockIdx.x;
  int h = bid % NH;
  int c = (bid / NH) % NC;
  int b = bid / (NH * NC);
  int tid = threadIdx.x, lane = tid & 63, w = tid >> 6;
  int fr = lane & 15, fq = lane >> 4;
  size_t row0 = (size_t)b * S_ + c * 64;
  const size_t abase = (size_t)(b * NH + h) * S_ + c * 64;
  if (tid < 64) acs[tid] = ac_c[abase + tid];
#pragma unroll
  for (int i = 0; i < 4; i++) {
    int cid = tid + i * 256; int l = cid >> 4, nc = (cid & 15) * 8;
    float e = __expf(ac_c[abase + l]);
    bf16x8 cv = *(const bf16x8*)(Cn + (row0 + l) * DS + nc);
    bf16x8 o;
#pragma unroll
    for (int j = 0; j < 8; j++) o[j] = (bf16)((float)cv[j] * e);
    *(bf16x8*)(Cs + l * 136 + nc) = o;
    *(bf16x8*)(BNs + l * 136 + nc) = *(const bf16x8*)(Bn + (row0 + l) * DS + nc);
  }
  const size_t xbase = (size_t)(b * NH + h) * HD * S_ + c * 64;
#pragma unroll
  for (int i = 0; i < 2; i++) {
    int cid = tid + i * 256; int p = cid >> 3, sc = (cid & 7) * 8;
    bf16x8 xv = *(const bf16x8*)(Xt + xbase + (size_t)p * S_ + sc);
    f32x4 d0 = *(const f32x4*)(dt_c + abase + sc);
    f32x4 d1 = *(const f32x4*)(dt_c + abase + sc + 4);
    bf16x8 o;
#pragma unroll
    for (int j = 0; j < 4; j++) { o[j] = (bf16)((float)xv[j] * d0[j]); o[4 + j] = (bf16)((float)xv[4 + j] * d1[j]); }
    *(bf16x8*)(Xs + p * 72 + sc) = o;
  }
  __syncthreads();
  bf16x8 ca[4];
#pragma unroll
  for (int ks = 0; ks < 4; ks++) ca[ks] = *(const bf16x8*)(Cs + (w * 16 + fr) * 136 + ks * 32 + fq * 8);
  f32x4 cb[4] = {};
  for (int st = 0; st <= w; st++)
#pragma unroll
    for (int ks = 0; ks < 4; ks++)
      cb[st] = __builtin_amdgcn_mfma_f32_16x16x32_bf16(ca[ks],
                 *(const bf16x8*)(BNs + (st * 16 + fr) * 136 + ks * 32 + fq * 8), cb[st], 0, 0, 0);
#pragma unroll
  for (int st = 0; st < 4; st++) {
    float es = (st <= w) ? __expf(-acs[st * 16 + fr]) : 0.f;
#pragma unroll
    for (int r = 0; r < 4; r++) {
      int lloc = fq * 4 + r;
      float g = 0.f;
      if (st < w) g = cb[st][r] * es;
      else if (st == w) g = (lloc >= fr) ? cb[st][r] * es : 0.f;
      G[(w * 16 + lloc) * 72 + st * 16 + fr] = (bf16)g;
    }
  }
  f32x4 acc[4] = {};
  {
    bf16x8 ga0 = *(const bf16x8*)(G + (w * 16 + fr) * 72 + fq * 8);
    bf16x8 ga1 = *(const bf16x8*)(G + (w * 16 + fr) * 72 + 32 + fq * 8);
#pragma unroll
    for (int pt = 0; pt < 4; pt++) {
      acc[pt] = __builtin_amdgcn_mfma_f32_16x16x32_bf16(ga0,
                  *(const bf16x8*)(Xs + (pt * 16 + fr) * 72 + fq * 8), acc[pt], 0, 0, 0);
      acc[pt] = __builtin_amdgcn_mfma_f32_16x16x32_bf16(ga1,
                  *(const bf16x8*)(Xs + (pt * 16 + fr) * 72 + 32 + fq * 8), acc[pt], 0, 0, 0);
    }
  }
  __syncthreads();
  const bf16* stp = states + (size_t)bid * 8192;
#pragma unroll
  for (int i = 0; i < 4; i++) {
    int cid = tid + i * 256; int p = cid >> 4, nc = (cid & 15) * 8;
    *(bf16x8*)(BNs + p * 136 + nc) = *(const bf16x8*)(stp + (size_t)p * 128 + nc);
  }
  __syncthreads();
#pragma unroll
  for (int pt = 0; pt < 4; pt++)
#pragma unroll
    for (int ks = 0; ks < 4; ks++)
      acc[pt] = __builtin_amdgcn_mfma_f32_16x16x32_bf16(ca[ks],
                  *(const bf16x8*)(BNs + (pt * 16 + fr) * 136 + ks * 32 + fq * 8), acc[pt], 0, 0, 0);
  float dph = Dp[h];
#pragma unroll
  for (int pt = 0; pt < 4; pt++) {
    int p = pt * 16 + fr;
    size_t tb = (xbase + (size_t)p * S_) + w * 16 + fq * 4;
    bf16x4 xs4 = *(const bf16x4*)(Xt + tb);
    bf16x4 z4  = *(const bf16x4*)(Zt + tb);
#pragma unroll
    for (int r = 0; r < 4; r++) {
      int l = w * 16 + fq * 4 + r;
      float yv = acc[pt][r] + (float)xs4[r] * dph;
      float z = (float)z4[r];
      yv *= z / (1.f + __expf(-z));
      ybf[((row0 + l) * NH + h) * HD + p] = (bf16)yv;
    }
  }
}

// ---------------- MFMA flash attention: 128-row q-tile per block, head per block, ----------------
// wave owns 32 q-rows x 64 s (2 q-col tiles): 32 MFMA vs 20 LDS reads per iter.
// Fixed-max softmax (|score| <= 42 -> exp2(s*SC - 62)); K/V double-buffered, 1 barrier/iter.
#define KSTR 72
#define PSTR 72
__global__ __launch_bounds__(256) void attn_mfma(const bf16* __restrict__ q,
                                                 const bf16* __restrict__ k,
                                                 const bf16* __restrict__ vtr,
                                                 bf16* __restrict__ o) {
  __shared__ bf16 Ks[2][64 * KSTR];
  __shared__ bf16 Vs[2][64 * KSTR];
  __shared__ bf16 Pl[4][32 * PSTR];
  int qt = (gridDim.x - 1) - blockIdx.x;   // 0..15, big tiles first
  int h = blockIdx.y, b = blockIdx.z;
  int kvh = h >> 2;
  int tid = threadIdx.x, lane = tid & 63, w = tid >> 6;
  int fr = lane & 15, fq = lane >> 4;
  const float SC = 0.18033688011112042f;   // 0.125 * log2(e)
  const float M2 = 62.0f;
  int qbase = qt * 128 + w * 32;           // wave's first q row
  int qmaxw = qbase + 31;
  // Q fragments (per-wave, 2 q-col tiles x 2 k-steps), loaded once
  bf16x8 bq[2][2];
#pragma unroll
  for (int qc = 0; qc < 2; qc++)
#pragma unroll
    for (int ks = 0; ks < 2; ks++)
      bq[qc][ks] = *(const bf16x8*)(q + (size_t)(b * S_ + qbase + qc * 16 + fr) * (HATT * HD)
                                      + h * HD + ks * 32 + fq * 8);
  // staging: thread -> rows (tid>>3, +32), 16B chunk (tid&7)*8
  int sr = tid >> 3, sc8 = (tid & 7) * 8;
  const bf16* kg = k + ((size_t)(b * S_) + sr) * (KVH * HD) + kvh * HD + sc8;
  const bf16* vg = vtr + ((size_t)(b * KVH + kvh) * HD + sr) * S_ + sc8;
  bf16x8 krg0, krg1, vrg0, vrg1;
  {
    krg0 = *(const bf16x8*)(kg);
    krg1 = *(const bf16x8*)(kg + (size_t)32 * (KVH * HD));
    vrg0 = *(const bf16x8*)(vg);
    vrg1 = *(const bf16x8*)(vg + (size_t)32 * S_);
    *(bf16x8*)(&Ks[0][sr * KSTR + sc8]) = krg0;
    *(bf16x8*)(&Ks[0][(sr + 32) * KSTR + sc8]) = krg1;
    *(bf16x8*)(&Vs[0][sr * KSTR + sc8]) = vrg0;
    *(bf16x8*)(&Vs[0][(sr + 32) * KSTR + sc8]) = vrg1;
  }
  float lsum[2] = {0.f, 0.f};
  f32x4 yacc[2][4] = {};
  bf16* Plw = Pl[w];
  int nkt = 2 * qt + 2;
  for (int kt = 0; kt < nkt; kt++) {
    int cur = kt & 1;
    bool more = (kt + 1) < nkt;
    if (more) {
      const bf16* kp = kg + (size_t)(kt + 1) * 64 * (KVH * HD);
      const bf16* vp = vg + (size_t)(kt + 1) * 64;
      krg0 = *(const bf16x8*)(kp);
      krg1 = *(const bf16x8*)(kp + (size_t)32 * (KVH * HD));
      vrg0 = *(const bf16x8*)(vp);
      vrg1 = *(const bf16x8*)(vp + (size_t)32 * S_);
    }
    __syncthreads();
    if (kt * 64 <= qmaxw) {
      // ---- S^T = K · Q^T per 16x16 tile, fixed-max softmax -> P[qlocal][slocal] ----
#pragma unroll
      for (int mi = 0; mi < 4; mi++) {
        int s0 = kt * 64 + mi * 16;
        if (s0 > qmaxw) {
          bf16x4 zz = {};
#pragma unroll
          for (int qc = 0; qc < 2; qc++)
            *(bf16x4*)(Plw + (qc * 16 + fr) * PSTR + mi * 16 + fq * 4) = zz;
        } else {
          const bf16* krow = &Ks[cur][(mi * 16 + fr) * KSTR];
          bf16x8 ak0 = *(const bf16x8*)(krow + fq * 8);
          bf16x8 ak1 = *(const bf16x8*)(krow + 32 + fq * 8);
#pragma unroll
          for (int qc = 0; qc < 2; qc++) {
            f32x4 s = {};
            s = __builtin_amdgcn_mfma_f32_16x16x32_bf16(ak0, bq[qc][0], s, 0, 0, 0);
            s = __builtin_amdgcn_mfma_f32_16x16x32_bf16(ak1, bq[qc][1], s, 0, 0, 0);
            int qq = qbase + qc * 16 + fr;
            bf16x4 pk;
#pragma unroll
            for (int r = 0; r < 4; r++) {
              int sp = s0 + fq * 4 + r;
              float p = (sp <= qq) ? __builtin_amdgcn_exp2f(s[r] * SC - M2) : 0.f;
              lsum[qc] += p;
              pk[r] = (bf16)p;
            }
            *(bf16x4*)(Plw + (qc * 16 + fr) * PSTR + mi * 16 + fq * 4) = pk;
          }
        }
      }
      // ---- PV: Y^T += V^T · P^T ----
#pragma unroll
      for (int ks2 = 0; ks2 < 2; ks2++) {
        bf16x8 bp[2];
#pragma unroll
        for (int qc = 0; qc < 2; qc++)
          bp[qc] = *(const bf16x8*)(Plw + (qc * 16 + fr) * PSTR + ks2 * 32 + fq * 8);
#pragma unroll
        for (int pi = 0; pi < 4; pi++) {
          bf16x8 av = *(const bf16x8*)(&Vs[cur][(pi * 16 + fr) * KSTR + ks2 * 32 + fq * 8]);
#pragma unroll
          for (int qc = 0; qc < 2; qc++)
            yacc[qc][pi] = __builtin_amdgcn_mfma_f32_16x16x32_bf16(av, bp[qc], yacc[qc][pi], 0, 0, 0);
        }
      }
    }
    if (more) {
      int nxt = cur ^ 1;
      *(bf16x8*)(&Ks[nxt][sr * KSTR + sc8]) = krg0;
      *(bf16x8*)(&Ks[nxt][(sr + 32) * KSTR + sc8]) = krg1;
      *(bf16x8*)(&Vs[nxt][sr * KSTR + sc8]) = vrg0;
      *(bf16x8*)(&Vs[nxt][(sr + 32) * KSTR + sc8]) = vrg1;
    }
  }
#pragma unroll
  for (int qc = 0; qc < 2; qc++) {
    lsum[qc] += __shfl_xor(lsum[qc], 16, 64);
    lsum[qc] += __shfl_xor(lsum[qc], 32, 64);
  }
#pragma unroll
  for (int qc = 0; qc < 2; qc++) {
    float inv = 1.f / lsum[qc];
    bf16* op = o + (size_t)(b * S_ + qbase + qc * 16 + fr) * (HATT * HD) + h * HD + fq * 4;
#pragma unroll
    for (int pi = 0; pi < 4; pi++) {
      bf16x4 ov;
#pragma unroll
      for (int r = 0; r < 4; r++) ov[r] = (bf16)(yacc[qc][pi][r] * inv);
      *(bf16x4*)(op + pi * 16) = ov;
    }
  }
}

// ---------------- workspace layout (byte offsets) ----------------
constexpr size_t OFF_WIN  = 0;                   // bf16 4480x1024
constexpr size_t OFF_WOUT = 9175040;             // bf16 1024x2048
constexpr size_t OFF_WQKV = 13369344;            // bf16 1536x1024 (q|k|v rows)
constexpr size_t OFF_WCP  = 16515072;            // bf16 1024x1024
constexpr size_t OFF_WFC  = 18612224;            // bf16 3072x1024
constexpr size_t OFF_WPR  = 24903680;            // bf16 1024x3072
constexpr size_t OFF_HBF  = 31195136;            // bf16 4096x1024
constexpr size_t OFF_BCDT = 39583744;            // bf16 4096x288
constexpr size_t OFF_XT   = 41943040;            // bf16 [b][h][p][sg]
constexpr size_t OFF_ZT   = 58720256;            // bf16 [b][h][p][sg]
constexpr size_t OFF_DTC  = 75497472;            // f32 [b][h][sg]
constexpr size_t OFF_DDC  = 76546048;            // f32
constexpr size_t OFF_ACC  = 77594624;            // f32
constexpr size_t OFF_T    = 78643200;            // f32 2048
constexpr size_t OFF_BN   = 78651392;            // bf16 4096x128
constexpr size_t OFF_CN   = 79699968;            // bf16 4096x128
constexpr size_t OFF_BTR  = 80748544;            // bf16 [b][n][sg]
constexpr size_t OFF_ST   = 81797120;            // bf16 2048x64x128 (33.5 MB now)
constexpr size_t OFF_YBF  = 148905984;           // bf16 4096x2048
constexpr size_t OFF_X1   = 165683200;           // f32 4096x1024 (end 182,460,416)
// aliases (st region dead after ssd_out; Xt/Zt dead after ssd_out; ybf dead after out_proj)
constexpr size_t OFF_P    = OFF_ST;              // f32 split-K partials (up to 50.3 MB)
constexpr size_t OFF_QB   = OFF_ST + 50331648;   // bf16 4096x1024
constexpr size_t OFF_KB   = OFF_ST + 58720256;   // bf16 4096x256
constexpr size_t OFF_VB   = OFF_ST + 60817408;   // bf16 4096x256
constexpr size_t OFF_VTR  = OFF_ST + 62914560;   // bf16 [b][kvh][p][sg] (end 146,821,120)
constexpr size_t OFF_Y2   = OFF_XT;              // bf16 4096x1024
constexpr size_t OFF_X2   = 50331648;            // f32 4096x1024 (in dead Xt/Zt space)
constexpr size_t OFF_MLP  = 132128768;           // bf16 4096x3072 (over dead regions)

extern "C" void kernel_launch(void* const* d_in, const int* in_sizes, int n_in,
                              void* d_out, int out_size, void* d_ws, size_t ws_size,
                              hipStream_t stream) {
  (void)in_sizes; (void)n_in; (void)out_size; (void)ws_size;
  const float* x        = (const float*)d_in[0];
  const float* mnorm_w  = (const float*)d_in[1];
  const float* in_w     = (const float*)d_in[2];
  const float* out_w    = (const float*)d_in[3];
  const float* Dp       = (const float*)d_in[4];
  const float* dt_bias  = (const float*)d_in[5];
  const float* A_log    = (const float*)d_in[6];
  const float* Bn_w     = (const float*)d_in[7];
  const float* Cn_w     = (const float*)d_in[8];
  const float* ln1_w    = (const float*)d_in[9];
  const float* ln1_b    = (const float*)d_in[10];
  const float* cq_w     = (const float*)d_in[11];
  const float* ck_w     = (const float*)d_in[12];
  const float* cv_w     = (const float*)d_in[13];
  const float* cproj_w  = (const float*)d_in[14];
  const float* q_gain   = (const float*)d_in[15];
  const float* ln2_w    = (const float*)d_in[16];
  const float* ln2_b    = (const float*)d_in[17];
  const float* fc_w     = (const float*)d_in[18];
  const float* proj_w   = (const float*)d_in[19];
  float* out = (float*)d_out;
  char* W8 = (char*)d_ws;

  bf16* w_in   = (bf16*)(W8 + OFF_WIN);
  bf16* w_out  = (bf16*)(W8 + OFF_WOUT);
  bf16* w_qkv  = (bf16*)(W8 + OFF_WQKV);
  bf16* w_cp   = (bf16*)(W8 + OFF_WCP);
  bf16* w_fc   = (bf16*)(W8 + OFF_WFC);
  bf16* w_pr   = (bf16*)(W8 + OFF_WPR);
  bf16* h_bf   = (bf16*)(W8 + OFF_HBF);
  bf16* bcdt   = (bf16*)(W8 + OFF_BCDT);
  bf16* Xt     = (bf16*)(W8 + OFF_XT);
  bf16* Zt     = (bf16*)(W8 + OFF_ZT);
  float* dt_c  = (float*)(W8 + OFF_DTC);
  float* ddc   = (float*)(W8 + OFF_DDC);
  float* ac_c  = (float*)(W8 + OFF_ACC);
  float* Tb    = (float*)(W8 + OFF_T);
  bf16* Bn     = (bf16*)(W8 + OFF_BN);
  bf16* Cn     = (bf16*)(W8 + OFF_CN);
  bf16* Btr    = (bf16*)(W8 + OFF_BTR);
  bf16* st     = (bf16*)(W8 + OFF_ST);
  bf16* ybf    = (bf16*)(W8 + OFF_YBF);
  float* x1    = (float*)(W8 + OFF_X1);
  float* Pbuf  = (float*)(W8 + OFF_P);
  bf16* qbf    = (bf16*)(W8 + OFF_QB);
  bf16* kbf    = (bf16*)(W8 + OFF_KB);
  bf16* vbf    = (bf16*)(W8 + OFF_VB);
  bf16* vtr    = (bf16*)(W8 + OFF_VTR);
  bf16* y2     = (bf16*)(W8 + OFF_Y2);
  float* x2    = (float*)(W8 + OFF_X2);
  bf16* mlp    = (bf16*)(W8 + OFF_MLP);

  // ---- weight casts (single launch; q/k/v cast into adjacent rows of w_qkv) ----
  CastArgs ca;
  ca.seg[0] = { in_w,    w_in,            4489216, 4587520, 0     };
  ca.seg[1] = { out_w,   w_out,           2097152, 2097152, 4480  };
  ca.seg[2] = { cq_w,    w_qkv,           1048576, 1048576, 6528  };
  ca.seg[3] = { ck_w,    w_qkv + 1048576,  262144,  262144, 7552  };
  ca.seg[4] = { cv_w,    w_qkv + 1310720,  262144,  262144, 7808  };
  ca.seg[5] = { cproj_w, w_cp,            1048576, 1048576, 8064  };
  ca.seg[6] = { fc_w,    w_fc,            3145728, 3145728, 9088  };
  ca.seg[7] = { proj_w,  w_pr,            3145728, 3145728, 12160 };
  castw_all<<<15232, 256, 0, stream>>>(ca);

  const size_t PS = (size_t)ROWS * 1024;   // partial stride for N=1024 GEMMs

  // ---- mamba block ----
  rmsnorm_k<<<ROWS, 256, 0, stream>>>(x, mnorm_w, h_bf, D_);
  gemm_inproj<<<dim3(35, 32), 256, 0, stream>>>(h_bf, w_in, Zt, Xt, bcdt);
  ssd_prep<<<B_ * NH * NC, 64, 0, stream>>>(bcdt, dt_bias, A_log, dt_c, ddc, ac_c, Tb);
  bc_norm<<<ROWS, 128, 0, stream>>>(bcdt, Bn_w, Cn_w, Bn, Cn);
  t64<<<2 * 2 * 32, 256, 0, stream>>>(Bn, Btr, 128, (size_t)2048 * 128, (size_t)128 * 2048, 2);
  ssd_states<<<B_ * NC * NH, 256, 0, stream>>>(Xt, Btr, ddc, st);
  ssd_scan<<<B_ * NH * 8, 256, 0, stream>>>(st, Tb);
  ssd_out<<<B_ * NC * NH, 256, 0, stream>>>(Cn, Bn, Xt, Zt, dt_c, ac_c, st, Dp, ybf);
  // out_proj: split-K=2 then fused reduce+residual+LN1
  gemm_sk<<<dim3(8, 32, 2), 256, 0, stream>>>(ybf, w_out, Pbuf, ROWS, D_, DI, 1024);
  reduce_ln2<<<ROWS, 256, 0, stream>>>(Pbuf, Pbuf + PS, x, ln1_w, ln1_b, x1, h_bf);

  // ---- attention block ----
  gemm_sk<<<dim3(12, 32, 2), 256, 0, stream>>>(h_bf, w_qkv, Pbuf, ROWS, 1536, D_, 512);
  reduce_qkv<<<ROWS, 256, 0, stream>>>(Pbuf, q_gain, qbf, kbf, vbf);
  t64<<<2 * 4 * 32, 256, 0, stream>>>(vbf, vtr, 256, (size_t)2048 * 256, (size_t)256 * 2048, 4);
  attn_mfma<<<dim3(S_ / 128, HATT, B_), 256, 0, stream>>>(qbf, kbf, vtr, y2);
  gemm_sk<<<dim3(8, 32, 2), 256, 0, stream>>>(y2, w_cp, Pbuf, ROWS, D_, D_, 512);
  reduce_ln2<<<ROWS, 256, 0, stream>>>(Pbuf, Pbuf + PS, x1, ln2_w, ln2_b, x2, h_bf);

  // ---- MLP ----
  gemm_mfma<1, bf16><<<dim3(24, 32), 256, 0, stream>>>(h_bf, w_fc, nullptr, mlp, ROWS, MLP, D_);
  gemm_sk<<<dim3(8, 32, 3), 256, 0, stream>>>(mlp, w_pr, Pbuf, ROWS, D_, MLP, 1024);
  reduce_out3<<<ROWS, 256, 0, stream>>>(Pbuf, Pbuf + PS, Pbuf + 2 * PS, x2, out);
}

// Round 8
// 535.083 us; speedup vs baseline: 1.3864x; 1.0743x over previous
//
#include <hip/hip_runtime.h>
#include <hip/hip_bf16.h>
#include <math.h>

// ---------------- problem constants ----------------
#define B_    2
#define S_    2048
#define D_    1024
#define DI    2048      // D_INNER
#define NH    32        // NHEADS (mamba)
#define HD    64        // HEADDIM
#define DS    128       // D_STATE
#define CH    64        // CHUNK
#define NC    32        // S_/CH
#define DP    4384      // D_PROJ
#define HATT  16        // attention heads
#define KVH   4         // kv heads
#define RD    16        // rope dims
#define MLP   3072
#define ROWS  (B_*S_)   // 4096

typedef __bf16 bf16;
typedef __bf16 bf16x8 __attribute__((ext_vector_type(8)));
typedef __bf16 bf16x4 __attribute__((ext_vector_type(4)));
typedef float  f32x4  __attribute__((ext_vector_type(4)));

__device__ __forceinline__ void async_copy16(const void* g, void* l) {
  __builtin_amdgcn_global_load_lds(
      (const __attribute__((address_space(1))) unsigned int*)g,
      (__attribute__((address_space(3))) unsigned int*)l, 16, 0, 0);
}

// ---------------- reductions ----------------
__device__ __forceinline__ float waveReduceSum(float v) {
#pragma unroll
  for (int off = 32; off > 0; off >>= 1) v += __shfl_down(v, off, 64);
  return v;
}

template<int NW>
__device__ __forceinline__ float blockReduceSum(float v, float* sh) {
  v = waveReduceSum(v);
  int lane = threadIdx.x & 63, wid = threadIdx.x >> 6;
  if (lane == 0) sh[wid] = v;
  __syncthreads();
  float s = 0.f;
#pragma unroll
  for (int i = 0; i < NW; i++) s += sh[i];
  __syncthreads();
  return s;
}

// ---------------- merged weight cast f32 -> bf16 ----------------
struct CastSeg { const float* src; bf16* dst; int nval; int ntot; int blk0; };
struct CastArgs { CastSeg seg[8]; };

__global__ __launch_bounds__(256) void castw_all(CastArgs a) {
  int blk = blockIdx.x;
  int si = 0;
#pragma unroll
  for (int i = 1; i < 8; i++) if (blk >= a.seg[i].blk0) si = i;
  CastSeg s = a.seg[si];
  int i = ((blk - s.blk0) * 256 + threadIdx.x) * 4;
  if (i >= s.ntot) return;
  float4 v = {0.f, 0.f, 0.f, 0.f};
  if (i < s.nval) v = *(const float4*)(s.src + i);
  bf16x4 o;
  o[0] = (bf16)v.x; o[1] = (bf16)v.y; o[2] = (bf16)v.z; o[3] = (bf16)v.w;
  *(bf16x4*)(s.dst + i) = o;
}

// ---------------- rmsnorm (f32 in, bf16 out) ----------------
__global__ __launch_bounds__(256) void rmsnorm_k(const float* __restrict__ x,
                                                 const float* __restrict__ w,
                                                 bf16* __restrict__ y, int n) {
  __shared__ float sh[4];
  size_t row = blockIdx.x;
  const float* xr = x + row * n;
  bf16* yr = y + row * n;
  float ss = 0.f;
  for (int i = threadIdx.x; i < n; i += 256) { float v = xr[i]; ss += v * v; }
  ss = blockReduceSum<4>(ss, sh);
  float inv = rsqrtf(ss / n + 1e-5f);
  for (int i = threadIdx.x; i < n; i += 256) yr[i] = (bf16)(xr[i] * inv * w[i]);
}

// ---------------- generic bf16 MFMA GEMM: C = act(A @ W^T), bm-fastest 1D grid ----------------
template<int ACT, typename OT>
__global__ __launch_bounds__(256) void gemm_mfma(const bf16* __restrict__ A,
                                                 const bf16* __restrict__ W,
                                                 const float* __restrict__ R,
                                                 OT* __restrict__ C,
                                                 int M, int N, int K) {
  __shared__ bf16 As[128 * 32];
  __shared__ bf16 Ws[128 * 32];
  int tid = threadIdx.x, lane = tid & 63, wave = tid >> 6;
  int mt = M >> 7;
  int bid = blockIdx.x;
  int bm = (bid % mt) * 128, bn = (bid / mt) * 128;
  const bf16* gA0 = A + (size_t)(bm + wave * 32 + (lane >> 2)) * K + (lane & 3) * 8;
  const bf16* gA1 = gA0 + (size_t)16 * K;
  const bf16* gW0 = W + (size_t)(bn + wave * 32 + (lane >> 2)) * K + (lane & 3) * 8;
  const bf16* gW1 = gW0 + (size_t)16 * K;
  bf16* lA0 = As + wave * 32 * 32;
  bf16* lA1 = lA0 + 16 * 32;
  bf16* lW0 = Ws + wave * 32 * 32;
  bf16* lW1 = lW0 + 16 * 32;
  int fr = lane & 15, fq = lane >> 4;
  int wm = wave >> 1, wn = wave & 1;
  const bf16* pA = As + (wm * 64 + fr) * 32 + fq * 8;
  const bf16* pW = Ws + (wn * 64 + fr) * 32 + fq * 8;
  f32x4 acc[4][4] = {};
  for (int k0 = 0; k0 < K; k0 += 32) {
    async_copy16(gA0, lA0);
    async_copy16(gA1, lA1);
    async_copy16(gW0, lW0);
    async_copy16(gW1, lW1);
    gA0 += 32; gA1 += 32; gW0 += 32; gW1 += 32;
    __syncthreads();
    bf16x8 af[4], bfr[4];
#pragma unroll
    for (int mi = 0; mi < 4; mi++) af[mi] = *(const bf16x8*)(pA + mi * 16 * 32);
#pragma unroll
    for (int ni = 0; ni < 4; ni++) bfr[ni] = *(const bf16x8*)(pW + ni * 16 * 32);
#pragma unroll
    for (int mi = 0; mi < 4; mi++)
#pragma unroll
      for (int ni = 0; ni < 4; ni++)
        acc[mi][ni] = __builtin_amdgcn_mfma_f32_16x16x32_bf16(af[mi], bfr[ni], acc[mi][ni], 0, 0, 0);
    __syncthreads();
  }
#pragma unroll
  for (int mi = 0; mi < 4; mi++) {
    int row = bm + wm * 64 + mi * 16 + fq * 4;
#pragma unroll
    for (int ni = 0; ni < 4; ni++) {
      int col = bn + wn * 64 + ni * 16 + fr;
      if (col < N) {
#pragma unroll
        for (int r = 0; r < 4; r++) {
          float v = acc[mi][ni][r];
          if (ACT == 1) v = v / (1.f + __expf(-v));
          if (R) v += R[(size_t)(row + r) * N + col];
          C[(size_t)(row + r) * N + col] = (OT)v;
        }
      }
    }
  }
}

// ---------------- split-K bf16 MFMA GEMM: P[ks] = A @ W^T (bf16 partials) ----------------
__global__ __launch_bounds__(256) void gemm_sk(const bf16* __restrict__ A,
                                               const bf16* __restrict__ W,
                                               bf16* __restrict__ P,
                                               int M, int N, int K, int kchunk) {
  __shared__ bf16 As[128 * 32];
  __shared__ bf16 Ws[128 * 32];
  int tid = threadIdx.x, lane = tid & 63, wave = tid >> 6;
  int mt = M >> 7;
  int bid = blockIdx.x;
  int bm = (bid % mt) * 128, bn = (bid / mt) * 128;
  int ks = blockIdx.z;
  int kbeg = ks * kchunk;
  const bf16* gA0 = A + (size_t)(bm + wave * 32 + (lane >> 2)) * K + kbeg + (lane & 3) * 8;
  const bf16* gA1 = gA0 + (size_t)16 * K;
  const bf16* gW0 = W + (size_t)(bn + wave * 32 + (lane >> 2)) * K + kbeg + (lane & 3) * 8;
  const bf16* gW1 = gW0 + (size_t)16 * K;
  bf16* lA0 = As + wave * 32 * 32;
  bf16* lA1 = lA0 + 16 * 32;
  bf16* lW0 = Ws + wave * 32 * 32;
  bf16* lW1 = lW0 + 16 * 32;
  int fr = lane & 15, fq = lane >> 4;
  int wm = wave >> 1, wn = wave & 1;
  const bf16* pA = As + (wm * 64 + fr) * 32 + fq * 8;
  const bf16* pW = Ws + (wn * 64 + fr) * 32 + fq * 8;
  f32x4 acc[4][4] = {};
  for (int k0 = 0; k0 < kchunk; k0 += 32) {
    async_copy16(gA0, lA0);
    async_copy16(gA1, lA1);
    async_copy16(gW0, lW0);
    async_copy16(gW1, lW1);
    gA0 += 32; gA1 += 32; gW0 += 32; gW1 += 32;
    __syncthreads();
    bf16x8 af[4], bfr[4];
#pragma unroll
    for (int mi = 0; mi < 4; mi++) af[mi] = *(const bf16x8*)(pA + mi * 16 * 32);
#pragma unroll
    for (int ni = 0; ni < 4; ni++) bfr[ni] = *(const bf16x8*)(pW + ni * 16 * 32);
#pragma unroll
    for (int mi = 0; mi < 4; mi++)
#pragma unroll
      for (int ni = 0; ni < 4; ni++)
        acc[mi][ni] = __builtin_amdgcn_mfma_f32_16x16x32_bf16(af[mi], bfr[ni], acc[mi][ni], 0, 0, 0);
    __syncthreads();
  }
  bf16* Pp = P + (size_t)ks * M * N;
#pragma unroll
  for (int mi = 0; mi < 4; mi++) {
    int row = bm + wm * 64 + mi * 16 + fq * 4;
#pragma unroll
    for (int ni = 0; ni < 4; ni++) {
      int col = bn + wn * 64 + ni * 16 + fr;
#pragma unroll
      for (int r = 0; r < 4; r++)
        Pp[(size_t)(row + r) * N + col] = (bf16)acc[mi][ni][r];
    }
  }
}

// ---------------- reduce 2 bf16 partials + residual + layernorm -> x_out f32, h bf16 ----------------
__global__ __launch_bounds__(256) void reduce_ln2(const bf16* __restrict__ p0,
                                                  const bf16* __restrict__ p1,
                                                  const float* __restrict__ res,
                                                  const float* __restrict__ w,
                                                  const float* __restrict__ b,
                                                  float* __restrict__ xo,
                                                  bf16* __restrict__ ho) {
  __shared__ float sh[4];
  size_t o = (size_t)blockIdx.x * 1024;
  int i = threadIdx.x * 4;
  bf16x4 a = *(const bf16x4*)(p0 + o + i);
  bf16x4 c = *(const bf16x4*)(p1 + o + i);
  f32x4 rv = *(const f32x4*)(res + o + i);
  f32x4 v;
  float s = 0.f, s2 = 0.f;
#pragma unroll
  for (int j = 0; j < 4; j++) {
    v[j] = (float)a[j] + (float)c[j] + rv[j];
    s += v[j]; s2 += v[j] * v[j];
  }
  s  = blockReduceSum<4>(s,  sh);
  s2 = blockReduceSum<4>(s2, sh);
  float mean = s / 1024.f;
  float var  = s2 / 1024.f - mean * mean;
  float inv  = rsqrtf(var + 1e-5f);
  f32x4 wv = *(const f32x4*)(w + i);
  f32x4 bv = *(const f32x4*)(b + i);
  *(f32x4*)(xo + o + i) = v;
  bf16x4 hv;
#pragma unroll
  for (int j = 0; j < 4; j++) hv[j] = (bf16)((v[j] - mean) * inv * wv[j] + bv[j]);
  *(bf16x4*)(ho + o + i) = hv;
}

// ---------------- reduce 3 bf16 partials + residual -> out f32 ----------------
__global__ __launch_bounds__(256) void reduce_out3(const bf16* __restrict__ p0,
                                                   const bf16* __restrict__ p1,
                                                   const bf16* __restrict__ p2,
                                                   const float* __restrict__ res,
                                                   float* __restrict__ out) {
  int i = (blockIdx.x * 256 + threadIdx.x) * 4;
  bf16x4 a = *(const bf16x4*)(p0 + i);
  bf16x4 c = *(const bf16x4*)(p1 + i);
  bf16x4 d = *(const bf16x4*)(p2 + i);
  f32x4 v = *(const f32x4*)(res + i);
#pragma unroll
  for (int j = 0; j < 4; j++) v[j] += (float)a[j] + (float)c[j] + (float)d[j];
  *(f32x4*)(out + i) = v;
}

// ---------------- reduce qkv bf16 partials + q/k rmsnorm + rope + gain -> bf16 ----------------
__global__ __launch_bounds__(256) void reduce_qkv(const bf16* __restrict__ P,
                                                  const float* __restrict__ q_gain,
                                                  bf16* __restrict__ q,
                                                  bf16* __restrict__ k,
                                                  bf16* __restrict__ v) {
  __shared__ float buf[1536];
  size_t row = blockIdx.x;
  size_t o = row * 1536;
  const bf16* p0 = P + o;
  const bf16* p1 = P + (size_t)ROWS * 1536 + o;
  int tid = threadIdx.x;
  for (int i = tid; i < 384; i += 256) {
    bf16x4 a = *(const bf16x4*)(p0 + i * 4);
    bf16x4 c = *(const bf16x4*)(p1 + i * 4);
    f32x4 vv;
#pragma unroll
    for (int j = 0; j < 4; j++) vv[j] = (float)a[j] + (float)c[j];
    *(f32x4*)(buf + i * 4) = vv;
  }
  __syncthreads();
  int lane = tid & 63, w = tid >> 6;
  int s = (int)(row & (S_ - 1));
  int ri = lane & 7;
  float rinv = __expf(-(float)ri * (0.125f * 9.210340371976184f)); // 10000^(-i/8)
  float ang = (float)s * rinv;
  float cs = cosf(ang), sn = sinf(ang);
#pragma unroll
  for (int j = 0; j < 6; j++) {
    int hh = w * 6 + j;
    float val = buf[hh * 64 + lane];
    if (hh < 20) {
      float ss = val * val;
#pragma unroll
      for (int off = 32; off > 0; off >>= 1) ss += __shfl_xor(ss, off, 64);
      val *= rsqrtf(ss / 64.f + 1.1920929e-7f);
      float other = __shfl_xor(val, 8, 64);
      float res = val;
      if (lane < RD) res = (lane < 8) ? (val * cs + other * sn) : (val * cs - other * sn);
      if (hh < 16) {
        res *= q_gain[hh];
        q[row * (HATT * HD) + hh * HD + lane] = (bf16)res;
      } else {
        k[row * (KVH * HD) + (hh - 16) * HD + lane] = (bf16)res;
      }
    } else {
      v[row * (KVH * HD) + (hh - 20) * HD + lane] = (bf16)val;
    }
  }
}

// ---------------- in_proj GEMM: writes Zt/Xt transposed + compact bcdt (bm-fastest) ----------------
__global__ __launch_bounds__(256) void gemm_inproj(const bf16* __restrict__ A,
                                                   const bf16* __restrict__ W,
                                                   bf16* __restrict__ zt,
                                                   bf16* __restrict__ xt,
                                                   bf16* __restrict__ bcdt) {
  const int K = 1024;
  __shared__ bf16 As[128 * 32];
  __shared__ bf16 Ws[128 * 32];
  int tid = threadIdx.x, lane = tid & 63, wave = tid >> 6;
  int bid = blockIdx.x;
  int bm = (bid & 31) * 128, bn = (bid >> 5) * 128;
  const bf16* gA0 = A + (size_t)(bm + wave * 32 + (lane >> 2)) * K + (lane & 3) * 8;
  const bf16* gA1 = gA0 + (size_t)16 * K;
  const bf16* gW0 = W + (size_t)(bn + wave * 32 + (lane >> 2)) * K + (lane & 3) * 8;
  const bf16* gW1 = gW0 + (size_t)16 * K;
  bf16* lA0 = As + wave * 32 * 32;
  bf16* lA1 = lA0 + 16 * 32;
  bf16* lW0 = Ws + wave * 32 * 32;
  bf16* lW1 = lW0 + 16 * 32;
  int fr = lane & 15, fq = lane >> 4;
  int wm = wave >> 1, wn = wave & 1;
  const bf16* pA = As + (wm * 64 + fr) * 32 + fq * 8;
  const bf16* pW = Ws + (wn * 64 + fr) * 32 + fq * 8;
  f32x4 acc[4][4] = {};
  for (int k0 = 0; k0 < K; k0 += 32) {
    async_copy16(gA0, lA0);
    async_copy16(gA1, lA1);
    async_copy16(gW0, lW0);
    async_copy16(gW1, lW1);
    gA0 += 32; gA1 += 32; gW0 += 32; gW1 += 32;
    __syncthreads();
    bf16x8 af[4], bfr[4];
#pragma unroll
    for (int mi = 0; mi < 4; mi++) af[mi] = *(const bf16x8*)(pA + mi * 16 * 32);
#pragma unroll
    for (int ni = 0; ni < 4; ni++) bfr[ni] = *(const bf16x8*)(pW + ni * 16 * 32);
#pragma unroll
    for (int mi = 0; mi < 4; mi++)
#pragma unroll
      for (int ni = 0; ni < 4; ni++)
        acc[mi][ni] = __builtin_amdgcn_mfma_f32_16x16x32_bf16(af[mi], bfr[ni], acc[mi][ni], 0, 0, 0);
    __syncthreads();
  }
#pragma unroll
  for (int mi = 0; mi < 4; mi++) {
    int row0m = bm + wm * 64 + mi * 16 + fq * 4;
    int b = row0m >> 11, sg = row0m & 2047;
#pragma unroll
    for (int ni = 0; ni < 4; ni++) {
      int col = bn + wn * 64 + ni * 16 + fr;
      bf16x4 o;
#pragma unroll
      for (int r = 0; r < 4; r++) o[r] = (bf16)acc[mi][ni][r];
      if (col < 2048) {
        *(bf16x4*)(zt + ((size_t)(b * NH + (col >> 6)) * HD + (col & 63)) * S_ + sg) = o;
      } else if (col < 4096) {
        int xc = col - 2048;
        *(bf16x4*)(xt + ((size_t)(b * NH + (xc >> 6)) * HD + (xc & 63)) * S_ + sg) = o;
      } else if (col < 4384) {
#pragma unroll
        for (int r = 0; r < 4; r++)
          bcdt[(size_t)(row0m + r) * 288 + (col - 4096)] = o[r];
      }
    }
  }
}

// ---------------- generic 64x64 tiled transpose (bf16), out row stride 2048 ----------------
__global__ __launch_bounds__(256) void t64(const bf16* __restrict__ in, bf16* __restrict__ out,
                                           int istr, size_t io, size_t oo, int n_nt) {
  __shared__ bf16 T[64 * 72];
  int bid = blockIdx.x;
  int st = bid & 31;
  int nt = (bid >> 5) % n_nt;
  int outer = bid / (32 * n_nt);
  const bf16* ip = in + outer * io + (size_t)st * 64 * istr + nt * 64;
  int tid = threadIdx.x;
#pragma unroll
  for (int i = 0; i < 2; i++) {
    int cid = tid + i * 256; int s = cid >> 3, pc = (cid & 7) * 8;
    *(bf16x8*)(T + s * 72 + pc) = *(const bf16x8*)(ip + (size_t)s * istr + pc);
  }
  __syncthreads();
  bf16* op = out + outer * oo + (size_t)nt * 64 * 2048 + st * 64;
#pragma unroll
  for (int i = 0; i < 2; i++) {
    int cid = tid + i * 256; int p = cid >> 3, sc = (cid & 7) * 8;
    bf16x8 o;
#pragma unroll
    for (int j = 0; j < 8; j++) o[j] = T[(sc + j) * 72 + p];
    *(bf16x8*)(op + (size_t)p * 2048 + sc) = o;
  }
}

// ---------------- SSD prep: dt softplus, per-chunk cumsum, decay factors ----------------
__global__ __launch_bounds__(64) void ssd_prep(const bf16* __restrict__ bcdt,
                                               const float* __restrict__ dt_bias,
                                               const float* __restrict__ A_log,
                                               float* __restrict__ dt_c,
                                               float* __restrict__ ddc,
                                               float* __restrict__ ac_c,
                                               float* __restrict__ T_out) {
  int bid = blockIdx.x;
  int c = bid % NC, hh = (bid / NC) % NH, b = bid / (NC * NH);
  int l = threadIdx.x;
  size_t row = (size_t)b * S_ + c * 64 + l;
  float raw = (float)bcdt[row * 288 + 256 + hh] + dt_bias[hh];
  float dtv = (raw > 20.f) ? raw : log1pf(__expf(raw));
  float a = -__expf(A_log[hh]) * dtv;
  float ps = a;
#pragma unroll
  for (int off = 1; off < 64; off <<= 1) {
    float t = __shfl_up(ps, off, 64);
    if (l >= off) ps += t;
  }
  float a63 = __shfl(ps, 63, 64);
  size_t o = ((size_t)b * NH + hh) * S_ + c * 64 + l;
  dt_c[o] = dtv;
  ac_c[o] = ps;
  ddc[o] = __expf(a63 - ps) * dtv;
  if (l == 63) T_out[(b * NH + hh) * NC + c] = ps;
}

// ---------------- B/C rmsnorm (bf16 out) ----------------
__global__ __launch_bounds__(128) void bc_norm(const bf16* __restrict__ bcdt,
                                               const float* __restrict__ Bw,
                                               const float* __restrict__ Cw,
                                               bf16* __restrict__ Bn,
                                               bf16* __restrict__ Cn) {
  __shared__ float shb[2], shc[2];
  size_t row = blockIdx.x;
  int i = threadIdx.x;
  float bv = (float)bcdt[row * 288 + i];
  float cv = (float)bcdt[row * 288 + 128 + i];
  float sb = waveReduceSum(bv * bv);
  float sc = waveReduceSum(cv * cv);
  int lane = threadIdx.x & 63, wid = threadIdx.x >> 6;
  if (lane == 0) { shb[wid] = sb; shc[wid] = sc; }
  __syncthreads();
  float tb = shb[0] + shb[1];
  float tc = shc[0] + shc[1];
  Bn[row * DS + i] = (bf16)(bv * rsqrtf(tb / DS + 1e-5f) * Bw[i]);
  Cn[row * DS + i] = (bf16)(cv * rsqrtf(tc / DS + 1e-5f) * Cw[i]);
}

// ---------------- chunk states via MFMA (bf16 output) ----------------
__global__ __launch_bounds__(256) void ssd_states(const bf16* __restrict__ Xt,
                                                  const bf16* __restrict__ Btr,
                                                  const float* __restrict__ ddc,
                                                  bf16* __restrict__ states) {
  __shared__ bf16 Xs[64 * 72];    // [p][s]
  __shared__ bf16 Bs[128 * 72];   // [n][s]
  int bid = blockIdx.x;           // (b*NC + c)*NH + h
  int h = bid % NH;
  int c = (bid / NH) % NC;
  int b = bid / (NH * NC);
  int tid = threadIdx.x, lane = tid & 63, w = tid >> 6;
  int fr = lane & 15, fq = lane >> 4;
  const size_t xbase = (size_t)(b * NH + h) * HD * S_ + c * 64;
  const size_t dbase = (size_t)(b * NH + h) * S_ + c * 64;
#pragma unroll
  for (int i = 0; i < 2; i++) {
    int cid = tid + i * 256; int p = cid >> 3, sc = (cid & 7) * 8;
    bf16x8 xv = *(const bf16x8*)(Xt + xbase + (size_t)p * S_ + sc);
    f32x4 d0 = *(const f32x4*)(ddc + dbase + sc);
    f32x4 d1 = *(const f32x4*)(ddc + dbase + sc + 4);
    bf16x8 o;
#pragma unroll
    for (int j = 0; j < 4; j++) { o[j] = (bf16)((float)xv[j] * d0[j]); o[4 + j] = (bf16)((float)xv[4 + j] * d1[j]); }
    *(bf16x8*)(Xs + p * 72 + sc) = o;
  }
  const size_t bbase = (size_t)b * 128 * S_ + c * 64;
#pragma unroll
  for (int i = 0; i < 4; i++) {
    int cid = tid + i * 256; int n = cid >> 3, sc = (cid & 7) * 8;
    *(bf16x8*)(Bs + n * 72 + sc) = *(const bf16x8*)(Btr + bbase + (size_t)n * S_ + sc);
  }
  __syncthreads();
  f32x4 acc[4][2] = {};
#pragma unroll
  for (int ks = 0; ks < 2; ks++) {
    bf16x8 a[4], bb[2];
#pragma unroll
    for (int pt = 0; pt < 4; pt++) a[pt] = *(const bf16x8*)(Xs + (pt * 16 + fr) * 72 + ks * 32 + fq * 8);
#pragma unroll
    for (int n2 = 0; n2 < 2; n2++) bb[n2] = *(const bf16x8*)(Bs + ((2 * w + n2) * 16 + fr) * 72 + ks * 32 + fq * 8);
#pragma unroll
    for (int pt = 0; pt < 4; pt++)
#pragma unroll
      for (int n2 = 0; n2 < 2; n2++)
        acc[pt][n2] = __builtin_amdgcn_mfma_f32_16x16x32_bf16(a[pt], bb[n2], acc[pt][n2], 0, 0, 0);
  }
  bf16* outp = states + (size_t)bid * 8192;
#pragma unroll
  for (int pt = 0; pt < 4; pt++)
#pragma unroll
    for (int n2 = 0; n2 < 2; n2++) {
      int n = (2 * w + n2) * 16 + fr;
#pragma unroll
      for (int r = 0; r < 4; r++)
        outp[(size_t)(pt * 16 + fq * 4 + r) * 128 + n] = (bf16)acc[pt][n2][r];
    }
}

// ---------------- inter-chunk scan (in place, bf16 storage, f32 math) ----------------
__global__ __launch_bounds__(256) void ssd_scan(bf16* __restrict__ states,
                                                const float* __restrict__ T) {
  __shared__ float eT[NC];
  int part = blockIdx.x & 7;
  int bh = blockIdx.x >> 3;
  int b = bh / NH, h = bh % NH;
  if (threadIdx.x < NC) eT[threadIdx.x] = __expf(T[(size_t)(b * NH + h) * NC + threadIdx.x]);
  __syncthreads();
  const size_t cstride = (size_t)NH * HD * DS;
  size_t base = ((size_t)b * NC * NH + h) * (HD * DS);
#pragma unroll
  for (int j = 0; j < 4; j++) {
    int e = part * 1024 + threadIdx.x + j * 256;
    float carry = 0.f;
    size_t idx = base + e;
    for (int c = 0; c < NC; c++) {
      float sv = (float)states[idx];
      states[idx] = (bf16)carry;
      carry = sv + eT[c] * carry;
      idx += cstride;
    }
  }
}

// ---------------- fused SSD output: Ydiag + Yoff + D-skip + gate (all MFMA) ----------------
__global__ __launch_bounds__(256) void ssd_out(const bf16* __restrict__ Cn,
                                               const bf16* __restrict__ Bn,
                                               const bf16* __restrict__ Xt,
                                               const bf16* __restrict__ Zt,
                                               const float* __restrict__ dt_c,
                                               const float* __restrict__ ac_c,
                                               const bf16* __restrict__ states,
                                               const float* __restrict__ Dp,
                                               bf16* __restrict__ ybf) {
  __shared__ bf16 Cs[64 * 136];
  __shared__ bf16 BNs[64 * 136];
  __shared__ bf16 Xs[64 * 72];
  __shared__ bf16 G[64 * 72];
  __shared__ float acs[64];
  int bid = blockIdx.x;
  int h = bid % NH;
  int c = (bid / NH) % NC;
  int b = bid / (NH * NC);
  int tid = threadIdx.x, lane = tid & 63, w = tid >> 6;
  int fr = lane & 15, fq = lane >> 4;
  size_t row0 = (size_t)b * S_ + c * 64;
  const size_t abase = (size_t)(b * NH + h) * S_ + c * 64;
  if (tid < 64) acs[tid] = ac_c[abase + tid];
#pragma unroll
  for (int i = 0; i < 4; i++) {
    int cid = tid + i * 256; int l = cid >> 4, nc = (cid & 15) * 8;
    float e = __expf(ac_c[abase + l]);
    bf16x8 cv = *(const bf16x8*)(Cn + (row0 + l) * DS + nc);
    bf16x8 o;
#pragma unroll
    for (int j = 0; j < 8; j++) o[j] = (bf16)((float)cv[j] * e);
    *(bf16x8*)(Cs + l * 136 + nc) = o;
    *(bf16x8*)(BNs + l * 136 + nc) = *(const bf16x8*)(Bn + (row0 + l) * DS + nc);
  }
  const size_t xbase = (size_t)(b * NH + h) * HD * S_ + c * 64;
#pragma unroll
  for (int i = 0; i < 2; i++) {
    int cid = tid + i * 256; int p = cid >> 3, sc = (cid & 7) * 8;
    bf16x8 xv = *(const bf16x8*)(Xt + xbase + (size_t)p * S_ + sc);
    f32x4 d0 = *(const f32x4*)(dt_c + abase + sc);
    f32x4 d1 = *(const f32x4*)(dt_c + abase + sc + 4);
    bf16x8 o;
#pragma unroll
    for (int j = 0; j < 4; j++) { o[j] = (bf16)((float)xv[j] * d0[j]); o[4 + j] = (bf16)((float)xv[4 + j] * d1[j]); }
    *(bf16x8*)(Xs + p * 72 + sc) = o;
  }
  __syncthreads();
  bf16x8 ca[4];
#pragma unroll
  for (int ks = 0; ks < 4; ks++) ca[ks] = *(const bf16x8*)(Cs + (w * 16 + fr) * 136 + ks * 32 + fq * 8);
  f32x4 cb[4] = {};
  for (int st = 0; st <= w; st++)
#pragma unroll
    for (int ks = 0; ks < 4; ks++)
      cb[st] = __builtin_amdgcn_mfma_f32_16x16x32_bf16(ca[ks],
                 *(const bf16x8*)(BNs + (st * 16 + fr) * 136 + ks * 32 + fq * 8), cb[st], 0, 0, 0);
#pragma unroll
  for (int st = 0; st < 4; st++) {
    float es = (st <= w) ? __expf(-acs[st * 16 + fr]) : 0.f;
#pragma unroll
    for (int r = 0; r < 4; r++) {
      int lloc = fq * 4 + r;
      float g = 0.f;
      if (st < w) g = cb[st][r] * es;
      else if (st == w) g = (lloc >= fr) ? cb[st][r] * es : 0.f;
      G[(w * 16 + lloc) * 72 + st * 16 + fr] = (bf16)g;
    }
  }
  f32x4 acc[4] = {};
  {
    bf16x8 ga0 = *(const bf16x8*)(G + (w * 16 + fr) * 72 + fq * 8);
    bf16x8 ga1 = *(const bf16x8*)(G + (w * 16 + fr) * 72 + 32 + fq * 8);
#pragma unroll
    for (int pt = 0; pt < 4; pt++) {
      acc[pt] = __builtin_amdgcn_mfma_f32_16x16x32_bf16(ga0,
                  *(const bf16x8*)(Xs + (pt * 16 + fr) * 72 + fq * 8), acc[pt], 0, 0, 0);
      acc[pt] = __builtin_amdgcn_mfma_f32_16x16x32_bf16(ga1,
                  *(const bf16x8*)(Xs + (pt * 16 + fr) * 72 + 32 + fq * 8), acc[pt], 0, 0, 0);
    }
  }
  __syncthreads();
  const bf16* stp = states + (size_t)bid * 8192;
#pragma unroll
  for (int i = 0; i < 4; i++) {
    int cid = tid + i * 256; int p = cid >> 4, nc = (cid & 15) * 8;
    *(bf16x8*)(BNs + p * 136 + nc) = *(const bf16x8*)(stp + (size_t)p * 128 + nc);
  }
  __syncthreads();
#pragma unroll
  for (int pt = 0; pt < 4; pt++)
#pragma unroll
    for (int ks = 0; ks < 4; ks++)
      acc[pt] = __builtin_amdgcn_mfma_f32_16x16x32_bf16(ca[ks],
                  *(const bf16x8*)(BNs + (pt * 16 + fr) * 136 + ks * 32 + fq * 8), acc[pt], 0, 0, 0);
  float dph = Dp[h];
#pragma unroll
  for (int pt = 0; pt < 4; pt++) {
    int p = pt * 16 + fr;
    size_t tb = (xbase + (size_t)p * S_) + w * 16 + fq * 4;
    bf16x4 xs4 = *(const bf16x4*)(Xt + tb);
    bf16x4 z4  = *(const bf16x4*)(Zt + tb);
#pragma unroll
    for (int r = 0; r < 4; r++) {
      int l = w * 16 + fq * 4 + r;
      float yv = acc[pt][r] + (float)xs4[r] * dph;
      float z = (float)z4[r];
      yv *= z / (1.f + __expf(-z));
      ybf[((row0 + l) * NH + h) * HD + p] = (bf16)yv;
    }
  }
}

// ---------------- MFMA flash attention: 128-row q-tile per block, head per block ----------------
#define KSTR 72
#define PSTR 72
__global__ __launch_bounds__(256) void attn_mfma(const bf16* __restrict__ q,
                                                 const bf16* __restrict__ k,
                                                 const bf16* __restrict__ vtr,
                                                 bf16* __restrict__ o) {
  __shared__ bf16 Ks[2][64 * KSTR];
  __shared__ bf16 Vs[2][64 * KSTR];
  __shared__ bf16 Pl[4][32 * PSTR];
  int qt = (gridDim.x - 1) - blockIdx.x;   // 0..15, big tiles first
  int h = blockIdx.y, b = blockIdx.z;
  int kvh = h >> 2;
  int tid = threadIdx.x, lane = tid & 63, w = tid >> 6;
  int fr = lane & 15, fq = lane >> 4;
  const float SC = 0.18033688011112042f;   // 0.125 * log2(e)
  const float M2 = 62.0f;
  int qbase = qt * 128 + w * 32;           // wave's first q row
  int qmaxw = qbase + 31;
  bf16x8 bq[2][2];
#pragma unroll
  for (int qc = 0; qc < 2; qc++)
#pragma unroll
    for (int ks = 0; ks < 2; ks++)
      bq[qc][ks] = *(const bf16x8*)(q + (size_t)(b * S_ + qbase + qc * 16 + fr) * (HATT * HD)
                                      + h * HD + ks * 32 + fq * 8);
  int sr = tid >> 3, sc8 = (tid & 7) * 8;
  const bf16* kg = k + ((size_t)(b * S_) + sr) * (KVH * HD) + kvh * HD + sc8;
  const bf16* vg = vtr + ((size_t)(b * KVH + kvh) * HD + sr) * S_ + sc8;
  bf16x8 krg0, krg1, vrg0, vrg1;
  {
    krg0 = *(const bf16x8*)(kg);
    krg1 = *(const bf16x8*)(kg + (size_t)32 * (KVH * HD));
    vrg0 = *(const bf16x8*)(vg);
    vrg1 = *(const bf16x8*)(vg + (size_t)32 * S_);
    *(bf16x8*)(&Ks[0][sr * KSTR + sc8]) = krg0;
    *(bf16x8*)(&Ks[0][(sr + 32) * KSTR + sc8]) = krg1;
    *(bf16x8*)(&Vs[0][sr * KSTR + sc8]) = vrg0;
    *(bf16x8*)(&Vs[0][(sr + 32) * KSTR + sc8]) = vrg1;
  }
  float lsum[2] = {0.f, 0.f};
  f32x4 yacc[2][4] = {};
  bf16* Plw = Pl[w];
  int nkt = 2 * qt + 2;
  for (int kt = 0; kt < nkt; kt++) {
    int cur = kt & 1;
    bool more = (kt + 1) < nkt;
    if (more) {
      const bf16* kp = kg + (size_t)(kt + 1) * 64 * (KVH * HD);
      const bf16* vp = vg + (size_t)(kt + 1) * 64;
      krg0 = *(const bf16x8*)(kp);
      krg1 = *(const bf16x8*)(kp + (size_t)32 * (KVH * HD));
      vrg0 = *(const bf16x8*)(vp);
      vrg1 = *(const bf16x8*)(vp + (size_t)32 * S_);
    }
    __syncthreads();
    if (kt * 64 <= qmaxw) {
#pragma unroll
      for (int mi = 0; mi < 4; mi++) {
        int s0 = kt * 64 + mi * 16;
        if (s0 > qmaxw) {
          bf16x4 zz = {};
#pragma unroll
          for (int qc = 0; qc < 2; qc++)
            *(bf16x4*)(Plw + (qc * 16 + fr) * PSTR + mi * 16 + fq * 4) = zz;
        } else {
          const bf16* krow = &Ks[cur][(mi * 16 + fr) * KSTR];
          bf16x8 ak0 = *(const bf16x8*)(krow + fq * 8);
          bf16x8 ak1 = *(const bf16x8*)(krow + 32 + fq * 8);
#pragma unroll
          for (int qc = 0; qc < 2; qc++) {
            f32x4 s = {};
            s = __builtin_amdgcn_mfma_f32_16x16x32_bf16(ak0, bq[qc][0], s, 0, 0, 0);
            s = __builtin_amdgcn_mfma_f32_16x16x32_bf16(ak1, bq[qc][1], s, 0, 0, 0);
            int qq = qbase + qc * 16 + fr;
            bf16x4 pk;
#pragma unroll
            for (int r = 0; r < 4; r++) {
              int sp = s0 + fq * 4 + r;
              float p = (sp <= qq) ? __builtin_amdgcn_exp2f(s[r] * SC - M2) : 0.f;
              lsum[qc] += p;
              pk[r] = (bf16)p;
            }
            *(bf16x4*)(Plw + (qc * 16 + fr) * PSTR + mi * 16 + fq * 4) = pk;
          }
        }
      }
#pragma unroll
      for (int ks2 = 0; ks2 < 2; ks2++) {
        bf16x8 bp[2];
#pragma unroll
        for (int qc = 0; qc < 2; qc++)
          bp[qc] = *(const bf16x8*)(Plw + (qc * 16 + fr) * PSTR + ks2 * 32 + fq * 8);
#pragma unroll
        for (int pi = 0; pi < 4; pi++) {
          bf16x8 av = *(const bf16x8*)(&Vs[cur][(pi * 16 + fr) * KSTR + ks2 * 32 + fq * 8]);
#pragma unroll
          for (int qc = 0; qc < 2; qc++)
            yacc[qc][pi] = __builtin_amdgcn_mfma_f32_16x16x32_bf16(av, bp[qc], yacc[qc][pi], 0, 0, 0);
        }
      }
    }
    if (more) {
      int nxt = cur ^ 1;
      *(bf16x8*)(&Ks[nxt][sr * KSTR + sc8]) = krg0;
      *(bf16x8*)(&Ks[nxt][(sr + 32) * KSTR + sc8]) = krg1;
      *(bf16x8*)(&Vs[nxt][sr * KSTR + sc8]) = vrg0;
      *(bf16x8*)(&Vs[nxt][(sr + 32) * KSTR + sc8]) = vrg1;
    }
  }
#pragma unroll
  for (int qc = 0; qc < 2; qc++) {
    lsum[qc] += __shfl_xor(lsum[qc], 16, 64);
    lsum[qc] += __shfl_xor(lsum[qc], 32, 64);
  }
#pragma unroll
  for (int qc = 0; qc < 2; qc++) {
    float inv = 1.f / lsum[qc];
    bf16* op = o + (size_t)(b * S_ + qbase + qc * 16 + fr) * (HATT * HD) + h * HD + fq * 4;
#pragma unroll
    for (int pi = 0; pi < 4; pi++) {
      bf16x4 ov;
#pragma unroll
      for (int r = 0; r < 4; r++) ov[r] = (bf16)(yacc[qc][pi][r] * inv);
      *(bf16x4*)(op + pi * 16) = ov;
    }
  }
}

// ---------------- workspace layout (byte offsets) ----------------
constexpr size_t OFF_WIN  = 0;                   // bf16 4480x1024
constexpr size_t OFF_WOUT = 9175040;             // bf16 1024x2048
constexpr size_t OFF_WQKV = 13369344;            // bf16 1536x1024 (q|k|v rows)
constexpr size_t OFF_WCP  = 16515072;            // bf16 1024x1024
constexpr size_t OFF_WFC  = 18612224;            // bf16 3072x1024
constexpr size_t OFF_WPR  = 24903680;            // bf16 1024x3072
constexpr size_t OFF_HBF  = 31195136;            // bf16 4096x1024
constexpr size_t OFF_BCDT = 39583744;            // bf16 4096x288
constexpr size_t OFF_XT   = 41943040;            // bf16 [b][h][p][sg]
constexpr size_t OFF_ZT   = 58720256;            // bf16 [b][h][p][sg]
constexpr size_t OFF_DTC  = 75497472;            // f32 [b][h][sg]
constexpr size_t OFF_DDC  = 76546048;            // f32
constexpr size_t OFF_ACC  = 77594624;            // f32
constexpr size_t OFF_T    = 78643200;            // f32 2048
constexpr size_t OFF_BN   = 78651392;            // bf16 4096x128
constexpr size_t OFF_CN   = 79699968;            // bf16 4096x128
constexpr size_t OFF_BTR  = 80748544;            // bf16 [b][n][sg]
constexpr size_t OFF_ST   = 81797120;            // bf16 2048x64x128 (33.5 MB)
constexpr size_t OFF_YBF  = 148905984;           // bf16 4096x2048
constexpr size_t OFF_X1   = 165683200;           // f32 4096x1024 (end 182,460,416)
// aliases (st region dead after ssd_out; Xt/Zt dead after ssd_out; ybf dead after out_proj)
constexpr size_t OFF_P    = OFF_ST;              // bf16 split-K partials (<= 25.2 MB)
constexpr size_t OFF_QB   = OFF_ST + 50331648;   // bf16 4096x1024
constexpr size_t OFF_KB   = OFF_ST + 58720256;   // bf16 4096x256
constexpr size_t OFF_VB   = OFF_ST + 60817408;   // bf16 4096x256
constexpr size_t OFF_VTR  = OFF_ST + 62914560;   // bf16 [b][kvh][p][sg] (end 146,821,120)
constexpr size_t OFF_Y2   = OFF_XT;              // bf16 4096x1024
constexpr size_t OFF_X2   = 50331648;            // f32 4096x1024 (in dead Xt/Zt space)
constexpr size_t OFF_MLP  = 132128768;           // bf16 4096x3072 (over dead regions)

extern "C" void kernel_launch(void* const* d_in, const int* in_sizes, int n_in,
                              void* d_out, int out_size, void* d_ws, size_t ws_size,
                              hipStream_t stream) {
  (void)in_sizes; (void)n_in; (void)out_size; (void)ws_size;
  const float* x        = (const float*)d_in[0];
  const float* mnorm_w  = (const float*)d_in[1];
  const float* in_w     = (const float*)d_in[2];
  const float* out_w    = (const float*)d_in[3];
  const float* Dp       = (const float*)d_in[4];
  const float* dt_bias  = (const float*)d_in[5];
  const float* A_log    = (const float*)d_in[6];
  const float* Bn_w     = (const float*)d_in[7];
  const float* Cn_w     = (const float*)d_in[8];
  const float* ln1_w    = (const float*)d_in[9];
  const float* ln1_b    = (const float*)d_in[10];
  const float* cq_w     = (const float*)d_in[11];
  const float* ck_w     = (const float*)d_in[12];
  const float* cv_w     = (const float*)d_in[13];
  const float* cproj_w  = (const float*)d_in[14];
  const float* q_gain   = (const float*)d_in[15];
  const float* ln2_w    = (const float*)d_in[16];
  const float* ln2_b    = (const float*)d_in[17];
  const float* fc_w     = (const float*)d_in[18];
  const float* proj_w   = (const float*)d_in[19];
  float* out = (float*)d_out;
  char* W8 = (char*)d_ws;

  bf16* w_in   = (bf16*)(W8 + OFF_WIN);
  bf16* w_out  = (bf16*)(W8 + OFF_WOUT);
  bf16* w_qkv  = (bf16*)(W8 + OFF_WQKV);
  bf16* w_cp   = (bf16*)(W8 + OFF_WCP);
  bf16* w_fc   = (bf16*)(W8 + OFF_WFC);
  bf16* w_pr   = (bf16*)(W8 + OFF_WPR);
  bf16* h_bf   = (bf16*)(W8 + OFF_HBF);
  bf16* bcdt   = (bf16*)(W8 + OFF_BCDT);
  bf16* Xt     = (bf16*)(W8 + OFF_XT);
  bf16* Zt     = (bf16*)(W8 + OFF_ZT);
  float* dt_c  = (float*)(W8 + OFF_DTC);
  float* ddc   = (float*)(W8 + OFF_DDC);
  float* ac_c  = (float*)(W8 + OFF_ACC);
  float* Tb    = (float*)(W8 + OFF_T);
  bf16* Bn     = (bf16*)(W8 + OFF_BN);
  bf16* Cn     = (bf16*)(W8 + OFF_CN);
  bf16* Btr    = (bf16*)(W8 + OFF_BTR);
  bf16* st     = (bf16*)(W8 + OFF_ST);
  bf16* ybf    = (bf16*)(W8 + OFF_YBF);
  float* x1    = (float*)(W8 + OFF_X1);
  bf16* Pbuf   = (bf16*)(W8 + OFF_P);
  bf16* qbf    = (bf16*)(W8 + OFF_QB);
  bf16* kbf    = (bf16*)(W8 + OFF_KB);
  bf16* vbf    = (bf16*)(W8 + OFF_VB);
  bf16* vtr    = (bf16*)(W8 + OFF_VTR);
  bf16* y2     = (bf16*)(W8 + OFF_Y2);
  float* x2    = (float*)(W8 + OFF_X2);
  bf16* mlp    = (bf16*)(W8 + OFF_MLP);

  // ---- weight casts (single launch; q/k/v cast into adjacent rows of w_qkv) ----
  CastArgs ca;
  ca.seg[0] = { in_w,    w_in,            4489216, 4587520, 0     };
  ca.seg[1] = { out_w,   w_out,           2097152, 2097152, 4480  };
  ca.seg[2] = { cq_w,    w_qkv,           1048576, 1048576, 6528  };
  ca.seg[3] = { ck_w,    w_qkv + 1048576,  262144,  262144, 7552  };
  ca.seg[4] = { cv_w,    w_qkv + 1310720,  262144,  262144, 7808  };
  ca.seg[5] = { cproj_w, w_cp,            1048576, 1048576, 8064  };
  ca.seg[6] = { fc_w,    w_fc,            3145728, 3145728, 9088  };
  ca.seg[7] = { proj_w,  w_pr,            3145728, 3145728, 12160 };
  castw_all<<<15232, 256, 0, stream>>>(ca);

  const size_t PS  = (size_t)ROWS * 1024;   // partial stride (elements) for N=1024 GEMMs

  // ---- mamba block ----
  rmsnorm_k<<<ROWS, 256, 0, stream>>>(x, mnorm_w, h_bf, D_);
  gemm_inproj<<<32 * 35, 256, 0, stream>>>(h_bf, w_in, Zt, Xt, bcdt);
  ssd_prep<<<B_ * NH * NC, 64, 0, stream>>>(bcdt, dt_bias, A_log, dt_c, ddc, ac_c, Tb);
  bc_norm<<<ROWS, 128, 0, stream>>>(bcdt, Bn_w, Cn_w, Bn, Cn);
  t64<<<2 * 2 * 32, 256, 0, stream>>>(Bn, Btr, 128, (size_t)2048 * 128, (size_t)128 * 2048, 2);
  ssd_states<<<B_ * NC * NH, 256, 0, stream>>>(Xt, Btr, ddc, st);
  ssd_scan<<<B_ * NH * 8, 256, 0, stream>>>(st, Tb);
  ssd_out<<<B_ * NC * NH, 256, 0, stream>>>(Cn, Bn, Xt, Zt, dt_c, ac_c, st, Dp, ybf);
  // out_proj: split-K=2 then fused reduce+residual+LN1
  gemm_sk<<<dim3(32 * 8, 1, 2), 256, 0, stream>>>(ybf, w_out, Pbuf, ROWS, D_, DI, 1024);
  reduce_ln2<<<ROWS, 256, 0, stream>>>(Pbuf, Pbuf + PS, x, ln1_w, ln1_b, x1, h_bf);

  // ---- attention block ----
  gemm_sk<<<dim3(32 * 12, 1, 2), 256, 0, stream>>>(h_bf, w_qkv, Pbuf, ROWS, 1536, D_, 512);
  reduce_qkv<<<ROWS, 256, 0, stream>>>(Pbuf, q_gain, qbf, kbf, vbf);
  t64<<<2 * 4 * 32, 256, 0, stream>>>(vbf, vtr, 256, (size_t)2048 * 256, (size_t)256 * 2048, 4);
  attn_mfma<<<dim3(S_ / 128, HATT, B_), 256, 0, stream>>>(qbf, kbf, vtr, y2);
  gemm_sk<<<dim3(32 * 8, 1, 2), 256, 0, stream>>>(y2, w_cp, Pbuf, ROWS, D_, D_, 512);
  reduce_ln2<<<ROWS, 256, 0, stream>>>(Pbuf, Pbuf + PS, x1, ln2_w, ln2_b, x2, h_bf);

  // ---- MLP ----
  gemm_mfma<1, bf16><<<32 * 24, 256, 0, stream>>>(h_bf, w_fc, nullptr, mlp, ROWS, MLP, D_);
  gemm_sk<<<dim3(32 * 8, 1, 3), 256, 0, stream>>>(mlp, w_pr, Pbuf, ROWS, D_, MLP, 1024);
  reduce_out3<<<ROWS, 256, 0, stream>>>(Pbuf, Pbuf + PS, Pbuf + 2 * PS, x2, out);
}

// Round 9
// 535.023 us; speedup vs baseline: 1.3865x; 1.0001x over previous
//
#include <hip/hip_runtime.h>
#include <hip/hip_bf16.h>
#include <math.h>

// ---------------- problem constants ----------------
#define B_    2
#define S_    2048
#define D_    1024
#define DI    2048      // D_INNER
#define NH    32        // NHEADS (mamba)
#define HD    64        // HEADDIM
#define DS    128       // D_STATE
#define CH    64        // CHUNK
#define NC    32        // S_/CH
#define DP    4384      // D_PROJ
#define HATT  16        // attention heads
#define KVH   4         // kv heads
#define RD    16        // rope dims
#define MLP   3072
#define ROWS  (B_*S_)   // 4096

typedef __bf16 bf16;
typedef __bf16 bf16x8 __attribute__((ext_vector_type(8)));
typedef __bf16 bf16x4 __attribute__((ext_vector_type(4)));
typedef float  f32x4  __attribute__((ext_vector_type(4)));

__device__ __forceinline__ void async_copy16(const void* g, void* l) {
  __builtin_amdgcn_global_load_lds(
      (const __attribute__((address_space(1))) unsigned int*)g,
      (__attribute__((address_space(3))) unsigned int*)l, 16, 0, 0);
}

// ---------------- reductions ----------------
__device__ __forceinline__ float waveReduceSum(float v) {
#pragma unroll
  for (int off = 32; off > 0; off >>= 1) v += __shfl_down(v, off, 64);
  return v;
}

template<int NW>
__device__ __forceinline__ float blockReduceSum(float v, float* sh) {
  v = waveReduceSum(v);
  int lane = threadIdx.x & 63, wid = threadIdx.x >> 6;
  if (lane == 0) sh[wid] = v;
  __syncthreads();
  float s = 0.f;
#pragma unroll
  for (int i = 0; i < NW; i++) s += sh[i];
  __syncthreads();
  return s;
}

// ---------------- merged weight cast f32 -> bf16 ----------------
struct CastSeg { const float* src; bf16* dst; int nval; int ntot; int blk0; };
struct CastArgs { CastSeg seg[8]; };

__global__ __launch_bounds__(256) void castw_all(CastArgs a) {
  int blk = blockIdx.x;
  int si = 0;
#pragma unroll
  for (int i = 1; i < 8; i++) if (blk >= a.seg[i].blk0) si = i;
  CastSeg s = a.seg[si];
  int i = ((blk - s.blk0) * 256 + threadIdx.x) * 4;
  if (i >= s.ntot) return;
  float4 v = {0.f, 0.f, 0.f, 0.f};
  if (i < s.nval) v = *(const float4*)(s.src + i);
  bf16x4 o;
  o[0] = (bf16)v.x; o[1] = (bf16)v.y; o[2] = (bf16)v.z; o[3] = (bf16)v.w;
  *(bf16x4*)(s.dst + i) = o;
}

// ---------------- rmsnorm (f32 in, bf16 out) ----------------
__global__ __launch_bounds__(256) void rmsnorm_k(const float* __restrict__ x,
                                                 const float* __restrict__ w,
                                                 bf16* __restrict__ y, int n) {
  __shared__ float sh[4];
  size_t row = blockIdx.x;
  const float* xr = x + row * n;
  bf16* yr = y + row * n;
  float ss = 0.f;
  for (int i = threadIdx.x; i < n; i += 256) { float v = xr[i]; ss += v * v; }
  ss = blockReduceSum<4>(ss, sh);
  float inv = rsqrtf(ss / n + 1e-5f);
  for (int i = threadIdx.x; i < n; i += 256) yr[i] = (bf16)(xr[i] * inv * w[i]);
}

// ---------------- generic bf16 MFMA GEMM: C = act(A @ W^T), bm-fastest 1D grid ----------------
template<int ACT, typename OT>
__global__ __launch_bounds__(256) void gemm_mfma(const bf16* __restrict__ A,
                                                 const bf16* __restrict__ W,
                                                 const float* __restrict__ R,
                                                 OT* __restrict__ C,
                                                 int M, int N, int K) {
  __shared__ bf16 As[128 * 32];
  __shared__ bf16 Ws[128 * 32];
  int tid = threadIdx.x, lane = tid & 63, wave = tid >> 6;
  int mt = M >> 7;
  int bid = blockIdx.x;
  int bm = (bid % mt) * 128, bn = (bid / mt) * 128;
  const bf16* gA0 = A + (size_t)(bm + wave * 32 + (lane >> 2)) * K + (lane & 3) * 8;
  const bf16* gA1 = gA0 + (size_t)16 * K;
  const bf16* gW0 = W + (size_t)(bn + wave * 32 + (lane >> 2)) * K + (lane & 3) * 8;
  const bf16* gW1 = gW0 + (size_t)16 * K;
  bf16* lA0 = As + wave * 32 * 32;
  bf16* lA1 = lA0 + 16 * 32;
  bf16* lW0 = Ws + wave * 32 * 32;
  bf16* lW1 = lW0 + 16 * 32;
  int fr = lane & 15, fq = lane >> 4;
  int wm = wave >> 1, wn = wave & 1;
  const bf16* pA = As + (wm * 64 + fr) * 32 + fq * 8;
  const bf16* pW = Ws + (wn * 64 + fr) * 32 + fq * 8;
  f32x4 acc[4][4] = {};
  for (int k0 = 0; k0 < K; k0 += 32) {
    async_copy16(gA0, lA0);
    async_copy16(gA1, lA1);
    async_copy16(gW0, lW0);
    async_copy16(gW1, lW1);
    gA0 += 32; gA1 += 32; gW0 += 32; gW1 += 32;
    __syncthreads();
    bf16x8 af[4], bfr[4];
#pragma unroll
    for (int mi = 0; mi < 4; mi++) af[mi] = *(const bf16x8*)(pA + mi * 16 * 32);
#pragma unroll
    for (int ni = 0; ni < 4; ni++) bfr[ni] = *(const bf16x8*)(pW + ni * 16 * 32);
#pragma unroll
    for (int mi = 0; mi < 4; mi++)
#pragma unroll
      for (int ni = 0; ni < 4; ni++)
        acc[mi][ni] = __builtin_amdgcn_mfma_f32_16x16x32_bf16(af[mi], bfr[ni], acc[mi][ni], 0, 0, 0);
    __syncthreads();
  }
#pragma unroll
  for (int mi = 0; mi < 4; mi++) {
    int row = bm + wm * 64 + mi * 16 + fq * 4;
#pragma unroll
    for (int ni = 0; ni < 4; ni++) {
      int col = bn + wn * 64 + ni * 16 + fr;
      if (col < N) {
#pragma unroll
        for (int r = 0; r < 4; r++) {
          float v = acc[mi][ni][r];
          if (ACT == 1) v = v / (1.f + __expf(-v));
          if (R) v += R[(size_t)(row + r) * N + col];
          C[(size_t)(row + r) * N + col] = (OT)v;
        }
      }
    }
  }
}

// ---------------- split-K bf16 MFMA GEMM: P[ks] = A @ W^T (bf16 partials) ----------------
__global__ __launch_bounds__(256) void gemm_sk(const bf16* __restrict__ A,
                                               const bf16* __restrict__ W,
                                               bf16* __restrict__ P,
                                               int M, int N, int K, int kchunk) {
  __shared__ bf16 As[128 * 32];
  __shared__ bf16 Ws[128 * 32];
  int tid = threadIdx.x, lane = tid & 63, wave = tid >> 6;
  int mt = M >> 7;
  int bid = blockIdx.x;
  int bm = (bid % mt) * 128, bn = (bid / mt) * 128;
  int ks = blockIdx.z;
  int kbeg = ks * kchunk;
  const bf16* gA0 = A + (size_t)(bm + wave * 32 + (lane >> 2)) * K + kbeg + (lane & 3) * 8;
  const bf16* gA1 = gA0 + (size_t)16 * K;
  const bf16* gW0 = W + (size_t)(bn + wave * 32 + (lane >> 2)) * K + kbeg + (lane & 3) * 8;
  const bf16* gW1 = gW0 + (size_t)16 * K;
  bf16* lA0 = As + wave * 32 * 32;
  bf16* lA1 = lA0 + 16 * 32;
  bf16* lW0 = Ws + wave * 32 * 32;
  bf16* lW1 = lW0 + 16 * 32;
  int fr = lane & 15, fq = lane >> 4;
  int wm = wave >> 1, wn = wave & 1;
  const bf16* pA = As + (wm * 64 + fr) * 32 + fq * 8;
  const bf16* pW = Ws + (wn * 64 + fr) * 32 + fq * 8;
  f32x4 acc[4][4] = {};
  for (int k0 = 0; k0 < kchunk; k0 += 32) {
    async_copy16(gA0, lA0);
    async_copy16(gA1, lA1);
    async_copy16(gW0, lW0);
    async_copy16(gW1, lW1);
    gA0 += 32; gA1 += 32; gW0 += 32; gW1 += 32;
    __syncthreads();
    bf16x8 af[4], bfr[4];
#pragma unroll
    for (int mi = 0; mi < 4; mi++) af[mi] = *(const bf16x8*)(pA + mi * 16 * 32);
#pragma unroll
    for (int ni = 0; ni < 4; ni++) bfr[ni] = *(const bf16x8*)(pW + ni * 16 * 32);
#pragma unroll
    for (int mi = 0; mi < 4; mi++)
#pragma unroll
      for (int ni = 0; ni < 4; ni++)
        acc[mi][ni] = __builtin_amdgcn_mfma_f32_16x16x32_bf16(af[mi], bfr[ni], acc[mi][ni], 0, 0, 0);
    __syncthreads();
  }
  bf16* Pp = P + (size_t)ks * M * N;
#pragma unroll
  for (int mi = 0; mi < 4; mi++) {
    int row = bm + wm * 64 + mi * 16 + fq * 4;
#pragma unroll
    for (int ni = 0; ni < 4; ni++) {
      int col = bn + wn * 64 + ni * 16 + fr;
#pragma unroll
      for (int r = 0; r < 4; r++)
        Pp[(size_t)(row + r) * N + col] = (bf16)acc[mi][ni][r];
    }
  }
}

// ---------------- reduce 2 bf16 partials + residual + layernorm -> x_out f32, h bf16 ----------------
__global__ __launch_bounds__(256) void reduce_ln2(const bf16* __restrict__ p0,
                                                  const bf16* __restrict__ p1,
                                                  const float* __restrict__ res,
                                                  const float* __restrict__ w,
                                                  const float* __restrict__ b,
                                                  float* __restrict__ xo,
                                                  bf16* __restrict__ ho) {
  __shared__ float sh[4];
  size_t o = (size_t)blockIdx.x * 1024;
  int i = threadIdx.x * 4;
  bf16x4 a = *(const bf16x4*)(p0 + o + i);
  bf16x4 c = *(const bf16x4*)(p1 + o + i);
  f32x4 rv = *(const f32x4*)(res + o + i);
  f32x4 v;
  float s = 0.f, s2 = 0.f;
#pragma unroll
  for (int j = 0; j < 4; j++) {
    v[j] = (float)a[j] + (float)c[j] + rv[j];
    s += v[j]; s2 += v[j] * v[j];
  }
  s  = blockReduceSum<4>(s,  sh);
  s2 = blockReduceSum<4>(s2, sh);
  float mean = s / 1024.f;
  float var  = s2 / 1024.f - mean * mean;
  float inv  = rsqrtf(var + 1e-5f);
  f32x4 wv = *(const f32x4*)(w + i);
  f32x4 bv = *(const f32x4*)(b + i);
  *(f32x4*)(xo + o + i) = v;
  bf16x4 hv;
#pragma unroll
  for (int j = 0; j < 4; j++) hv[j] = (bf16)((v[j] - mean) * inv * wv[j] + bv[j]);
  *(bf16x4*)(ho + o + i) = hv;
}

// ---------------- reduce 3 bf16 partials + residual -> out f32 ----------------
__global__ __launch_bounds__(256) void reduce_out3(const bf16* __restrict__ p0,
                                                   const bf16* __restrict__ p1,
                                                   const bf16* __restrict__ p2,
                                                   const float* __restrict__ res,
                                                   float* __restrict__ out) {
  int i = (blockIdx.x * 256 + threadIdx.x) * 4;
  bf16x4 a = *(const bf16x4*)(p0 + i);
  bf16x4 c = *(const bf16x4*)(p1 + i);
  bf16x4 d = *(const bf16x4*)(p2 + i);
  f32x4 v = *(const f32x4*)(res + i);
#pragma unroll
  for (int j = 0; j < 4; j++) v[j] += (float)a[j] + (float)c[j] + (float)d[j];
  *(f32x4*)(out + i) = v;
}

// ---------------- reduce qkv bf16 partials + q/k rmsnorm + rope + gain -> bf16 ----------------
__global__ __launch_bounds__(256) void reduce_qkv(const bf16* __restrict__ P,
                                                  const float* __restrict__ q_gain,
                                                  bf16* __restrict__ q,
                                                  bf16* __restrict__ k,
                                                  bf16* __restrict__ v) {
  __shared__ float buf[1536];
  size_t row = blockIdx.x;
  size_t o = row * 1536;
  const bf16* p0 = P + o;
  const bf16* p1 = P + (size_t)ROWS * 1536 + o;
  int tid = threadIdx.x;
  for (int i = tid; i < 384; i += 256) {
    bf16x4 a = *(const bf16x4*)(p0 + i * 4);
    bf16x4 c = *(const bf16x4*)(p1 + i * 4);
    f32x4 vv;
#pragma unroll
    for (int j = 0; j < 4; j++) vv[j] = (float)a[j] + (float)c[j];
    *(f32x4*)(buf + i * 4) = vv;
  }
  __syncthreads();
  int lane = tid & 63, w = tid >> 6;
  int s = (int)(row & (S_ - 1));
  int ri = lane & 7;
  float rinv = __expf(-(float)ri * (0.125f * 9.210340371976184f)); // 10000^(-i/8)
  float ang = (float)s * rinv;
  float cs = cosf(ang), sn = sinf(ang);
#pragma unroll
  for (int j = 0; j < 6; j++) {
    int hh = w * 6 + j;
    float val = buf[hh * 64 + lane];
    if (hh < 20) {
      float ss = val * val;
#pragma unroll
      for (int off = 32; off > 0; off >>= 1) ss += __shfl_xor(ss, off, 64);
      val *= rsqrtf(ss / 64.f + 1.1920929e-7f);
      float other = __shfl_xor(val, 8, 64);
      float res = val;
      if (lane < RD) res = (lane < 8) ? (val * cs + other * sn) : (val * cs - other * sn);
      if (hh < 16) {
        res *= q_gain[hh];
        q[row * (HATT * HD) + hh * HD + lane] = (bf16)res;
      } else {
        k[row * (KVH * HD) + (hh - 16) * HD + lane] = (bf16)res;
      }
    } else {
      v[row * (KVH * HD) + (hh - 20) * HD + lane] = (bf16)val;
    }
  }
}

// ---------------- in_proj GEMM: writes Zt/Xt transposed + compact bcdt (bm-fastest) ----------------
__global__ __launch_bounds__(256) void gemm_inproj(const bf16* __restrict__ A,
                                                   const bf16* __restrict__ W,
                                                   bf16* __restrict__ zt,
                                                   bf16* __restrict__ xt,
                                                   bf16* __restrict__ bcdt) {
  const int K = 1024;
  __shared__ bf16 As[128 * 32];
  __shared__ bf16 Ws[128 * 32];
  int tid = threadIdx.x, lane = tid & 63, wave = tid >> 6;
  int bid = blockIdx.x;
  int bm = (bid & 31) * 128, bn = (bid >> 5) * 128;
  const bf16* gA0 = A + (size_t)(bm + wave * 32 + (lane >> 2)) * K + (lane & 3) * 8;
  const bf16* gA1 = gA0 + (size_t)16 * K;
  const bf16* gW0 = W + (size_t)(bn + wave * 32 + (lane >> 2)) * K + (lane & 3) * 8;
  const bf16* gW1 = gW0 + (size_t)16 * K;
  bf16* lA0 = As + wave * 32 * 32;
  bf16* lA1 = lA0 + 16 * 32;
  bf16* lW0 = Ws + wave * 32 * 32;
  bf16* lW1 = lW0 + 16 * 32;
  int fr = lane & 15, fq = lane >> 4;
  int wm = wave >> 1, wn = wave & 1;
  const bf16* pA = As + (wm * 64 + fr) * 32 + fq * 8;
  const bf16* pW = Ws + (wn * 64 + fr) * 32 + fq * 8;
  f32x4 acc[4][4] = {};
  for (int k0 = 0; k0 < K; k0 += 32) {
    async_copy16(gA0, lA0);
    async_copy16(gA1, lA1);
    async_copy16(gW0, lW0);
    async_copy16(gW1, lW1);
    gA0 += 32; gA1 += 32; gW0 += 32; gW1 += 32;
    __syncthreads();
    bf16x8 af[4], bfr[4];
#pragma unroll
    for (int mi = 0; mi < 4; mi++) af[mi] = *(const bf16x8*)(pA + mi * 16 * 32);
#pragma unroll
    for (int ni = 0; ni < 4; ni++) bfr[ni] = *(const bf16x8*)(pW + ni * 16 * 32);
#pragma unroll
    for (int mi = 0; mi < 4; mi++)
#pragma unroll
      for (int ni = 0; ni < 4; ni++)
        acc[mi][ni] = __builtin_amdgcn_mfma_f32_16x16x32_bf16(af[mi], bfr[ni], acc[mi][ni], 0, 0, 0);
    __syncthreads();
  }
#pragma unroll
  for (int mi = 0; mi < 4; mi++) {
    int row0m = bm + wm * 64 + mi * 16 + fq * 4;
    int b = row0m >> 11, sg = row0m & 2047;
#pragma unroll
    for (int ni = 0; ni < 4; ni++) {
      int col = bn + wn * 64 + ni * 16 + fr;
      bf16x4 o;
#pragma unroll
      for (int r = 0; r < 4; r++) o[r] = (bf16)acc[mi][ni][r];
      if (col < 2048) {
        *(bf16x4*)(zt + ((size_t)(b * NH + (col >> 6)) * HD + (col & 63)) * S_ + sg) = o;
      } else if (col < 4096) {
        int xc = col - 2048;
        *(bf16x4*)(xt + ((size_t)(b * NH + (xc >> 6)) * HD + (xc & 63)) * S_ + sg) = o;
      } else if (col < 4384) {
#pragma unroll
        for (int r = 0; r < 4; r++)
          bcdt[(size_t)(row0m + r) * 288 + (col - 4096)] = o[r];
      }
    }
  }
}

// ---------------- generic 64x64 tiled transpose (bf16), out row stride 2048 ----------------
__global__ __launch_bounds__(256) void t64(const bf16* __restrict__ in, bf16* __restrict__ out,
                                           int istr, size_t io, size_t oo, int n_nt) {
  __shared__ bf16 T[64 * 72];
  int bid = blockIdx.x;
  int st = bid & 31;
  int nt = (bid >> 5) % n_nt;
  int outer = bid / (32 * n_nt);
  const bf16* ip = in + outer * io + (size_t)st * 64 * istr + nt * 64;
  int tid = threadIdx.x;
#pragma unroll
  for (int i = 0; i < 2; i++) {
    int cid = tid + i * 256; int s = cid >> 3, pc = (cid & 7) * 8;
    *(bf16x8*)(T + s * 72 + pc) = *(const bf16x8*)(ip + (size_t)s * istr + pc);
  }
  __syncthreads();
  bf16* op = out + outer * oo + (size_t)nt * 64 * 2048 + st * 64;
#pragma unroll
  for (int i = 0; i < 2; i++) {
    int cid = tid + i * 256; int p = cid >> 3, sc = (cid & 7) * 8;
    bf16x8 o;
#pragma unroll
    for (int j = 0; j < 8; j++) o[j] = T[(sc + j) * 72 + p];
    *(bf16x8*)(op + (size_t)p * 2048 + sc) = o;
  }
}

// ---------------- SSD prep: dt softplus, per-chunk cumsum, decay factors ----------------
__global__ __launch_bounds__(64) void ssd_prep(const bf16* __restrict__ bcdt,
                                               const float* __restrict__ dt_bias,
                                               const float* __restrict__ A_log,
                                               float* __restrict__ dt_c,
                                               float* __restrict__ ddc,
                                               float* __restrict__ ac_c,
                                               float* __restrict__ T_out) {
  int bid = blockIdx.x;
  int c = bid % NC, hh = (bid / NC) % NH, b = bid / (NC * NH);
  int l = threadIdx.x;
  size_t row = (size_t)b * S_ + c * 64 + l;
  float raw = (float)bcdt[row * 288 + 256 + hh] + dt_bias[hh];
  float dtv = (raw > 20.f) ? raw : log1pf(__expf(raw));
  float a = -__expf(A_log[hh]) * dtv;
  float ps = a;
#pragma unroll
  for (int off = 1; off < 64; off <<= 1) {
    float t = __shfl_up(ps, off, 64);
    if (l >= off) ps += t;
  }
  float a63 = __shfl(ps, 63, 64);
  size_t o = ((size_t)b * NH + hh) * S_ + c * 64 + l;
  dt_c[o] = dtv;
  ac_c[o] = ps;
  ddc[o] = __expf(a63 - ps) * dtv;
  if (l == 63) T_out[(b * NH + hh) * NC + c] = ps;
}

// ---------------- B/C rmsnorm (bf16 out) ----------------
__global__ __launch_bounds__(128) void bc_norm(const bf16* __restrict__ bcdt,
                                               const float* __restrict__ Bw,
                                               const float* __restrict__ Cw,
                                               bf16* __restrict__ Bn,
                                               bf16* __restrict__ Cn) {
  __shared__ float shb[2], shc[2];
  size_t row = blockIdx.x;
  int i = threadIdx.x;
  float bv = (float)bcdt[row * 288 + i];
  float cv = (float)bcdt[row * 288 + 128 + i];
  float sb = waveReduceSum(bv * bv);
  float sc = waveReduceSum(cv * cv);
  int lane = threadIdx.x & 63, wid = threadIdx.x >> 6;
  if (lane == 0) { shb[wid] = sb; shc[wid] = sc; }
  __syncthreads();
  float tb = shb[0] + shb[1];
  float tc = shc[0] + shc[1];
  Bn[row * DS + i] = (bf16)(bv * rsqrtf(tb / DS + 1e-5f) * Bw[i]);
  Cn[row * DS + i] = (bf16)(cv * rsqrtf(tc / DS + 1e-5f) * Cw[i]);
}

// ---------------- chunk states via MFMA (bf16 output) ----------------
__global__ __launch_bounds__(256) void ssd_states(const bf16* __restrict__ Xt,
                                                  const bf16* __restrict__ Btr,
                                                  const float* __restrict__ ddc,
                                                  bf16* __restrict__ states) {
  __shared__ bf16 Xs[64 * 72];    // [p][s]
  __shared__ bf16 Bs[128 * 72];   // [n][s]
  int bid = blockIdx.x;           // (b*NC + c)*NH + h
  int h = bid % NH;
  int c = (bid / NH) % NC;
  int b = bid / (NH * NC);
  int tid = threadIdx.x, lane = tid & 63, w = tid >> 6;
  int fr = lane & 15, fq = lane >> 4;
  const size_t xbase = (size_t)(b * NH + h) * HD * S_ + c * 64;
  const size_t dbase = (size_t)(b * NH + h) * S_ + c * 64;
#pragma unroll
  for (int i = 0; i < 2; i++) {
    int cid = tid + i * 256; int p = cid >> 3, sc = (cid & 7) * 8;
    bf16x8 xv = *(const bf16x8*)(Xt + xbase + (size_t)p * S_ + sc);
    f32x4 d0 = *(const f32x4*)(ddc + dbase + sc);
    f32x4 d1 = *(const f32x4*)(ddc + dbase + sc + 4);
    bf16x8 o;
#pragma unroll
    for (int j = 0; j < 4; j++) { o[j] = (bf16)((float)xv[j] * d0[j]); o[4 + j] = (bf16)((float)xv[4 + j] * d1[j]); }
    *(bf16x8*)(Xs + p * 72 + sc) = o;
  }
  const size_t bbase = (size_t)b * 128 * S_ + c * 64;
#pragma unroll
  for (int i = 0; i < 4; i++) {
    int cid = tid + i * 256; int n = cid >> 3, sc = (cid & 7) * 8;
    *(bf16x8*)(Bs + n * 72 + sc) = *(const bf16x8*)(Btr + bbase + (size_t)n * S_ + sc);
  }
  __syncthreads();
  f32x4 acc[4][2] = {};
#pragma unroll
  for (int ks = 0; ks < 2; ks++) {
    bf16x8 a[4], bb[2];
#pragma unroll
    for (int pt = 0; pt < 4; pt++) a[pt] = *(const bf16x8*)(Xs + (pt * 16 + fr) * 72 + ks * 32 + fq * 8);
#pragma unroll
    for (int n2 = 0; n2 < 2; n2++) bb[n2] = *(const bf16x8*)(Bs + ((2 * w + n2) * 16 + fr) * 72 + ks * 32 + fq * 8);
#pragma unroll
    for (int pt = 0; pt < 4; pt++)
#pragma unroll
      for (int n2 = 0; n2 < 2; n2++)
        acc[pt][n2] = __builtin_amdgcn_mfma_f32_16x16x32_bf16(a[pt], bb[n2], acc[pt][n2], 0, 0, 0);
  }
  bf16* outp = states + (size_t)bid * 8192;
#pragma unroll
  for (int pt = 0; pt < 4; pt++)
#pragma unroll
    for (int n2 = 0; n2 < 2; n2++) {
      int n = (2 * w + n2) * 16 + fr;
#pragma unroll
      for (int r = 0; r < 4; r++)
        outp[(size_t)(pt * 16 + fq * 4 + r) * 128 + n] = (bf16)acc[pt][n2][r];
    }
}

// ---------------- inter-chunk scan (in place, bf16 storage, f32 math) ----------------
__global__ __launch_bounds__(256) void ssd_scan(bf16* __restrict__ states,
                                                const float* __restrict__ T) {
  __shared__ float eT[NC];
  int part = blockIdx.x & 7;
  int bh = blockIdx.x >> 3;
  int b = bh / NH, h = bh % NH;
  if (threadIdx.x < NC) eT[threadIdx.x] = __expf(T[(size_t)(b * NH + h) * NC + threadIdx.x]);
  __syncthreads();
  const size_t cstride = (size_t)NH * HD * DS;
  size_t base = ((size_t)b * NC * NH + h) * (HD * DS);
#pragma unroll
  for (int j = 0; j < 4; j++) {
    int e = part * 1024 + threadIdx.x + j * 256;
    float carry = 0.f;
    size_t idx = base + e;
    for (int c = 0; c < NC; c++) {
      float sv = (float)states[idx];
      states[idx] = (bf16)carry;
      carry = sv + eT[c] * carry;
      idx += cstride;
    }
  }
}

// ---------------- fused SSD output: Ydiag + Yoff + D-skip + gate (all MFMA) ----------------
__global__ __launch_bounds__(256) void ssd_out(const bf16* __restrict__ Cn,
                                               const bf16* __restrict__ Bn,
                                               const bf16* __restrict__ Xt,
                                               const bf16* __restrict__ Zt,
                                               const float* __restrict__ dt_c,
                                               const float* __restrict__ ac_c,
                                               const bf16* __restrict__ states,
                                               const float* __restrict__ Dp,
                                               bf16* __restrict__ ybf) {
  __shared__ bf16 Cs[64 * 136];
  __shared__ bf16 BNs[64 * 136];
  __shared__ bf16 Xs[64 * 72];
  __shared__ bf16 G[64 * 72];
  __shared__ float acs[64];
  int bid = blockIdx.x;
  int h = bid % NH;
  int c = (bid / NH) % NC;
  int b = bid / (NH * NC);
  int tid = threadIdx.x, lane = tid & 63, w = tid >> 6;
  int fr = lane & 15, fq = lane >> 4;
  size_t row0 = (size_t)b * S_ + c * 64;
  const size_t abase = (size_t)(b * NH + h) * S_ + c * 64;
  if (tid < 64) acs[tid] = ac_c[abase + tid];
#pragma unroll
  for (int i = 0; i < 4; i++) {
    int cid = tid + i * 256; int l = cid >> 4, nc = (cid & 15) * 8;
    float e = __expf(ac_c[abase + l]);
    bf16x8 cv = *(const bf16x8*)(Cn + (row0 + l) * DS + nc);
    bf16x8 o;
#pragma unroll
    for (int j = 0; j < 8; j++) o[j] = (bf16)((float)cv[j] * e);
    *(bf16x8*)(Cs + l * 136 + nc) = o;
    *(bf16x8*)(BNs + l * 136 + nc) = *(const bf16x8*)(Bn + (row0 + l) * DS + nc);
  }
  const size_t xbase = (size_t)(b * NH + h) * HD * S_ + c * 64;
#pragma unroll
  for (int i = 0; i < 2; i++) {
    int cid = tid + i * 256; int p = cid >> 3, sc = (cid & 7) * 8;
    bf16x8 xv = *(const bf16x8*)(Xt + xbase + (size_t)p * S_ + sc);
    f32x4 d0 = *(const f32x4*)(dt_c + abase + sc);
    f32x4 d1 = *(const f32x4*)(dt_c + abase + sc + 4);
    bf16x8 o;
#pragma unroll
    for (int j = 0; j < 4; j++) { o[j] = (bf16)((float)xv[j] * d0[j]); o[4 + j] = (bf16)((float)xv[4 + j] * d1[j]); }
    *(bf16x8*)(Xs + p * 72 + sc) = o;
  }
  __syncthreads();
  bf16x8 ca[4];
#pragma unroll
  for (int ks = 0; ks < 4; ks++) ca[ks] = *(const bf16x8*)(Cs + (w * 16 + fr) * 136 + ks * 32 + fq * 8);
  f32x4 cb[4] = {};
  for (int st = 0; st <= w; st++)
#pragma unroll
    for (int ks = 0; ks < 4; ks++)
      cb[st] = __builtin_amdgcn_mfma_f32_16x16x32_bf16(ca[ks],
                 *(const bf16x8*)(BNs + (st * 16 + fr) * 136 + ks * 32 + fq * 8), cb[st], 0, 0, 0);
#pragma unroll
  for (int st = 0; st < 4; st++) {
    float es = (st <= w) ? __expf(-acs[st * 16 + fr]) : 0.f;
#pragma unroll
    for (int r = 0; r < 4; r++) {
      int lloc = fq * 4 + r;
      float g = 0.f;
      if (st < w) g = cb[st][r] * es;
      else if (st == w) g = (lloc >= fr) ? cb[st][r] * es : 0.f;
      G[(w * 16 + lloc) * 72 + st * 16 + fr] = (bf16)g;
    }
  }
  f32x4 acc[4] = {};
  {
    bf16x8 ga0 = *(const bf16x8*)(G + (w * 16 + fr) * 72 + fq * 8);
    bf16x8 ga1 = *(const bf16x8*)(G + (w * 16 + fr) * 72 + 32 + fq * 8);
#pragma unroll
    for (int pt = 0; pt < 4; pt++) {
      acc[pt] = __builtin_amdgcn_mfma_f32_16x16x32_bf16(ga0,
                  *(const bf16x8*)(Xs + (pt * 16 + fr) * 72 + fq * 8), acc[pt], 0, 0, 0);
      acc[pt] = __builtin_amdgcn_mfma_f32_16x16x32_bf16(ga1,
                  *(const bf16x8*)(Xs + (pt * 16 + fr) * 72 + 32 + fq * 8), acc[pt], 0, 0, 0);
    }
  }
  __syncthreads();
  const bf16* stp = states + (size_t)bid * 8192;
#pragma unroll
  for (int i = 0; i < 4; i++) {
    int cid = tid + i * 256; int p = cid >> 4, nc = (cid & 15) * 8;
    *(bf16x8*)(BNs + p * 136 + nc) = *(const bf16x8*)(stp + (size_t)p * 128 + nc);
  }
  __syncthreads();
#pragma unroll
  for (int pt = 0; pt < 4; pt++)
#pragma unroll
    for (int ks = 0; ks < 4; ks++)
      acc[pt] = __builtin_amdgcn_mfma_f32_16x16x32_bf16(ca[ks],
                  *(const bf16x8*)(BNs + (pt * 16 + fr) * 136 + ks * 32 + fq * 8), acc[pt], 0, 0, 0);
  float dph = Dp[h];
#pragma unroll
  for (int pt = 0; pt < 4; pt++) {
    int p = pt * 16 + fr;
    size_t tb = (xbase + (size_t)p * S_) + w * 16 + fq * 4;
    bf16x4 xs4 = *(const bf16x4*)(Xt + tb);
    bf16x4 z4  = *(const bf16x4*)(Zt + tb);
#pragma unroll
    for (int r = 0; r < 4; r++) {
      int l = w * 16 + fq * 4 + r;
      float yv = acc[pt][r] + (float)xs4[r] * dph;
      float z = (float)z4[r];
      yv *= z / (1.f + __expf(-z));
      ybf[((row0 + l) * NH + h) * HD + p] = (bf16)yv;
    }
  }
}

// ---------------- split-S MFMA flash attention (fixed-max softmax -> partials sum) ----------------
// chunk c covers kt in [sk*8, min(sk*8+8, 2qt+2)); partial O (unnormalized, f32) + lsum
// written per (qt, sk); combined by attn_red. nch(qt) = qt/4 + 1.
#define KSTR 72
#define PSTR 72
__global__ __launch_bounds__(256) void attn_mfma(const bf16* __restrict__ q,
                                                 const bf16* __restrict__ k,
                                                 const bf16* __restrict__ vtr,
                                                 float* __restrict__ Po,
                                                 float* __restrict__ Ls) {
  __shared__ bf16 Ks[2][64 * KSTR];
  __shared__ bf16 Vs[2][64 * KSTR];
  __shared__ bf16 Pl[4][32 * PSTR];
  int c = 39 - blockIdx.x;                 // full 8-iter chunks first
  int g = (c < 4) ? 0 : (c < 12) ? 1 : (c < 24) ? 2 : 3;
  int gbase = (g == 0) ? 0 : (g == 1) ? 4 : (g == 2) ? 12 : 24;
  int d = c - gbase;
  int qt = 4 * g + d / (g + 1);
  int sk = d % (g + 1);
  int h = blockIdx.y, b = blockIdx.z;
  int kvh = h >> 2;
  int tid = threadIdx.x, lane = tid & 63, w = tid >> 6;
  int fr = lane & 15, fq = lane >> 4;
  const float SC = 0.18033688011112042f;   // 0.125 * log2(e)
  const float M2 = 62.0f;
  int kt0 = sk * 8;
  int ktend = min(kt0 + 8, 2 * qt + 2);
  int qbase = qt * 128 + w * 32;           // wave's first q row
  int qmaxw = qbase + 31;
  bf16x8 bq[2][2];
#pragma unroll
  for (int qc = 0; qc < 2; qc++)
#pragma unroll
    for (int ks = 0; ks < 2; ks++)
      bq[qc][ks] = *(const bf16x8*)(q + (size_t)(b * S_ + qbase + qc * 16 + fr) * (HATT * HD)
                                      + h * HD + ks * 32 + fq * 8);
  int sr = tid >> 3, sc8 = (tid & 7) * 8;
  const bf16* kg = k + ((size_t)(b * S_) + sr) * (KVH * HD) + kvh * HD + sc8;
  const bf16* vg = vtr + ((size_t)(b * KVH + kvh) * HD + sr) * S_ + sc8;
  bf16x8 krg0, krg1, vrg0, vrg1;
  {
    const bf16* kp = kg + (size_t)kt0 * 64 * (KVH * HD);
    const bf16* vp = vg + (size_t)kt0 * 64;
    krg0 = *(const bf16x8*)(kp);
    krg1 = *(const bf16x8*)(kp + (size_t)32 * (KVH * HD));
    vrg0 = *(const bf16x8*)(vp);
    vrg1 = *(const bf16x8*)(vp + (size_t)32 * S_);
    *(bf16x8*)(&Ks[0][sr * KSTR + sc8]) = krg0;
    *(bf16x8*)(&Ks[0][(sr + 32) * KSTR + sc8]) = krg1;
    *(bf16x8*)(&Vs[0][sr * KSTR + sc8]) = vrg0;
    *(bf16x8*)(&Vs[0][(sr + 32) * KSTR + sc8]) = vrg1;
  }
  float lsum[2] = {0.f, 0.f};
  f32x4 yacc[2][4] = {};
  bf16* Plw = Pl[w];
  for (int kt = kt0; kt < ktend; kt++) {
    int cur = (kt - kt0) & 1;
    bool more = (kt + 1) < ktend;
    if (more) {
      const bf16* kp = kg + (size_t)(kt + 1) * 64 * (KVH * HD);
      const bf16* vp = vg + (size_t)(kt + 1) * 64;
      krg0 = *(const bf16x8*)(kp);
      krg1 = *(const bf16x8*)(kp + (size_t)32 * (KVH * HD));
      vrg0 = *(const bf16x8*)(vp);
      vrg1 = *(const bf16x8*)(vp + (size_t)32 * S_);
    }
    __syncthreads();
    if (kt * 64 <= qmaxw) {
#pragma unroll
      for (int mi = 0; mi < 4; mi++) {
        int s0 = kt * 64 + mi * 16;
        if (s0 > qmaxw) {
          bf16x4 zz = {};
#pragma unroll
          for (int qc = 0; qc < 2; qc++)
            *(bf16x4*)(Plw + (qc * 16 + fr) * PSTR + mi * 16 + fq * 4) = zz;
        } else {
          const bf16* krow = &Ks[cur][(mi * 16 + fr) * KSTR];
          bf16x8 ak0 = *(const bf16x8*)(krow + fq * 8);
          bf16x8 ak1 = *(const bf16x8*)(krow + 32 + fq * 8);
#pragma unroll
          for (int qc = 0; qc < 2; qc++) {
            f32x4 s = {};
            s = __builtin_amdgcn_mfma_f32_16x16x32_bf16(ak0, bq[qc][0], s, 0, 0, 0);
            s = __builtin_amdgcn_mfma_f32_16x16x32_bf16(ak1, bq[qc][1], s, 0, 0, 0);
            int qq = qbase + qc * 16 + fr;
            bf16x4 pk;
#pragma unroll
            for (int r = 0; r < 4; r++) {
              int sp = s0 + fq * 4 + r;
              float p = (sp <= qq) ? __builtin_amdgcn_exp2f(s[r] * SC - M2) : 0.f;
              lsum[qc] += p;
              pk[r] = (bf16)p;
            }
            *(bf16x4*)(Plw + (qc * 16 + fr) * PSTR + mi * 16 + fq * 4) = pk;
          }
        }
      }
#pragma unroll
      for (int ks2 = 0; ks2 < 2; ks2++) {
        bf16x8 bp[2];
#pragma unroll
        for (int qc = 0; qc < 2; qc++)
          bp[qc] = *(const bf16x8*)(Plw + (qc * 16 + fr) * PSTR + ks2 * 32 + fq * 8);
#pragma unroll
        for (int pi = 0; pi < 4; pi++) {
          bf16x8 av = *(const bf16x8*)(&Vs[cur][(pi * 16 + fr) * KSTR + ks2 * 32 + fq * 8]);
#pragma unroll
          for (int qc = 0; qc < 2; qc++)
            yacc[qc][pi] = __builtin_amdgcn_mfma_f32_16x16x32_bf16(av, bp[qc], yacc[qc][pi], 0, 0, 0);
        }
      }
    }
    if (more) {
      int nxt = cur ^ 1;
      *(bf16x8*)(&Ks[nxt][sr * KSTR + sc8]) = krg0;
      *(bf16x8*)(&Ks[nxt][(sr + 32) * KSTR + sc8]) = krg1;
      *(bf16x8*)(&Vs[nxt][sr * KSTR + sc8]) = vrg0;
      *(bf16x8*)(&Vs[nxt][(sr + 32) * KSTR + sc8]) = vrg1;
    }
  }
#pragma unroll
  for (int qc = 0; qc < 2; qc++) {
    lsum[qc] += __shfl_xor(lsum[qc], 16, 64);
    lsum[qc] += __shfl_xor(lsum[qc], 32, 64);
    int qrow = qt * 128 + w * 32 + qc * 16 + fr;
    if (fq == 0)
      Ls[((size_t)(b * 16 + h) * 2048 + qrow) * 4 + sk] = lsum[qc];
    float* pop = Po + ((((size_t)(b * 16 + h) * 16 + qt) * 4 + sk) * 128
                        + w * 32 + qc * 16 + fr) * 64 + fq * 4;
#pragma unroll
    for (int pi = 0; pi < 4; pi++)
      *(f32x4*)(pop + pi * 16) = yacc[qc][pi];
  }
}

// ---------------- attention partial combine + normalize -> y2 bf16 ----------------
__global__ __launch_bounds__(256) void attn_red(const float* __restrict__ Po,
                                                const float* __restrict__ Ls,
                                                bf16* __restrict__ y2) {
  int row = blockIdx.x;            // 0..4095
  int b = row >> 11;
  int qrow = row & 2047;
  int qt = qrow >> 7, r = qrow & 127;
  int nch = (qt >> 2) + 1;
  int t = threadIdx.x;
  int h = t >> 4, e4 = (t & 15) << 2;
  const float* lp = Ls + ((size_t)(b * 16 + h) * 2048 + qrow) * 4;
  float ls = 0.f;
  f32x4 acc = {};
  for (int sk = 0; sk < nch; sk++) {
    ls += lp[sk];
    const float* pp = Po + ((((size_t)(b * 16 + h) * 16 + qt) * 4 + sk) * 128 + r) * 64 + e4;
    acc += *(const f32x4*)(pp);
  }
  float inv = 1.f / ls;
  bf16x4 o;
#pragma unroll
  for (int j = 0; j < 4; j++) o[j] = (bf16)(acc[j] * inv);
  *(bf16x4*)(y2 + (size_t)row * 1024 + h * 64 + e4) = o;
}

// ---------------- workspace layout (byte offsets) ----------------
constexpr size_t OFF_WIN  = 0;                   // bf16 4480x1024
constexpr size_t OFF_WOUT = 9175040;             // bf16 1024x2048
constexpr size_t OFF_WQKV = 13369344;            // bf16 1536x1024 (q|k|v rows)
constexpr size_t OFF_WCP  = 16515072;            // bf16 1024x1024
constexpr size_t OFF_WFC  = 18612224;            // bf16 3072x1024
constexpr size_t OFF_WPR  = 24903680;            // bf16 1024x3072
constexpr size_t OFF_HBF  = 31195136;            // bf16 4096x1024
constexpr size_t OFF_BCDT = 39583744;            // bf16 4096x288; reused: Ls f32 (1 MiB)
constexpr size_t OFF_XT   = 41943040;            // bf16 [b][h][p][sg] (16.7 MB)
constexpr size_t OFF_ZT   = 58720256;            // bf16 [b][h][p][sg] (16.7 MB)
constexpr size_t OFF_DTC  = 75497472;            // f32 [b][h][sg]
constexpr size_t OFF_DDC  = 76546048;            // f32
constexpr size_t OFF_ACC  = 77594624;            // f32
constexpr size_t OFF_T    = 78643200;            // f32 2048
constexpr size_t OFF_BN   = 78651392;            // bf16 4096x128
constexpr size_t OFF_CN   = 79699968;            // bf16 4096x128
constexpr size_t OFF_BTR  = 80748544;            // bf16 [b][n][sg]
constexpr size_t OFF_ST   = 81797120;            // bf16 states (33.5 MB); reused: Po f32 64 MiB
constexpr size_t OFF_YBF  = 148905984;           // bf16 4096x2048
constexpr size_t OFF_X1   = 165683200;           // f32 4096x1024 (end 182,460,416)
// phase-2 aliases
constexpr size_t OFF_P    = OFF_ST;              // bf16 split-K partials (<= 25.2 MB)
constexpr size_t OFF_PO   = OFF_ST;              // f32 attn partials [b][h][qt][4][128][64] = 64 MiB
constexpr size_t OFF_LS   = OFF_BCDT;            // f32 attn lsums [b][h][2048][4] = 1 MiB
constexpr size_t OFF_QB   = OFF_XT;              // bf16 4096x1024 (8.4 MB)
constexpr size_t OFF_KB   = OFF_XT + 8388608;    // bf16 4096x256
constexpr size_t OFF_VB   = OFF_XT + 10485760;   // bf16 4096x256
constexpr size_t OFF_VTR  = OFF_XT + 12582912;   // bf16 [b][kvh][p][sg]
constexpr size_t OFF_Y2   = OFF_ZT;              // bf16 4096x1024
constexpr size_t OFF_X2   = 50331648;            // f32 4096x1024 (over dead kb/vb/vtr/y2)
constexpr size_t OFF_MLP  = 132128768;           // bf16 4096x3072 (over dead regions)

extern "C" void kernel_launch(void* const* d_in, const int* in_sizes, int n_in,
                              void* d_out, int out_size, void* d_ws, size_t ws_size,
                              hipStream_t stream) {
  (void)in_sizes; (void)n_in; (void)out_size; (void)ws_size;
  const float* x        = (const float*)d_in[0];
  const float* mnorm_w  = (const float*)d_in[1];
  const float* in_w     = (const float*)d_in[2];
  const float* out_w    = (const float*)d_in[3];
  const float* Dp       = (const float*)d_in[4];
  const float* dt_bias  = (const float*)d_in[5];
  const float* A_log    = (const float*)d_in[6];
  const float* Bn_w     = (const float*)d_in[7];
  const float* Cn_w     = (const float*)d_in[8];
  const float* ln1_w    = (const float*)d_in[9];
  const float* ln1_b    = (const float*)d_in[10];
  const float* cq_w     = (const float*)d_in[11];
  const float* ck_w     = (const float*)d_in[12];
  const float* cv_w     = (const float*)d_in[13];
  const float* cproj_w  = (const float*)d_in[14];
  const float* q_gain   = (const float*)d_in[15];
  const float* ln2_w    = (const float*)d_in[16];
  const float* ln2_b    = (const float*)d_in[17];
  const float* fc_w     = (const float*)d_in[18];
  const float* proj_w   = (const float*)d_in[19];
  float* out = (float*)d_out;
  char* W8 = (char*)d_ws;

  bf16* w_in   = (bf16*)(W8 + OFF_WIN);
  bf16* w_out  = (bf16*)(W8 + OFF_WOUT);
  bf16* w_qkv  = (bf16*)(W8 + OFF_WQKV);
  bf16* w_cp   = (bf16*)(W8 + OFF_WCP);
  bf16* w_fc   = (bf16*)(W8 + OFF_WFC);
  bf16* w_pr   = (bf16*)(W8 + OFF_WPR);
  bf16* h_bf   = (bf16*)(W8 + OFF_HBF);
  bf16* bcdt   = (bf16*)(W8 + OFF_BCDT);
  bf16* Xt     = (bf16*)(W8 + OFF_XT);
  bf16* Zt     = (bf16*)(W8 + OFF_ZT);
  float* dt_c  = (float*)(W8 + OFF_DTC);
  float* ddc   = (float*)(W8 + OFF_DDC);
  float* ac_c  = (float*)(W8 + OFF_ACC);
  float* Tb    = (float*)(W8 + OFF_T);
  bf16* Bn     = (bf16*)(W8 + OFF_BN);
  bf16* Cn     = (bf16*)(W8 + OFF_CN);
  bf16* Btr    = (bf16*)(W8 + OFF_BTR);
  bf16* st     = (bf16*)(W8 + OFF_ST);
  bf16* ybf    = (bf16*)(W8 + OFF_YBF);
  float* x1    = (float*)(W8 + OFF_X1);
  bf16* Pbuf   = (bf16*)(W8 + OFF_P);
  float* Po    = (float*)(W8 + OFF_PO);
  float* Ls    = (float*)(W8 + OFF_LS);
  bf16* qbf    = (bf16*)(W8 + OFF_QB);
  bf16* kbf    = (bf16*)(W8 + OFF_KB);
  bf16* vbf    = (bf16*)(W8 + OFF_VB);
  bf16* vtr    = (bf16*)(W8 + OFF_VTR);
  bf16* y2     = (bf16*)(W8 + OFF_Y2);
  float* x2    = (float*)(W8 + OFF_X2);
  bf16* mlp    = (bf16*)(W8 + OFF_MLP);

  // ---- weight casts (single launch; q/k/v cast into adjacent rows of w_qkv) ----
  CastArgs ca;
  ca.seg[0] = { in_w,    w_in,            4489216, 4587520, 0     };
  ca.seg[1] = { out_w,   w_out,           2097152, 2097152, 4480  };
  ca.seg[2] = { cq_w,    w_qkv,           1048576, 1048576, 6528  };
  ca.seg[3] = { ck_w,    w_qkv + 1048576,  262144,  262144, 7552  };
  ca.seg[4] = { cv_w,    w_qkv + 1310720,  262144,  262144, 7808  };
  ca.seg[5] = { cproj_w, w_cp,            1048576, 1048576, 8064  };
  ca.seg[6] = { fc_w,    w_fc,            3145728, 3145728, 9088  };
  ca.seg[7] = { proj_w,  w_pr,            3145728, 3145728, 12160 };
  castw_all<<<15232, 256, 0, stream>>>(ca);

  const size_t PS  = (size_t)ROWS * 1024;   // partial stride (elements) for N=1024 GEMMs

  // ---- mamba block ----
  rmsnorm_k<<<ROWS, 256, 0, stream>>>(x, mnorm_w, h_bf, D_);
  gemm_inproj<<<32 * 35, 256, 0, stream>>>(h_bf, w_in, Zt, Xt, bcdt);
  ssd_prep<<<B_ * NH * NC, 64, 0, stream>>>(bcdt, dt_bias, A_log, dt_c, ddc, ac_c, Tb);
  bc_norm<<<ROWS, 128, 0, stream>>>(bcdt, Bn_w, Cn_w, Bn, Cn);
  t64<<<2 * 2 * 32, 256, 0, stream>>>(Bn, Btr, 128, (size_t)2048 * 128, (size_t)128 * 2048, 2);
  ssd_states<<<B_ * NC * NH, 256, 0, stream>>>(Xt, Btr, ddc, st);
  ssd_scan<<<B_ * NH * 8, 256, 0, stream>>>(st, Tb);
  ssd_out<<<B_ * NC * NH, 256, 0, stream>>>(Cn, Bn, Xt, Zt, dt_c, ac_c, st, Dp, ybf);
  // out_proj: split-K=2 then fused reduce+residual+LN1
  gemm_sk<<<dim3(32 * 8, 1, 2), 256, 0, stream>>>(ybf, w_out, Pbuf, ROWS, D_, DI, 1024);
  reduce_ln2<<<ROWS, 256, 0, stream>>>(Pbuf, Pbuf + PS, x, ln1_w, ln1_b, x1, h_bf);

  // ---- attention block ----
  gemm_sk<<<dim3(32 * 12, 1, 2), 256, 0, stream>>>(h_bf, w_qkv, Pbuf, ROWS, 1536, D_, 512);
  reduce_qkv<<<ROWS, 256, 0, stream>>>(Pbuf, q_gain, qbf, kbf, vbf);
  t64<<<2 * 4 * 32, 256, 0, stream>>>(vbf, vtr, 256, (size_t)2048 * 256, (size_t)256 * 2048, 4);
  attn_mfma<<<dim3(40, HATT, B_), 256, 0, stream>>>(qbf, kbf, vtr, Po, Ls);
  attn_red<<<ROWS, 256, 0, stream>>>(Po, Ls, y2);
  gemm_sk<<<dim3(32 * 8, 1, 2), 256, 0, stream>>>(y2, w_cp, Pbuf, ROWS, D_, D_, 512);
  reduce_ln2<<<ROWS, 256, 0, stream>>>(Pbuf, Pbuf + PS, x1, ln2_w, ln2_b, x2, h_bf);

  // ---- MLP ----
  gemm_mfma<1, bf16><<<32 * 24, 256, 0, stream>>>(h_bf, w_fc, nullptr, mlp, ROWS, MLP, D_);
  gemm_sk<<<dim3(32 * 8, 1, 3), 256, 0, stream>>>(mlp, w_pr, Pbuf, ROWS, D_, MLP, 1024);
  reduce_out3<<<ROWS, 256, 0, stream>>>(Pbuf, Pbuf + PS, Pbuf + 2 * PS, x2, out);
}

// Round 10
// 527.138 us; speedup vs baseline: 1.4073x; 1.0150x over previous
//
#include <hip/hip_runtime.h>
#include <hip/hip_bf16.h>
#include <math.h>

// ---------------- problem constants ----------------
#define B_    2
#define S_    2048
#define D_    1024
#define DI    2048      // D_INNER
#define NH    32        // NHEADS (mamba)
#define HD    64        // HEADDIM
#define DS    128       // D_STATE
#define CH    64        // CHUNK
#define NC    32        // S_/CH
#define DP    4384      // D_PROJ
#define HATT  16        // attention heads
#define KVH   4         // kv heads
#define RD    16        // rope dims
#define MLP   3072
#define ROWS  (B_*S_)   // 4096

typedef __bf16 bf16;
typedef __bf16 bf16x8 __attribute__((ext_vector_type(8)));
typedef __bf16 bf16x4 __attribute__((ext_vector_type(4)));
typedef float  f32x4  __attribute__((ext_vector_type(4)));

__device__ __forceinline__ void async_copy16(const void* g, void* l) {
  __builtin_amdgcn_global_load_lds(
      (const __attribute__((address_space(1))) unsigned int*)g,
      (__attribute__((address_space(3))) unsigned int*)l, 16, 0, 0);
}

// ---------------- reductions ----------------
__device__ __forceinline__ float waveReduceSum(float v) {
#pragma unroll
  for (int off = 32; off > 0; off >>= 1) v += __shfl_down(v, off, 64);
  return v;
}

template<int NW>
__device__ __forceinline__ float blockReduceSum(float v, float* sh) {
  v = waveReduceSum(v);
  int lane = threadIdx.x & 63, wid = threadIdx.x >> 6;
  if (lane == 0) sh[wid] = v;
  __syncthreads();
  float s = 0.f;
#pragma unroll
  for (int i = 0; i < NW; i++) s += sh[i];
  __syncthreads();
  return s;
}

// ---------------- merged weight cast f32 -> bf16 ----------------
struct CastSeg { const float* src; bf16* dst; int nval; int ntot; int blk0; };
struct CastArgs { CastSeg seg[8]; };

__global__ __launch_bounds__(256) void castw_all(CastArgs a) {
  int blk = blockIdx.x;
  int si = 0;
#pragma unroll
  for (int i = 1; i < 8; i++) if (blk >= a.seg[i].blk0) si = i;
  CastSeg s = a.seg[si];
  int i = ((blk - s.blk0) * 256 + threadIdx.x) * 4;
  if (i >= s.ntot) return;
  float4 v = {0.f, 0.f, 0.f, 0.f};
  if (i < s.nval) v = *(const float4*)(s.src + i);
  bf16x4 o;
  o[0] = (bf16)v.x; o[1] = (bf16)v.y; o[2] = (bf16)v.z; o[3] = (bf16)v.w;
  *(bf16x4*)(s.dst + i) = o;
}

// ---------------- rmsnorm (f32 in, bf16 out) ----------------
__global__ __launch_bounds__(256) void rmsnorm_k(const float* __restrict__ x,
                                                 const float* __restrict__ w,
                                                 bf16* __restrict__ y, int n) {
  __shared__ float sh[4];
  size_t row = blockIdx.x;
  const float* xr = x + row * n;
  bf16* yr = y + row * n;
  float ss = 0.f;
  for (int i = threadIdx.x; i < n; i += 256) { float v = xr[i]; ss += v * v; }
  ss = blockReduceSum<4>(ss, sh);
  float inv = rsqrtf(ss / n + 1e-5f);
  for (int i = threadIdx.x; i < n; i += 256) yr[i] = (bf16)(xr[i] * inv * w[i]);
}

// ---------------- generic bf16 MFMA GEMM: C = act(A @ W^T), bm-fastest 1D grid ----------------
template<int ACT, typename OT>
__global__ __launch_bounds__(256) void gemm_mfma(const bf16* __restrict__ A,
                                                 const bf16* __restrict__ W,
                                                 const float* __restrict__ R,
                                                 OT* __restrict__ C,
                                                 int M, int N, int K) {
  __shared__ bf16 As[128 * 32];
  __shared__ bf16 Ws[128 * 32];
  int tid = threadIdx.x, lane = tid & 63, wave = tid >> 6;
  int mt = M >> 7;
  int bid = blockIdx.x;
  int bm = (bid % mt) * 128, bn = (bid / mt) * 128;
  const bf16* gA0 = A + (size_t)(bm + wave * 32 + (lane >> 2)) * K + (lane & 3) * 8;
  const bf16* gA1 = gA0 + (size_t)16 * K;
  const bf16* gW0 = W + (size_t)(bn + wave * 32 + (lane >> 2)) * K + (lane & 3) * 8;
  const bf16* gW1 = gW0 + (size_t)16 * K;
  bf16* lA0 = As + wave * 32 * 32;
  bf16* lA1 = lA0 + 16 * 32;
  bf16* lW0 = Ws + wave * 32 * 32;
  bf16* lW1 = lW0 + 16 * 32;
  int fr = lane & 15, fq = lane >> 4;
  int wm = wave >> 1, wn = wave & 1;
  const bf16* pA = As + (wm * 64 + fr) * 32 + fq * 8;
  const bf16* pW = Ws + (wn * 64 + fr) * 32 + fq * 8;
  f32x4 acc[4][4] = {};
  for (int k0 = 0; k0 < K; k0 += 32) {
    async_copy16(gA0, lA0);
    async_copy16(gA1, lA1);
    async_copy16(gW0, lW0);
    async_copy16(gW1, lW1);
    gA0 += 32; gA1 += 32; gW0 += 32; gW1 += 32;
    __syncthreads();
    bf16x8 af[4], bfr[4];
#pragma unroll
    for (int mi = 0; mi < 4; mi++) af[mi] = *(const bf16x8*)(pA + mi * 16 * 32);
#pragma unroll
    for (int ni = 0; ni < 4; ni++) bfr[ni] = *(const bf16x8*)(pW + ni * 16 * 32);
#pragma unroll
    for (int mi = 0; mi < 4; mi++)
#pragma unroll
      for (int ni = 0; ni < 4; ni++)
        acc[mi][ni] = __builtin_amdgcn_mfma_f32_16x16x32_bf16(af[mi], bfr[ni], acc[mi][ni], 0, 0, 0);
    __syncthreads();
  }
#pragma unroll
  for (int mi = 0; mi < 4; mi++) {
    int row = bm + wm * 64 + mi * 16 + fq * 4;
#pragma unroll
    for (int ni = 0; ni < 4; ni++) {
      int col = bn + wn * 64 + ni * 16 + fr;
      if (col < N) {
#pragma unroll
        for (int r = 0; r < 4; r++) {
          float v = acc[mi][ni][r];
          if (ACT == 1) v = v / (1.f + __expf(-v));
          if (R) v += R[(size_t)(row + r) * N + col];
          C[(size_t)(row + r) * N + col] = (OT)v;
        }
      }
    }
  }
}

// ---------------- split-K bf16 MFMA GEMM: P[ks] = A @ W^T (bf16 partials) ----------------
__global__ __launch_bounds__(256) void gemm_sk(const bf16* __restrict__ A,
                                               const bf16* __restrict__ W,
                                               bf16* __restrict__ P,
                                               int M, int N, int K, int kchunk) {
  __shared__ bf16 As[128 * 32];
  __shared__ bf16 Ws[128 * 32];
  int tid = threadIdx.x, lane = tid & 63, wave = tid >> 6;
  int mt = M >> 7;
  int bid = blockIdx.x;
  int bm = (bid % mt) * 128, bn = (bid / mt) * 128;
  int ks = blockIdx.z;
  int kbeg = ks * kchunk;
  const bf16* gA0 = A + (size_t)(bm + wave * 32 + (lane >> 2)) * K + kbeg + (lane & 3) * 8;
  const bf16* gA1 = gA0 + (size_t)16 * K;
  const bf16* gW0 = W + (size_t)(bn + wave * 32 + (lane >> 2)) * K + kbeg + (lane & 3) * 8;
  const bf16* gW1 = gW0 + (size_t)16 * K;
  bf16* lA0 = As + wave * 32 * 32;
  bf16* lA1 = lA0 + 16 * 32;
  bf16* lW0 = Ws + wave * 32 * 32;
  bf16* lW1 = lW0 + 16 * 32;
  int fr = lane & 15, fq = lane >> 4;
  int wm = wave >> 1, wn = wave & 1;
  const bf16* pA = As + (wm * 64 + fr) * 32 + fq * 8;
  const bf16* pW = Ws + (wn * 64 + fr) * 32 + fq * 8;
  f32x4 acc[4][4] = {};
  for (int k0 = 0; k0 < kchunk; k0 += 32) {
    async_copy16(gA0, lA0);
    async_copy16(gA1, lA1);
    async_copy16(gW0, lW0);
    async_copy16(gW1, lW1);
    gA0 += 32; gA1 += 32; gW0 += 32; gW1 += 32;
    __syncthreads();
    bf16x8 af[4], bfr[4];
#pragma unroll
    for (int mi = 0; mi < 4; mi++) af[mi] = *(const bf16x8*)(pA + mi * 16 * 32);
#pragma unroll
    for (int ni = 0; ni < 4; ni++) bfr[ni] = *(const bf16x8*)(pW + ni * 16 * 32);
#pragma unroll
    for (int mi = 0; mi < 4; mi++)
#pragma unroll
      for (int ni = 0; ni < 4; ni++)
        acc[mi][ni] = __builtin_amdgcn_mfma_f32_16x16x32_bf16(af[mi], bfr[ni], acc[mi][ni], 0, 0, 0);
    __syncthreads();
  }
  bf16* Pp = P + (size_t)ks * M * N;
#pragma unroll
  for (int mi = 0; mi < 4; mi++) {
    int row = bm + wm * 64 + mi * 16 + fq * 4;
#pragma unroll
    for (int ni = 0; ni < 4; ni++) {
      int col = bn + wn * 64 + ni * 16 + fr;
#pragma unroll
      for (int r = 0; r < 4; r++)
        Pp[(size_t)(row + r) * N + col] = (bf16)acc[mi][ni][r];
    }
  }
}

// ---------------- reduce 2 bf16 partials + residual + layernorm -> x_out f32, h bf16 ----------------
__global__ __launch_bounds__(256) void reduce_ln2(const bf16* __restrict__ p0,
                                                  const bf16* __restrict__ p1,
                                                  const float* __restrict__ res,
                                                  const float* __restrict__ w,
                                                  const float* __restrict__ b,
                                                  float* __restrict__ xo,
                                                  bf16* __restrict__ ho) {
  __shared__ float sh[4];
  size_t o = (size_t)blockIdx.x * 1024;
  int i = threadIdx.x * 4;
  bf16x4 a = *(const bf16x4*)(p0 + o + i);
  bf16x4 c = *(const bf16x4*)(p1 + o + i);
  f32x4 rv = *(const f32x4*)(res + o + i);
  f32x4 v;
  float s = 0.f, s2 = 0.f;
#pragma unroll
  for (int j = 0; j < 4; j++) {
    v[j] = (float)a[j] + (float)c[j] + rv[j];
    s += v[j]; s2 += v[j] * v[j];
  }
  s  = blockReduceSum<4>(s,  sh);
  s2 = blockReduceSum<4>(s2, sh);
  float mean = s / 1024.f;
  float var  = s2 / 1024.f - mean * mean;
  float inv  = rsqrtf(var + 1e-5f);
  f32x4 wv = *(const f32x4*)(w + i);
  f32x4 bv = *(const f32x4*)(b + i);
  *(f32x4*)(xo + o + i) = v;
  bf16x4 hv;
#pragma unroll
  for (int j = 0; j < 4; j++) hv[j] = (bf16)((v[j] - mean) * inv * wv[j] + bv[j]);
  *(bf16x4*)(ho + o + i) = hv;
}

// ---------------- reduce 3 bf16 partials + residual -> out f32 ----------------
__global__ __launch_bounds__(256) void reduce_out3(const bf16* __restrict__ p0,
                                                   const bf16* __restrict__ p1,
                                                   const bf16* __restrict__ p2,
                                                   const float* __restrict__ res,
                                                   float* __restrict__ out) {
  int i = (blockIdx.x * 256 + threadIdx.x) * 4;
  bf16x4 a = *(const bf16x4*)(p0 + i);
  bf16x4 c = *(const bf16x4*)(p1 + i);
  bf16x4 d = *(const bf16x4*)(p2 + i);
  f32x4 v = *(const f32x4*)(res + i);
#pragma unroll
  for (int j = 0; j < 4; j++) v[j] += (float)a[j] + (float)c[j] + (float)d[j];
  *(f32x4*)(out + i) = v;
}

// ---------------- reduce qkv bf16 partials + q/k rmsnorm + rope + gain -> bf16 ----------------
__global__ __launch_bounds__(256) void reduce_qkv(const bf16* __restrict__ P,
                                                  const float* __restrict__ q_gain,
                                                  bf16* __restrict__ q,
                                                  bf16* __restrict__ k,
                                                  bf16* __restrict__ v) {
  __shared__ float buf[1536];
  size_t row = blockIdx.x;
  size_t o = row * 1536;
  const bf16* p0 = P + o;
  const bf16* p1 = P + (size_t)ROWS * 1536 + o;
  int tid = threadIdx.x;
  for (int i = tid; i < 384; i += 256) {
    bf16x4 a = *(const bf16x4*)(p0 + i * 4);
    bf16x4 c = *(const bf16x4*)(p1 + i * 4);
    f32x4 vv;
#pragma unroll
    for (int j = 0; j < 4; j++) vv[j] = (float)a[j] + (float)c[j];
    *(f32x4*)(buf + i * 4) = vv;
  }
  __syncthreads();
  int lane = tid & 63, w = tid >> 6;
  int s = (int)(row & (S_ - 1));
  int ri = lane & 7;
  float rinv = __expf(-(float)ri * (0.125f * 9.210340371976184f)); // 10000^(-i/8)
  float ang = (float)s * rinv;
  float cs = cosf(ang), sn = sinf(ang);
#pragma unroll
  for (int j = 0; j < 6; j++) {
    int hh = w * 6 + j;
    float val = buf[hh * 64 + lane];
    if (hh < 20) {
      float ss = val * val;
#pragma unroll
      for (int off = 32; off > 0; off >>= 1) ss += __shfl_xor(ss, off, 64);
      val *= rsqrtf(ss / 64.f + 1.1920929e-7f);
      float other = __shfl_xor(val, 8, 64);
      float res = val;
      if (lane < RD) res = (lane < 8) ? (val * cs + other * sn) : (val * cs - other * sn);
      if (hh < 16) {
        res *= q_gain[hh];
        q[row * (HATT * HD) + hh * HD + lane] = (bf16)res;
      } else {
        k[row * (KVH * HD) + (hh - 16) * HD + lane] = (bf16)res;
      }
    } else {
      v[row * (KVH * HD) + (hh - 20) * HD + lane] = (bf16)val;
    }
  }
}

// ---------------- in_proj GEMM: LDS-transposed coalesced Zt/Xt epilogue + bcdt ----------------
__global__ __launch_bounds__(256) void gemm_inproj(const bf16* __restrict__ A,
                                                   const bf16* __restrict__ W,
                                                   bf16* __restrict__ zt,
                                                   bf16* __restrict__ xt,
                                                   bf16* __restrict__ bcdt) {
  const int K = 1024;
  __shared__ bf16 As[128 * 32];
  __shared__ bf16 Ws[128 * 32];
  __shared__ bf16 Ts[64 * 136];
  int tid = threadIdx.x, lane = tid & 63, wave = tid >> 6;
  int bid = blockIdx.x;
  int bm = (bid & 31) * 128, bn = (bid >> 5) * 128;
  const bf16* gA0 = A + (size_t)(bm + wave * 32 + (lane >> 2)) * K + (lane & 3) * 8;
  const bf16* gA1 = gA0 + (size_t)16 * K;
  const bf16* gW0 = W + (size_t)(bn + wave * 32 + (lane >> 2)) * K + (lane & 3) * 8;
  const bf16* gW1 = gW0 + (size_t)16 * K;
  bf16* lA0 = As + wave * 32 * 32;
  bf16* lA1 = lA0 + 16 * 32;
  bf16* lW0 = Ws + wave * 32 * 32;
  bf16* lW1 = lW0 + 16 * 32;
  int fr = lane & 15, fq = lane >> 4;
  int wm = wave >> 1, wn = wave & 1;
  const bf16* pA = As + (wm * 64 + fr) * 32 + fq * 8;
  const bf16* pW = Ws + (wn * 64 + fr) * 32 + fq * 8;
  f32x4 acc[4][4] = {};
  for (int k0 = 0; k0 < K; k0 += 32) {
    async_copy16(gA0, lA0);
    async_copy16(gA1, lA1);
    async_copy16(gW0, lW0);
    async_copy16(gW1, lW1);
    gA0 += 32; gA1 += 32; gW0 += 32; gW1 += 32;
    __syncthreads();
    bf16x8 af[4], bfr[4];
#pragma unroll
    for (int mi = 0; mi < 4; mi++) af[mi] = *(const bf16x8*)(pA + mi * 16 * 32);
#pragma unroll
    for (int ni = 0; ni < 4; ni++) bfr[ni] = *(const bf16x8*)(pW + ni * 16 * 32);
#pragma unroll
    for (int mi = 0; mi < 4; mi++)
#pragma unroll
      for (int ni = 0; ni < 4; ni++)
        acc[mi][ni] = __builtin_amdgcn_mfma_f32_16x16x32_bf16(af[mi], bfr[ni], acc[mi][ni], 0, 0, 0);
    __syncthreads();
  }
  if (bn < 4096) {
    // z (bn<2048) or x (2048<=bn<4096) block: transpose via LDS, coalesced stores
    bf16* base = (bn < 2048) ? zt : xt;
    int bq = bm >> 11, bmS = bm & 2047;
#pragma unroll
    for (int p = 0; p < 2; p++) {
      __syncthreads();
      if (wn == p) {
#pragma unroll
        for (int mi = 0; mi < 4; mi++)
#pragma unroll
          for (int ni = 0; ni < 4; ni++) {
            bf16x4 o;
#pragma unroll
            for (int r = 0; r < 4; r++) o[r] = (bf16)acc[mi][ni][r];
            *(bf16x4*)(Ts + (ni * 16 + fr) * 136 + wm * 64 + mi * 16 + fq * 4) = o;
          }
      }
      __syncthreads();
      int hh = ((bn & 2047) + p * 64) >> 6;
      bf16* dst = base + ((size_t)(bq * NH + hh) * HD) * S_ + bmS;
#pragma unroll
      for (int i = 0; i < 4; i++) {
        int idx = tid + i * 256;
        int cl = idx >> 4, sgc = (idx & 15) * 8;
        *(bf16x8*)(dst + (size_t)cl * S_ + sgc) = *(const bf16x8*)(Ts + cl * 136 + sgc);
      }
    }
  } else {
    // bcdt columns (4096..4383), direct scalar path
#pragma unroll
    for (int mi = 0; mi < 4; mi++) {
      int row0m = bm + wm * 64 + mi * 16 + fq * 4;
#pragma unroll
      for (int ni = 0; ni < 4; ni++) {
        int col = bn + wn * 64 + ni * 16 + fr;
        if (col < 4384) {
#pragma unroll
          for (int r = 0; r < 4; r++)
            bcdt[(size_t)(row0m + r) * 288 + (col - 4096)] = (bf16)acc[mi][ni][r];
        }
      }
    }
  }
}

// ---------------- generic 64x64 tiled transpose (bf16), out row stride 2048 ----------------
__global__ __launch_bounds__(256) void t64(const bf16* __restrict__ in, bf16* __restrict__ out,
                                           int istr, size_t io, size_t oo, int n_nt) {
  __shared__ bf16 T[64 * 72];
  int bid = blockIdx.x;
  int st = bid & 31;
  int nt = (bid >> 5) % n_nt;
  int outer = bid / (32 * n_nt);
  const bf16* ip = in + outer * io + (size_t)st * 64 * istr + nt * 64;
  int tid = threadIdx.x;
#pragma unroll
  for (int i = 0; i < 2; i++) {
    int cid = tid + i * 256; int s = cid >> 3, pc = (cid & 7) * 8;
    *(bf16x8*)(T + s * 72 + pc) = *(const bf16x8*)(ip + (size_t)s * istr + pc);
  }
  __syncthreads();
  bf16* op = out + outer * oo + (size_t)nt * 64 * 2048 + st * 64;
#pragma unroll
  for (int i = 0; i < 2; i++) {
    int cid = tid + i * 256; int p = cid >> 3, sc = (cid & 7) * 8;
    bf16x8 o;
#pragma unroll
    for (int j = 0; j < 8; j++) o[j] = T[(sc + j) * 72 + p];
    *(bf16x8*)(op + (size_t)p * 2048 + sc) = o;
  }
}

// ---------------- SSD prep: dt softplus, per-chunk cumsum, decay factors ----------------
__global__ __launch_bounds__(64) void ssd_prep(const bf16* __restrict__ bcdt,
                                               const float* __restrict__ dt_bias,
                                               const float* __restrict__ A_log,
                                               float* __restrict__ dt_c,
                                               float* __restrict__ ddc,
                                               float* __restrict__ ac_c,
                                               float* __restrict__ T_out) {
  int bid = blockIdx.x;
  int c = bid % NC, hh = (bid / NC) % NH, b = bid / (NC * NH);
  int l = threadIdx.x;
  size_t row = (size_t)b * S_ + c * 64 + l;
  float raw = (float)bcdt[row * 288 + 256 + hh] + dt_bias[hh];
  float dtv = (raw > 20.f) ? raw : log1pf(__expf(raw));
  float a = -__expf(A_log[hh]) * dtv;
  float ps = a;
#pragma unroll
  for (int off = 1; off < 64; off <<= 1) {
    float t = __shfl_up(ps, off, 64);
    if (l >= off) ps += t;
  }
  float a63 = __shfl(ps, 63, 64);
  size_t o = ((size_t)b * NH + hh) * S_ + c * 64 + l;
  dt_c[o] = dtv;
  ac_c[o] = ps;
  ddc[o] = __expf(a63 - ps) * dtv;
  if (l == 63) T_out[(b * NH + hh) * NC + c] = ps;
}

// ---------------- B/C rmsnorm (bf16 out) ----------------
__global__ __launch_bounds__(128) void bc_norm(const bf16* __restrict__ bcdt,
                                               const float* __restrict__ Bw,
                                               const float* __restrict__ Cw,
                                               bf16* __restrict__ Bn,
                                               bf16* __restrict__ Cn) {
  __shared__ float shb[2], shc[2];
  size_t row = blockIdx.x;
  int i = threadIdx.x;
  float bv = (float)bcdt[row * 288 + i];
  float cv = (float)bcdt[row * 288 + 128 + i];
  float sb = waveReduceSum(bv * bv);
  float sc = waveReduceSum(cv * cv);
  int lane = threadIdx.x & 63, wid = threadIdx.x >> 6;
  if (lane == 0) { shb[wid] = sb; shc[wid] = sc; }
  __syncthreads();
  float tb = shb[0] + shb[1];
  float tc = shc[0] + shc[1];
  Bn[row * DS + i] = (bf16)(bv * rsqrtf(tb / DS + 1e-5f) * Bw[i]);
  Cn[row * DS + i] = (bf16)(cv * rsqrtf(tc / DS + 1e-5f) * Cw[i]);
}

// ---------------- chunk states via MFMA (bf16 output) ----------------
__global__ __launch_bounds__(256) void ssd_states(const bf16* __restrict__ Xt,
                                                  const bf16* __restrict__ Btr,
                                                  const float* __restrict__ ddc,
                                                  bf16* __restrict__ states) {
  __shared__ bf16 Xs[64 * 72];    // [p][s]
  __shared__ bf16 Bs[128 * 72];   // [n][s]
  int bid = blockIdx.x;           // (b*NC + c)*NH + h
  int h = bid % NH;
  int c = (bid / NH) % NC;
  int b = bid / (NH * NC);
  int tid = threadIdx.x, lane = tid & 63, w = tid >> 6;
  int fr = lane & 15, fq = lane >> 4;
  const size_t xbase = (size_t)(b * NH + h) * HD * S_ + c * 64;
  const size_t dbase = (size_t)(b * NH + h) * S_ + c * 64;
#pragma unroll
  for (int i = 0; i < 2; i++) {
    int cid = tid + i * 256; int p = cid >> 3, sc = (cid & 7) * 8;
    bf16x8 xv = *(const bf16x8*)(Xt + xbase + (size_t)p * S_ + sc);
    f32x4 d0 = *(const f32x4*)(ddc + dbase + sc);
    f32x4 d1 = *(const f32x4*)(ddc + dbase + sc + 4);
    bf16x8 o;
#pragma unroll
    for (int j = 0; j < 4; j++) { o[j] = (bf16)((float)xv[j] * d0[j]); o[4 + j] = (bf16)((float)xv[4 + j] * d1[j]); }
    *(bf16x8*)(Xs + p * 72 + sc) = o;
  }
  const size_t bbase = (size_t)b * 128 * S_ + c * 64;
#pragma unroll
  for (int i = 0; i < 4; i++) {
    int cid = tid + i * 256; int n = cid >> 3, sc = (cid & 7) * 8;
    *(bf16x8*)(Bs + n * 72 + sc) = *(const bf16x8*)(Btr + bbase + (size_t)n * S_ + sc);
  }
  __syncthreads();
  f32x4 acc[4][2] = {};
#pragma unroll
  for (int ks = 0; ks < 2; ks++) {
    bf16x8 a[4], bb[2];
#pragma unroll
    for (int pt = 0; pt < 4; pt++) a[pt] = *(const bf16x8*)(Xs + (pt * 16 + fr) * 72 + ks * 32 + fq * 8);
#pragma unroll
    for (int n2 = 0; n2 < 2; n2++) bb[n2] = *(const bf16x8*)(Bs + ((2 * w + n2) * 16 + fr) * 72 + ks * 32 + fq * 8);
#pragma unroll
    for (int pt = 0; pt < 4; pt++)
#pragma unroll
      for (int n2 = 0; n2 < 2; n2++)
        acc[pt][n2] = __builtin_amdgcn_mfma_f32_16x16x32_bf16(a[pt], bb[n2], acc[pt][n2], 0, 0, 0);
  }
  bf16* outp = states + (size_t)bid * 8192;
#pragma unroll
  for (int pt = 0; pt < 4; pt++)
#pragma unroll
    for (int n2 = 0; n2 < 2; n2++) {
      int n = (2 * w + n2) * 16 + fr;
#pragma unroll
      for (int r = 0; r < 4; r++)
        outp[(size_t)(pt * 16 + fq * 4 + r) * 128 + n] = (bf16)acc[pt][n2][r];
    }
}

// ---------------- inter-chunk scan (in place, bf16 storage, f32 math) ----------------
__global__ __launch_bounds__(256) void ssd_scan(bf16* __restrict__ states,
                                                const float* __restrict__ T) {
  __shared__ float eT[NC];
  int part = blockIdx.x & 7;
  int bh = blockIdx.x >> 3;
  int b = bh / NH, h = bh % NH;
  if (threadIdx.x < NC) eT[threadIdx.x] = __expf(T[(size_t)(b * NH + h) * NC + threadIdx.x]);
  __syncthreads();
  const size_t cstride = (size_t)NH * HD * DS;
  size_t base = ((size_t)b * NC * NH + h) * (HD * DS);
#pragma unroll
  for (int j = 0; j < 4; j++) {
    int e = part * 1024 + threadIdx.x + j * 256;
    float carry = 0.f;
    size_t idx = base + e;
    for (int c = 0; c < NC; c++) {
      float sv = (float)states[idx];
      states[idx] = (bf16)carry;
      carry = sv + eT[c] * carry;
      idx += cstride;
    }
  }
}

// ---------------- fused SSD output: Ydiag + Yoff + D-skip + gate (all MFMA) ----------------
__global__ __launch_bounds__(256) void ssd_out(const bf16* __restrict__ Cn,
                                               const bf16* __restrict__ Bn,
                                               const bf16* __restrict__ Xt,
                                               const bf16* __restrict__ Zt,
                                               const float* __restrict__ dt_c,
                                               const float* __restrict__ ac_c,
                                               const bf16* __restrict__ states,
                                               const float* __restrict__ Dp,
                                               bf16* __restrict__ ybf) {
  __shared__ bf16 Cs[64 * 136];
  __shared__ bf16 BNs[64 * 136];
  __shared__ bf16 Xs[64 * 72];
  __shared__ bf16 G[64 * 72];
  __shared__ float acs[64];
  int bid = blockIdx.x;
  int h = bid % NH;
  int c = (bid / NH) % NC;
  int b = bid / (NH * NC);
  int tid = threadIdx.x, lane = tid & 63, w = tid >> 6;
  int fr = lane & 15, fq = lane >> 4;
  size_t row0 = (size_t)b * S_ + c * 64;
  const size_t abase = (size_t)(b * NH + h) * S_ + c * 64;
  if (tid < 64) acs[tid] = ac_c[abase + tid];
#pragma unroll
  for (int i = 0; i < 4; i++) {
    int cid = tid + i * 256; int l = cid >> 4, nc = (cid & 15) * 8;
    float e = __expf(ac_c[abase + l]);
    bf16x8 cv = *(const bf16x8*)(Cn + (row0 + l) * DS + nc);
    bf16x8 o;
#pragma unroll
    for (int j = 0; j < 8; j++) o[j] = (bf16)((float)cv[j] * e);
    *(bf16x8*)(Cs + l * 136 + nc) = o;
    *(bf16x8*)(BNs + l * 136 + nc) = *(const bf16x8*)(Bn + (row0 + l) * DS + nc);
  }
  const size_t xbase = (size_t)(b * NH + h) * HD * S_ + c * 64;
#pragma unroll
  for (int i = 0; i < 2; i++) {
    int cid = tid + i * 256; int p = cid >> 3, sc = (cid & 7) * 8;
    bf16x8 xv = *(const bf16x8*)(Xt + xbase + (size_t)p * S_ + sc);
    f32x4 d0 = *(const f32x4*)(dt_c + abase + sc);
    f32x4 d1 = *(const f32x4*)(dt_c + abase + sc + 4);
    bf16x8 o;
#pragma unroll
    for (int j = 0; j < 4; j++) { o[j] = (bf16)((float)xv[j] * d0[j]); o[4 + j] = (bf16)((float)xv[4 + j] * d1[j]); }
    *(bf16x8*)(Xs + p * 72 + sc) = o;
  }
  __syncthreads();
  bf16x8 ca[4];
#pragma unroll
  for (int ks = 0; ks < 4; ks++) ca[ks] = *(const bf16x8*)(Cs + (w * 16 + fr) * 136 + ks * 32 + fq * 8);
  f32x4 cb[4] = {};
  for (int st = 0; st <= w; st++)
#pragma unroll
    for (int ks = 0; ks < 4; ks++)
      cb[st] = __builtin_amdgcn_mfma_f32_16x16x32_bf16(ca[ks],
                 *(const bf16x8*)(BNs + (st * 16 + fr) * 136 + ks * 32 + fq * 8), cb[st], 0, 0, 0);
#pragma unroll
  for (int st = 0; st < 4; st++) {
    float es = (st <= w) ? __expf(-acs[st * 16 + fr]) : 0.f;
#pragma unroll
    for (int r = 0; r < 4; r++) {
      int lloc = fq * 4 + r;
      float g = 0.f;
      if (st < w) g = cb[st][r] * es;
      else if (st == w) g = (lloc >= fr) ? cb[st][r] * es : 0.f;
      G[(w * 16 + lloc) * 72 + st * 16 + fr] = (bf16)g;
    }
  }
  f32x4 acc[4] = {};
  {
    bf16x8 ga0 = *(const bf16x8*)(G + (w * 16 + fr) * 72 + fq * 8);
    bf16x8 ga1 = *(const bf16x8*)(G + (w * 16 + fr) * 72 + 32 + fq * 8);
#pragma unroll
    for (int pt = 0; pt < 4; pt++) {
      acc[pt] = __builtin_amdgcn_mfma_f32_16x16x32_bf16(ga0,
                  *(const bf16x8*)(Xs + (pt * 16 + fr) * 72 + fq * 8), acc[pt], 0, 0, 0);
      acc[pt] = __builtin_amdgcn_mfma_f32_16x16x32_bf16(ga1,
                  *(const bf16x8*)(Xs + (pt * 16 + fr) * 72 + 32 + fq * 8), acc[pt], 0, 0, 0);
    }
  }
  __syncthreads();
  const bf16* stp = states + (size_t)bid * 8192;
#pragma unroll
  for (int i = 0; i < 4; i++) {
    int cid = tid + i * 256; int p = cid >> 4, nc = (cid & 15) * 8;
    *(bf16x8*)(BNs + p * 136 + nc) = *(const bf16x8*)(stp + (size_t)p * 128 + nc);
  }
  __syncthreads();
#pragma unroll
  for (int pt = 0; pt < 4; pt++)
#pragma unroll
    for (int ks = 0; ks < 4; ks++)
      acc[pt] = __builtin_amdgcn_mfma_f32_16x16x32_bf16(ca[ks],
                  *(const bf16x8*)(BNs + (pt * 16 + fr) * 136 + ks * 32 + fq * 8), acc[pt], 0, 0, 0);
  float dph = Dp[h];
#pragma unroll
  for (int pt = 0; pt < 4; pt++) {
    int p = pt * 16 + fr;
    size_t tb = (xbase + (size_t)p * S_) + w * 16 + fq * 4;
    bf16x4 xs4 = *(const bf16x4*)(Xt + tb);
    bf16x4 z4  = *(const bf16x4*)(Zt + tb);
#pragma unroll
    for (int r = 0; r < 4; r++) {
      int l = w * 16 + fq * 4 + r;
      float yv = acc[pt][r] + (float)xs4[r] * dph;
      float z = (float)z4[r];
      yv *= z / (1.f + __expf(-z));
      ybf[((row0 + l) * NH + h) * HD + p] = (bf16)yv;
    }
  }
}

// ---------------- split-S MFMA flash attention (fixed-max softmax -> partials sum) ----------------
#define KSTR 72
#define PSTR 72
__global__ __launch_bounds__(256) void attn_mfma(const bf16* __restrict__ q,
                                                 const bf16* __restrict__ k,
                                                 const bf16* __restrict__ vtr,
                                                 bf16* __restrict__ Po,
                                                 float* __restrict__ Ls) {
  __shared__ bf16 Ks[2][64 * KSTR];
  __shared__ bf16 Vs[2][64 * KSTR];
  __shared__ bf16 Pl[4][32 * PSTR];
  int c = 39 - blockIdx.x;                 // full 8-iter chunks first
  int g = (c < 4) ? 0 : (c < 12) ? 1 : (c < 24) ? 2 : 3;
  int gbase = (g == 0) ? 0 : (g == 1) ? 4 : (g == 2) ? 12 : 24;
  int d = c - gbase;
  int qt = 4 * g + d / (g + 1);
  int sk = d % (g + 1);
  int h = blockIdx.y, b = blockIdx.z;
  int kvh = h >> 2;
  int tid = threadIdx.x, lane = tid & 63, w = tid >> 6;
  int fr = lane & 15, fq = lane >> 4;
  const float SC = 0.18033688011112042f;   // 0.125 * log2(e)
  const float M2 = 62.0f;
  int kt0 = sk * 8;
  int ktend = min(kt0 + 8, 2 * qt + 2);
  int qbase = qt * 128 + w * 32;           // wave's first q row
  int qmaxw = qbase + 31;
  bf16x8 bq[2][2];
#pragma unroll
  for (int qc = 0; qc < 2; qc++)
#pragma unroll
    for (int ks = 0; ks < 2; ks++)
      bq[qc][ks] = *(const bf16x8*)(q + (size_t)(b * S_ + qbase + qc * 16 + fr) * (HATT * HD)
                                      + h * HD + ks * 32 + fq * 8);
  int sr = tid >> 3, sc8 = (tid & 7) * 8;
  const bf16* kg = k + ((size_t)(b * S_) + sr) * (KVH * HD) + kvh * HD + sc8;
  const bf16* vg = vtr + ((size_t)(b * KVH + kvh) * HD + sr) * S_ + sc8;
  bf16x8 krg0, krg1, vrg0, vrg1;
  {
    const bf16* kp = kg + (size_t)kt0 * 64 * (KVH * HD);
    const bf16* vp = vg + (size_t)kt0 * 64;
    krg0 = *(const bf16x8*)(kp);
    krg1 = *(const bf16x8*)(kp + (size_t)32 * (KVH * HD));
    vrg0 = *(const bf16x8*)(vp);
    vrg1 = *(const bf16x8*)(vp + (size_t)32 * S_);
    *(bf16x8*)(&Ks[0][sr * KSTR + sc8]) = krg0;
    *(bf16x8*)(&Ks[0][(sr + 32) * KSTR + sc8]) = krg1;
    *(bf16x8*)(&Vs[0][sr * KSTR + sc8]) = vrg0;
    *(bf16x8*)(&Vs[0][(sr + 32) * KSTR + sc8]) = vrg1;
  }
  float lsum[2] = {0.f, 0.f};
  f32x4 yacc[2][4] = {};
  bf16* Plw = Pl[w];
  for (int kt = kt0; kt < ktend; kt++) {
    int cur = (kt - kt0) & 1;
    bool more = (kt + 1) < ktend;
    if (more) {
      const bf16* kp = kg + (size_t)(kt + 1) * 64 * (KVH * HD);
      const bf16* vp = vg + (size_t)(kt + 1) * 64;
      krg0 = *(const bf16x8*)(kp);
      krg1 = *(const bf16x8*)(kp + (size_t)32 * (KVH * HD));
      vrg0 = *(const bf16x8*)(vp);
      vrg1 = *(const bf16x8*)(vp + (size_t)32 * S_);
    }
    __syncthreads();
    if (kt * 64 <= qmaxw) {
#pragma unroll
      for (int mi = 0; mi < 4; mi++) {
        int s0 = kt * 64 + mi * 16;
        if (s0 > qmaxw) {
          bf16x4 zz = {};
#pragma unroll
          for (int qc = 0; qc < 2; qc++)
            *(bf16x4*)(Plw + (qc * 16 + fr) * PSTR + mi * 16 + fq * 4) = zz;
        } else {
          const bf16* krow = &Ks[cur][(mi * 16 + fr) * KSTR];
          bf16x8 ak0 = *(const bf16x8*)(krow + fq * 8);
          bf16x8 ak1 = *(const bf16x8*)(krow + 32 + fq * 8);
#pragma unroll
          for (int qc = 0; qc < 2; qc++) {
            f32x4 s = {};
            s = __builtin_amdgcn_mfma_f32_16x16x32_bf16(ak0, bq[qc][0], s, 0, 0, 0);
            s = __builtin_amdgcn_mfma_f32_16x16x32_bf16(ak1, bq[qc][1], s, 0, 0, 0);
            int qq = qbase + qc * 16 + fr;
            bf16x4 pk;
#pragma unroll
            for (int r = 0; r < 4; r++) {
              int sp = s0 + fq * 4 + r;
              float p = (sp <= qq) ? __builtin_amdgcn_exp2f(s[r] * SC - M2) : 0.f;
              lsum[qc] += p;
              pk[r] = (bf16)p;
            }
            *(bf16x4*)(Plw + (qc * 16 + fr) * PSTR + mi * 16 + fq * 4) = pk;
          }
        }
      }
#pragma unroll
      for (int ks2 = 0; ks2 < 2; ks2++) {
        bf16x8 bp[2];
#pragma unroll
        for (int qc = 0; qc < 2; qc++)
          bp[qc] = *(const bf16x8*)(Plw + (qc * 16 + fr) * PSTR + ks2 * 32 + fq * 8);
#pragma unroll
        for (int pi = 0; pi < 4; pi++) {
          bf16x8 av = *(const bf16x8*)(&Vs[cur][(pi * 16 + fr) * KSTR + ks2 * 32 + fq * 8]);
#pragma unroll
          for (int qc = 0; qc < 2; qc++)
            yacc[qc][pi] = __builtin_amdgcn_mfma_f32_16x16x32_bf16(av, bp[qc], yacc[qc][pi], 0, 0, 0);
        }
      }
    }
    if (more) {
      int nxt = cur ^ 1;
      *(bf16x8*)(&Ks[nxt][sr * KSTR + sc8]) = krg0;
      *(bf16x8*)(&Ks[nxt][(sr + 32) * KSTR + sc8]) = krg1;
      *(bf16x8*)(&Vs[nxt][sr * KSTR + sc8]) = vrg0;
      *(bf16x8*)(&Vs[nxt][(sr + 32) * KSTR + sc8]) = vrg1;
    }
  }
#pragma unroll
  for (int qc = 0; qc < 2; qc++) {
    lsum[qc] += __shfl_xor(lsum[qc], 16, 64);
    lsum[qc] += __shfl_xor(lsum[qc], 32, 64);
    int qrow = qt * 128 + w * 32 + qc * 16 + fr;
    if (fq == 0)
      Ls[((size_t)(b * 16 + h) * 2048 + qrow) * 4 + sk] = lsum[qc];
    bf16* pop = Po + ((((size_t)(b * 16 + h) * 16 + qt) * 4 + sk) * 128
                       + w * 32 + qc * 16 + fr) * 64 + fq * 4;
#pragma unroll
    for (int pi = 0; pi < 4; pi++) {
      bf16x4 o;
#pragma unroll
      for (int r = 0; r < 4; r++) o[r] = (bf16)yacc[qc][pi][r];
      *(bf16x4*)(pop + pi * 16) = o;
    }
  }
}

// ---------------- attention partial combine + normalize -> y2 bf16 ----------------
__global__ __launch_bounds__(256) void attn_red(const bf16* __restrict__ Po,
                                                const float* __restrict__ Ls,
                                                bf16* __restrict__ y2) {
  int row = blockIdx.x;            // 0..4095
  int b = row >> 11;
  int qrow = row & 2047;
  int qt = qrow >> 7, r = qrow & 127;
  int nch = (qt >> 2) + 1;
  int t = threadIdx.x;
  int h = t >> 4, e4 = (t & 15) << 2;
  const float* lp = Ls + ((size_t)(b * 16 + h) * 2048 + qrow) * 4;
  float ls = 0.f;
  f32x4 acc = {};
  for (int sk = 0; sk < nch; sk++) {
    ls += lp[sk];
    const bf16* pp = Po + ((((size_t)(b * 16 + h) * 16 + qt) * 4 + sk) * 128 + r) * 64 + e4;
    bf16x4 v = *(const bf16x4*)(pp);
#pragma unroll
    for (int j = 0; j < 4; j++) acc[j] += (float)v[j];
  }
  float inv = 1.f / ls;
  bf16x4 o;
#pragma unroll
  for (int j = 0; j < 4; j++) o[j] = (bf16)(acc[j] * inv);
  *(bf16x4*)(y2 + (size_t)row * 1024 + h * 64 + e4) = o;
}

// ---------------- workspace layout (byte offsets) ----------------
constexpr size_t OFF_WIN  = 0;                   // bf16 4480x1024
constexpr size_t OFF_WOUT = 9175040;             // bf16 1024x2048
constexpr size_t OFF_WQKV = 13369344;            // bf16 1536x1024 (q|k|v rows)
constexpr size_t OFF_WCP  = 16515072;            // bf16 1024x1024
constexpr size_t OFF_WFC  = 18612224;            // bf16 3072x1024
constexpr size_t OFF_WPR  = 24903680;            // bf16 1024x3072
constexpr size_t OFF_HBF  = 31195136;            // bf16 4096x1024
constexpr size_t OFF_BCDT = 39583744;            // bf16 4096x288; reused: Ls f32 (1 MiB)
constexpr size_t OFF_XT   = 41943040;            // bf16 [b][h][p][sg] (16.7 MB)
constexpr size_t OFF_ZT   = 58720256;            // bf16 [b][h][p][sg] (16.7 MB)
constexpr size_t OFF_DTC  = 75497472;            // f32 [b][h][sg]
constexpr size_t OFF_DDC  = 76546048;            // f32
constexpr size_t OFF_ACC  = 77594624;            // f32
constexpr size_t OFF_T    = 78643200;            // f32 2048
constexpr size_t OFF_BN   = 78651392;            // bf16 4096x128
constexpr size_t OFF_CN   = 79699968;            // bf16 4096x128
constexpr size_t OFF_BTR  = 80748544;            // bf16 [b][n][sg]
constexpr size_t OFF_ST   = 81797120;            // bf16 states (33.5 MB); reused: Po bf16 32 MiB
constexpr size_t OFF_YBF  = 148905984;           // bf16 4096x2048
constexpr size_t OFF_X1   = 165683200;           // f32 4096x1024 (end 182,460,416)
// phase-2 aliases
constexpr size_t OFF_P    = OFF_ST;              // bf16 split-K partials (<= 25.2 MB)
constexpr size_t OFF_PO   = OFF_ST;              // bf16 attn partials [b][h][qt][4][128][64] = 32 MiB
constexpr size_t OFF_LS   = OFF_BCDT;            // f32 attn lsums [b][h][2048][4] = 1 MiB
constexpr size_t OFF_QB   = OFF_XT;              // bf16 4096x1024 (8.4 MB)
constexpr size_t OFF_KB   = OFF_XT + 8388608;    // bf16 4096x256
constexpr size_t OFF_VB   = OFF_XT + 10485760;   // bf16 4096x256
constexpr size_t OFF_VTR  = OFF_XT + 12582912;   // bf16 [b][kvh][p][sg]
constexpr size_t OFF_Y2   = OFF_ZT;              // bf16 4096x1024
constexpr size_t OFF_X2   = 50331648;            // f32 4096x1024 (over dead kb/vb/vtr/y2)
constexpr size_t OFF_MLP  = 132128768;           // bf16 4096x3072 (over dead regions)

extern "C" void kernel_launch(void* const* d_in, const int* in_sizes, int n_in,
                              void* d_out, int out_size, void* d_ws, size_t ws_size,
                              hipStream_t stream) {
  (void)in_sizes; (void)n_in; (void)out_size; (void)ws_size;
  const float* x        = (const float*)d_in[0];
  const float* mnorm_w  = (const float*)d_in[1];
  const float* in_w     = (const float*)d_in[2];
  const float* out_w    = (const float*)d_in[3];
  const float* Dp       = (const float*)d_in[4];
  const float* dt_bias  = (const float*)d_in[5];
  const float* A_log    = (const float*)d_in[6];
  const float* Bn_w     = (const float*)d_in[7];
  const float* Cn_w     = (const float*)d_in[8];
  const float* ln1_w    = (const float*)d_in[9];
  const float* ln1_b    = (const float*)d_in[10];
  const float* cq_w     = (const float*)d_in[11];
  const float* ck_w     = (const float*)d_in[12];
  const float* cv_w     = (const float*)d_in[13];
  const float* cproj_w  = (const float*)d_in[14];
  const float* q_gain   = (const float*)d_in[15];
  const float* ln2_w    = (const float*)d_in[16];
  const float* ln2_b    = (const float*)d_in[17];
  const float* fc_w     = (const float*)d_in[18];
  const float* proj_w   = (const float*)d_in[19];
  float* out = (float*)d_out;
  char* W8 = (char*)d_ws;

  bf16* w_in   = (bf16*)(W8 + OFF_WIN);
  bf16* w_out  = (bf16*)(W8 + OFF_WOUT);
  bf16* w_qkv  = (bf16*)(W8 + OFF_WQKV);
  bf16* w_cp   = (bf16*)(W8 + OFF_WCP);
  bf16* w_fc   = (bf16*)(W8 + OFF_WFC);
  bf16* w_pr   = (bf16*)(W8 + OFF_WPR);
  bf16* h_bf   = (bf16*)(W8 + OFF_HBF);
  bf16* bcdt   = (bf16*)(W8 + OFF_BCDT);
  bf16* Xt     = (bf16*)(W8 + OFF_XT);
  bf16* Zt     = (bf16*)(W8 + OFF_ZT);
  float* dt_c  = (float*)(W8 + OFF_DTC);
  float* ddc   = (float*)(W8 + OFF_DDC);
  float* ac_c  = (float*)(W8 + OFF_ACC);
  float* Tb    = (float*)(W8 + OFF_T);
  bf16* Bn     = (bf16*)(W8 + OFF_BN);
  bf16* Cn     = (bf16*)(W8 + OFF_CN);
  bf16* Btr    = (bf16*)(W8 + OFF_BTR);
  bf16* st     = (bf16*)(W8 + OFF_ST);
  bf16* ybf    = (bf16*)(W8 + OFF_YBF);
  float* x1    = (float*)(W8 + OFF_X1);
  bf16* Pbuf   = (bf16*)(W8 + OFF_P);
  bf16* Po     = (bf16*)(W8 + OFF_PO);
  float* Ls    = (float*)(W8 + OFF_LS);
  bf16* qbf    = (bf16*)(W8 + OFF_QB);
  bf16* kbf    = (bf16*)(W8 + OFF_KB);
  bf16* vbf    = (bf16*)(W8 + OFF_VB);
  bf16* vtr    = (bf16*)(W8 + OFF_VTR);
  bf16* y2     = (bf16*)(W8 + OFF_Y2);
  float* x2    = (float*)(W8 + OFF_X2);
  bf16* mlp    = (bf16*)(W8 + OFF_MLP);

  // ---- weight casts (single launch; q/k/v cast into adjacent rows of w_qkv) ----
  CastArgs ca;
  ca.seg[0] = { in_w,    w_in,            4489216, 4587520, 0     };
  ca.seg[1] = { out_w,   w_out,           2097152, 2097152, 4480  };
  ca.seg[2] = { cq_w,    w_qkv,           1048576, 1048576, 6528  };
  ca.seg[3] = { ck_w,    w_qkv + 1048576,  262144,  262144, 7552  };
  ca.seg[4] = { cv_w,    w_qkv + 1310720,  262144,  262144, 7808  };
  ca.seg[5] = { cproj_w, w_cp,            1048576, 1048576, 8064  };
  ca.seg[6] = { fc_w,    w_fc,            3145728, 3145728, 9088  };
  ca.seg[7] = { proj_w,  w_pr,            3145728, 3145728, 12160 };
  castw_all<<<15232, 256, 0, stream>>>(ca);

  const size_t PS  = (size_t)ROWS * 1024;   // partial stride (elements) for N=1024 GEMMs

  // ---- mamba block ----
  rmsnorm_k<<<ROWS, 256, 0, stream>>>(x, mnorm_w, h_bf, D_);
  gemm_inproj<<<32 * 35, 256, 0, stream>>>(h_bf, w_in, Zt, Xt, bcdt);
  ssd_prep<<<B_ * NH * NC, 64, 0, stream>>>(bcdt, dt_bias, A_log, dt_c, ddc, ac_c, Tb);
  bc_norm<<<ROWS, 128, 0, stream>>>(bcdt, Bn_w, Cn_w, Bn, Cn);
  t64<<<2 * 2 * 32, 256, 0, stream>>>(Bn, Btr, 128, (size_t)2048 * 128, (size_t)128 * 2048, 2);
  ssd_states<<<B_ * NC * NH, 256, 0, stream>>>(Xt, Btr, ddc, st);
  ssd_scan<<<B_ * NH * 8, 256, 0, stream>>>(st, Tb);
  ssd_out<<<B_ * NC * NH, 256, 0, stream>>>(Cn, Bn, Xt, Zt, dt_c, ac_c, st, Dp, ybf);
  // out_proj: split-K=2 then fused reduce+residual+LN1
  gemm_sk<<<dim3(32 * 8, 1, 2), 256, 0, stream>>>(ybf, w_out, Pbuf, ROWS, D_, DI, 1024);
  reduce_ln2<<<ROWS, 256, 0, stream>>>(Pbuf, Pbuf + PS, x, ln1_w, ln1_b, x1, h_bf);

  // ---- attention block ----
  gemm_sk<<<dim3(32 * 12, 1, 2), 256, 0, stream>>>(h_bf, w_qkv, Pbuf, ROWS, 1536, D_, 512);
  reduce_qkv<<<ROWS, 256, 0, stream>>>(Pbuf, q_gain, qbf, kbf, vbf);
  t64<<<2 * 4 * 32, 256, 0, stream>>>(vbf, vtr, 256, (size_t)2048 * 256, (size_t)256 * 2048, 4);
  attn_mfma<<<dim3(40, HATT, B_), 256, 0, stream>>>(qbf, kbf, vtr, Po, Ls);
  attn_red<<<ROWS, 256, 0, stream>>>(Po, Ls, y2);
  gemm_sk<<<dim3(32 * 8, 1, 2), 256, 0, stream>>>(y2, w_cp, Pbuf, ROWS, D_, D_, 512);
  reduce_ln2<<<ROWS, 256, 0, stream>>>(Pbuf, Pbuf + PS, x1, ln2_w, ln2_b, x2, h_bf);

  // ---- MLP ----
  gemm_mfma<1, bf16><<<32 * 24, 256, 0, stream>>>(h_bf, w_fc, nullptr, mlp, ROWS, MLP, D_);
  gemm_sk<<<dim3(32 * 8, 1, 3), 256, 0, stream>>>(mlp, w_pr, Pbuf, ROWS, D_, MLP, 1024);
  reduce_out3<<<ROWS, 256, 0, stream>>>(Pbuf, Pbuf + PS, Pbuf + 2 * PS, x2, out);
}

// Round 11
// 514.606 us; speedup vs baseline: 1.4415x; 1.0244x over previous
//
#include <hip/hip_runtime.h>
#include <hip/hip_bf16.h>
#include <math.h>

// ---------------- problem constants ----------------
#define B_    2
#define S_    2048
#define D_    1024
#define DI    2048      // D_INNER
#define NH    32        // NHEADS (mamba)
#define HD    64        // HEADDIM
#define DS    128       // D_STATE
#define CH    64        // CHUNK
#define NC    32        // S_/CH
#define DP    4384      // D_PROJ
#define HATT  16        // attention heads
#define KVH   4         // kv heads
#define RD    16        // rope dims
#define MLP   3072
#define ROWS  (B_*S_)   // 4096

typedef __bf16 bf16;
typedef __bf16 bf16x8 __attribute__((ext_vector_type(8)));
typedef __bf16 bf16x4 __attribute__((ext_vector_type(4)));
typedef float  f32x4  __attribute__((ext_vector_type(4)));

__device__ __forceinline__ void async_copy16(const void* g, void* l) {
  __builtin_amdgcn_global_load_lds(
      (const __attribute__((address_space(1))) unsigned int*)g,
      (__attribute__((address_space(3))) unsigned int*)l, 16, 0, 0);
}

// ---------------- reductions ----------------
__device__ __forceinline__ float waveReduceSum(float v) {
#pragma unroll
  for (int off = 32; off > 0; off >>= 1) v += __shfl_down(v, off, 64);
  return v;
}

template<int NW>
__device__ __forceinline__ float blockReduceSum(float v, float* sh) {
  v = waveReduceSum(v);
  int lane = threadIdx.x & 63, wid = threadIdx.x >> 6;
  if (lane == 0) sh[wid] = v;
  __syncthreads();
  float s = 0.f;
#pragma unroll
  for (int i = 0; i < NW; i++) s += sh[i];
  __syncthreads();
  return s;
}

// ---------------- merged weight cast f32 -> bf16 ----------------
struct CastSeg { const float* src; bf16* dst; int nval; int ntot; int blk0; };
struct CastArgs { CastSeg seg[8]; };

__global__ __launch_bounds__(256) void castw_all(CastArgs a) {
  int blk = blockIdx.x;
  int si = 0;
#pragma unroll
  for (int i = 1; i < 8; i++) if (blk >= a.seg[i].blk0) si = i;
  CastSeg s = a.seg[si];
  int i = ((blk - s.blk0) * 256 + threadIdx.x) * 4;
  if (i >= s.ntot) return;
  float4 v = {0.f, 0.f, 0.f, 0.f};
  if (i < s.nval) v = *(const float4*)(s.src + i);
  bf16x4 o;
  o[0] = (bf16)v.x; o[1] = (bf16)v.y; o[2] = (bf16)v.z; o[3] = (bf16)v.w;
  *(bf16x4*)(s.dst + i) = o;
}

// ---------------- rmsnorm (f32 in, bf16 out) ----------------
__global__ __launch_bounds__(256) void rmsnorm_k(const float* __restrict__ x,
                                                 const float* __restrict__ w,
                                                 bf16* __restrict__ y, int n) {
  __shared__ float sh[4];
  size_t row = blockIdx.x;
  const float* xr = x + row * n;
  bf16* yr = y + row * n;
  float ss = 0.f;
  for (int i = threadIdx.x; i < n; i += 256) { float v = xr[i]; ss += v * v; }
  ss = blockReduceSum<4>(ss, sh);
  float inv = rsqrtf(ss / n + 1e-5f);
  for (int i = threadIdx.x; i < n; i += 256) yr[i] = (bf16)(xr[i] * inv * w[i]);
}

// ---------------- generic bf16 MFMA GEMM: C = act(A @ W^T), bm-fastest 1D grid ----------------
template<int ACT, typename OT>
__global__ __launch_bounds__(256) void gemm_mfma(const bf16* __restrict__ A,
                                                 const bf16* __restrict__ W,
                                                 const float* __restrict__ R,
                                                 OT* __restrict__ C,
                                                 int M, int N, int K) {
  __shared__ bf16 As[128 * 32];
  __shared__ bf16 Ws[128 * 32];
  int tid = threadIdx.x, lane = tid & 63, wave = tid >> 6;
  int mt = M >> 7;
  int bid = blockIdx.x;
  int bm = (bid % mt) * 128, bn = (bid / mt) * 128;
  const bf16* gA0 = A + (size_t)(bm + wave * 32 + (lane >> 2)) * K + (lane & 3) * 8;
  const bf16* gA1 = gA0 + (size_t)16 * K;
  const bf16* gW0 = W + (size_t)(bn + wave * 32 + (lane >> 2)) * K + (lane & 3) * 8;
  const bf16* gW1 = gW0 + (size_t)16 * K;
  bf16* lA0 = As + wave * 32 * 32;
  bf16* lA1 = lA0 + 16 * 32;
  bf16* lW0 = Ws + wave * 32 * 32;
  bf16* lW1 = lW0 + 16 * 32;
  int fr = lane & 15, fq = lane >> 4;
  int wm = wave >> 1, wn = wave & 1;
  const bf16* pA = As + (wm * 64 + fr) * 32 + fq * 8;
  const bf16* pW = Ws + (wn * 64 + fr) * 32 + fq * 8;
  f32x4 acc[4][4] = {};
  for (int k0 = 0; k0 < K; k0 += 32) {
    async_copy16(gA0, lA0);
    async_copy16(gA1, lA1);
    async_copy16(gW0, lW0);
    async_copy16(gW1, lW1);
    gA0 += 32; gA1 += 32; gW0 += 32; gW1 += 32;
    __syncthreads();
    bf16x8 af[4], bfr[4];
#pragma unroll
    for (int mi = 0; mi < 4; mi++) af[mi] = *(const bf16x8*)(pA + mi * 16 * 32);
#pragma unroll
    for (int ni = 0; ni < 4; ni++) bfr[ni] = *(const bf16x8*)(pW + ni * 16 * 32);
#pragma unroll
    for (int mi = 0; mi < 4; mi++)
#pragma unroll
      for (int ni = 0; ni < 4; ni++)
        acc[mi][ni] = __builtin_amdgcn_mfma_f32_16x16x32_bf16(af[mi], bfr[ni], acc[mi][ni], 0, 0, 0);
    __syncthreads();
  }
#pragma unroll
  for (int mi = 0; mi < 4; mi++) {
    int row = bm + wm * 64 + mi * 16 + fq * 4;
#pragma unroll
    for (int ni = 0; ni < 4; ni++) {
      int col = bn + wn * 64 + ni * 16 + fr;
      if (col < N) {
#pragma unroll
        for (int r = 0; r < 4; r++) {
          float v = acc[mi][ni][r];
          if (ACT == 1) v = v / (1.f + __expf(-v));
          if (R) v += R[(size_t)(row + r) * N + col];
          C[(size_t)(row + r) * N + col] = (OT)v;
        }
      }
    }
  }
}

// ---------------- split-K bf16 MFMA GEMM: P[ks] = A @ W^T (bf16 partials) ----------------
__global__ __launch_bounds__(256) void gemm_sk(const bf16* __restrict__ A,
                                               const bf16* __restrict__ W,
                                               bf16* __restrict__ P,
                                               int M, int N, int K, int kchunk) {
  __shared__ bf16 As[128 * 32];
  __shared__ bf16 Ws[128 * 32];
  int tid = threadIdx.x, lane = tid & 63, wave = tid >> 6;
  int mt = M >> 7;
  int bid = blockIdx.x;
  int bm = (bid % mt) * 128, bn = (bid / mt) * 128;
  int ks = blockIdx.z;
  int kbeg = ks * kchunk;
  const bf16* gA0 = A + (size_t)(bm + wave * 32 + (lane >> 2)) * K + kbeg + (lane & 3) * 8;
  const bf16* gA1 = gA0 + (size_t)16 * K;
  const bf16* gW0 = W + (size_t)(bn + wave * 32 + (lane >> 2)) * K + kbeg + (lane & 3) * 8;
  const bf16* gW1 = gW0 + (size_t)16 * K;
  bf16* lA0 = As + wave * 32 * 32;
  bf16* lA1 = lA0 + 16 * 32;
  bf16* lW0 = Ws + wave * 32 * 32;
  bf16* lW1 = lW0 + 16 * 32;
  int fr = lane & 15, fq = lane >> 4;
  int wm = wave >> 1, wn = wave & 1;
  const bf16* pA = As + (wm * 64 + fr) * 32 + fq * 8;
  const bf16* pW = Ws + (wn * 64 + fr) * 32 + fq * 8;
  f32x4 acc[4][4] = {};
  for (int k0 = 0; k0 < kchunk; k0 += 32) {
    async_copy16(gA0, lA0);
    async_copy16(gA1, lA1);
    async_copy16(gW0, lW0);
    async_copy16(gW1, lW1);
    gA0 += 32; gA1 += 32; gW0 += 32; gW1 += 32;
    __syncthreads();
    bf16x8 af[4], bfr[4];
#pragma unroll
    for (int mi = 0; mi < 4; mi++) af[mi] = *(const bf16x8*)(pA + mi * 16 * 32);
#pragma unroll
    for (int ni = 0; ni < 4; ni++) bfr[ni] = *(const bf16x8*)(pW + ni * 16 * 32);
#pragma unroll
    for (int mi = 0; mi < 4; mi++)
#pragma unroll
      for (int ni = 0; ni < 4; ni++)
        acc[mi][ni] = __builtin_amdgcn_mfma_f32_16x16x32_bf16(af[mi], bfr[ni], acc[mi][ni], 0, 0, 0);
    __syncthreads();
  }
  bf16* Pp = P + (size_t)ks * M * N;
#pragma unroll
  for (int mi = 0; mi < 4; mi++) {
    int row = bm + wm * 64 + mi * 16 + fq * 4;
#pragma unroll
    for (int ni = 0; ni < 4; ni++) {
      int col = bn + wn * 64 + ni * 16 + fr;
#pragma unroll
      for (int r = 0; r < 4; r++)
        Pp[(size_t)(row + r) * N + col] = (bf16)acc[mi][ni][r];
    }
  }
}

// ---------------- reduce 2 bf16 partials + residual + layernorm -> x_out f32, h bf16 ----------------
__global__ __launch_bounds__(256) void reduce_ln2(const bf16* __restrict__ p0,
                                                  const bf16* __restrict__ p1,
                                                  const float* __restrict__ res,
                                                  const float* __restrict__ w,
                                                  const float* __restrict__ b,
                                                  float* __restrict__ xo,
                                                  bf16* __restrict__ ho) {
  __shared__ float sh[4];
  size_t o = (size_t)blockIdx.x * 1024;
  int i = threadIdx.x * 4;
  bf16x4 a = *(const bf16x4*)(p0 + o + i);
  bf16x4 c = *(const bf16x4*)(p1 + o + i);
  f32x4 rv = *(const f32x4*)(res + o + i);
  f32x4 v;
  float s = 0.f, s2 = 0.f;
#pragma unroll
  for (int j = 0; j < 4; j++) {
    v[j] = (float)a[j] + (float)c[j] + rv[j];
    s += v[j]; s2 += v[j] * v[j];
  }
  s  = blockReduceSum<4>(s,  sh);
  s2 = blockReduceSum<4>(s2, sh);
  float mean = s / 1024.f;
  float var  = s2 / 1024.f - mean * mean;
  float inv  = rsqrtf(var + 1e-5f);
  f32x4 wv = *(const f32x4*)(w + i);
  f32x4 bv = *(const f32x4*)(b + i);
  *(f32x4*)(xo + o + i) = v;
  bf16x4 hv;
#pragma unroll
  for (int j = 0; j < 4; j++) hv[j] = (bf16)((v[j] - mean) * inv * wv[j] + bv[j]);
  *(bf16x4*)(ho + o + i) = hv;
}

// ---------------- reduce 3 bf16 partials + residual -> out f32 ----------------
__global__ __launch_bounds__(256) void reduce_out3(const bf16* __restrict__ p0,
                                                   const bf16* __restrict__ p1,
                                                   const bf16* __restrict__ p2,
                                                   const float* __restrict__ res,
                                                   float* __restrict__ out) {
  int i = (blockIdx.x * 256 + threadIdx.x) * 4;
  bf16x4 a = *(const bf16x4*)(p0 + i);
  bf16x4 c = *(const bf16x4*)(p1 + i);
  bf16x4 d = *(const bf16x4*)(p2 + i);
  f32x4 v = *(const f32x4*)(res + i);
#pragma unroll
  for (int j = 0; j < 4; j++) v[j] += (float)a[j] + (float)c[j] + (float)d[j];
  *(f32x4*)(out + i) = v;
}

// ---------------- reduce qkv bf16 partials + q/k rmsnorm + rope + gain -> bf16 ----------------
__global__ __launch_bounds__(256) void reduce_qkv(const bf16* __restrict__ P,
                                                  const float* __restrict__ q_gain,
                                                  bf16* __restrict__ q,
                                                  bf16* __restrict__ k,
                                                  bf16* __restrict__ v) {
  __shared__ float buf[1536];
  size_t row = blockIdx.x;
  size_t o = row * 1536;
  const bf16* p0 = P + o;
  const bf16* p1 = P + (size_t)ROWS * 1536 + o;
  int tid = threadIdx.x;
  for (int i = tid; i < 384; i += 256) {
    bf16x4 a = *(const bf16x4*)(p0 + i * 4);
    bf16x4 c = *(const bf16x4*)(p1 + i * 4);
    f32x4 vv;
#pragma unroll
    for (int j = 0; j < 4; j++) vv[j] = (float)a[j] + (float)c[j];
    *(f32x4*)(buf + i * 4) = vv;
  }
  __syncthreads();
  int lane = tid & 63, w = tid >> 6;
  int s = (int)(row & (S_ - 1));
  int ri = lane & 7;
  float rinv = __expf(-(float)ri * (0.125f * 9.210340371976184f)); // 10000^(-i/8)
  float ang = (float)s * rinv;
  float cs = cosf(ang), sn = sinf(ang);
#pragma unroll
  for (int j = 0; j < 6; j++) {
    int hh = w * 6 + j;
    float val = buf[hh * 64 + lane];
    if (hh < 20) {
      float ss = val * val;
#pragma unroll
      for (int off = 32; off > 0; off >>= 1) ss += __shfl_xor(ss, off, 64);
      val *= rsqrtf(ss / 64.f + 1.1920929e-7f);
      float other = __shfl_xor(val, 8, 64);
      float res = val;
      if (lane < RD) res = (lane < 8) ? (val * cs + other * sn) : (val * cs - other * sn);
      if (hh < 16) {
        res *= q_gain[hh];
        q[row * (HATT * HD) + hh * HD + lane] = (bf16)res;
      } else {
        k[row * (KVH * HD) + (hh - 16) * HD + lane] = (bf16)res;
      }
    } else {
      v[row * (KVH * HD) + (hh - 20) * HD + lane] = (bf16)val;
    }
  }
}

// ---------------- in_proj GEMM: LDS-transposed coalesced Zt/Xt epilogue + bcdt ----------------
__global__ __launch_bounds__(256) void gemm_inproj(const bf16* __restrict__ A,
                                                   const bf16* __restrict__ W,
                                                   bf16* __restrict__ zt,
                                                   bf16* __restrict__ xt,
                                                   bf16* __restrict__ bcdt) {
  const int K = 1024;
  __shared__ bf16 As[128 * 32];
  __shared__ bf16 Ws[128 * 32];
  __shared__ bf16 Ts[64 * 136];
  int tid = threadIdx.x, lane = tid & 63, wave = tid >> 6;
  int bid = blockIdx.x;
  int bm = (bid & 31) * 128, bn = (bid >> 5) * 128;
  const bf16* gA0 = A + (size_t)(bm + wave * 32 + (lane >> 2)) * K + (lane & 3) * 8;
  const bf16* gA1 = gA0 + (size_t)16 * K;
  const bf16* gW0 = W + (size_t)(bn + wave * 32 + (lane >> 2)) * K + (lane & 3) * 8;
  const bf16* gW1 = gW0 + (size_t)16 * K;
  bf16* lA0 = As + wave * 32 * 32;
  bf16* lA1 = lA0 + 16 * 32;
  bf16* lW0 = Ws + wave * 32 * 32;
  bf16* lW1 = lW0 + 16 * 32;
  int fr = lane & 15, fq = lane >> 4;
  int wm = wave >> 1, wn = wave & 1;
  const bf16* pA = As + (wm * 64 + fr) * 32 + fq * 8;
  const bf16* pW = Ws + (wn * 64 + fr) * 32 + fq * 8;
  f32x4 acc[4][4] = {};
  for (int k0 = 0; k0 < K; k0 += 32) {
    async_copy16(gA0, lA0);
    async_copy16(gA1, lA1);
    async_copy16(gW0, lW0);
    async_copy16(gW1, lW1);
    gA0 += 32; gA1 += 32; gW0 += 32; gW1 += 32;
    __syncthreads();
    bf16x8 af[4], bfr[4];
#pragma unroll
    for (int mi = 0; mi < 4; mi++) af[mi] = *(const bf16x8*)(pA + mi * 16 * 32);
#pragma unroll
    for (int ni = 0; ni < 4; ni++) bfr[ni] = *(const bf16x8*)(pW + ni * 16 * 32);
#pragma unroll
    for (int mi = 0; mi < 4; mi++)
#pragma unroll
      for (int ni = 0; ni < 4; ni++)
        acc[mi][ni] = __builtin_amdgcn_mfma_f32_16x16x32_bf16(af[mi], bfr[ni], acc[mi][ni], 0, 0, 0);
    __syncthreads();
  }
  if (bn < 4096) {
    bf16* base = (bn < 2048) ? zt : xt;
    int bq = bm >> 11, bmS = bm & 2047;
#pragma unroll
    for (int p = 0; p < 2; p++) {
      __syncthreads();
      if (wn == p) {
#pragma unroll
        for (int mi = 0; mi < 4; mi++)
#pragma unroll
          for (int ni = 0; ni < 4; ni++) {
            bf16x4 o;
#pragma unroll
            for (int r = 0; r < 4; r++) o[r] = (bf16)acc[mi][ni][r];
            *(bf16x4*)(Ts + (ni * 16 + fr) * 136 + wm * 64 + mi * 16 + fq * 4) = o;
          }
      }
      __syncthreads();
      int hh = ((bn & 2047) + p * 64) >> 6;
      bf16* dst = base + ((size_t)(bq * NH + hh) * HD) * S_ + bmS;
#pragma unroll
      for (int i = 0; i < 4; i++) {
        int idx = tid + i * 256;
        int cl = idx >> 4, sgc = (idx & 15) * 8;
        *(bf16x8*)(dst + (size_t)cl * S_ + sgc) = *(const bf16x8*)(Ts + cl * 136 + sgc);
      }
    }
  } else {
#pragma unroll
    for (int mi = 0; mi < 4; mi++) {
      int row0m = bm + wm * 64 + mi * 16 + fq * 4;
#pragma unroll
      for (int ni = 0; ni < 4; ni++) {
        int col = bn + wn * 64 + ni * 16 + fr;
        if (col < 4384) {
#pragma unroll
          for (int r = 0; r < 4; r++)
            bcdt[(size_t)(row0m + r) * 288 + (col - 4096)] = (bf16)acc[mi][ni][r];
        }
      }
    }
  }
}

// ---------------- generic 64x64 tiled transpose (bf16), out row stride 2048 ----------------
__global__ __launch_bounds__(256) void t64(const bf16* __restrict__ in, bf16* __restrict__ out,
                                           int istr, size_t io, size_t oo, int n_nt) {
  __shared__ bf16 T[64 * 72];
  int bid = blockIdx.x;
  int st = bid & 31;
  int nt = (bid >> 5) % n_nt;
  int outer = bid / (32 * n_nt);
  const bf16* ip = in + outer * io + (size_t)st * 64 * istr + nt * 64;
  int tid = threadIdx.x;
#pragma unroll
  for (int i = 0; i < 2; i++) {
    int cid = tid + i * 256; int s = cid >> 3, pc = (cid & 7) * 8;
    *(bf16x8*)(T + s * 72 + pc) = *(const bf16x8*)(ip + (size_t)s * istr + pc);
  }
  __syncthreads();
  bf16* op = out + outer * oo + (size_t)nt * 64 * 2048 + st * 64;
#pragma unroll
  for (int i = 0; i < 2; i++) {
    int cid = tid + i * 256; int p = cid >> 3, sc = (cid & 7) * 8;
    bf16x8 o;
#pragma unroll
    for (int j = 0; j < 8; j++) o[j] = T[(sc + j) * 72 + p];
    *(bf16x8*)(op + (size_t)p * 2048 + sc) = o;
  }
}

// ---------------- SSD prep: dt softplus, per-chunk cumsum, decay factors ----------------
__global__ __launch_bounds__(64) void ssd_prep(const bf16* __restrict__ bcdt,
                                               const float* __restrict__ dt_bias,
                                               const float* __restrict__ A_log,
                                               float* __restrict__ dt_c,
                                               float* __restrict__ ddc,
                                               float* __restrict__ ac_c,
                                               float* __restrict__ T_out) {
  int bid = blockIdx.x;
  int c = bid % NC, hh = (bid / NC) % NH, b = bid / (NC * NH);
  int l = threadIdx.x;
  size_t row = (size_t)b * S_ + c * 64 + l;
  float raw = (float)bcdt[row * 288 + 256 + hh] + dt_bias[hh];
  float dtv = (raw > 20.f) ? raw : log1pf(__expf(raw));
  float a = -__expf(A_log[hh]) * dtv;
  float ps = a;
#pragma unroll
  for (int off = 1; off < 64; off <<= 1) {
    float t = __shfl_up(ps, off, 64);
    if (l >= off) ps += t;
  }
  float a63 = __shfl(ps, 63, 64);
  size_t o = ((size_t)b * NH + hh) * S_ + c * 64 + l;
  dt_c[o] = dtv;
  ac_c[o] = ps;
  ddc[o] = __expf(a63 - ps) * dtv;
  if (l == 63) T_out[(b * NH + hh) * NC + c] = ps;
}

// ---------------- B/C rmsnorm (bf16 out) ----------------
__global__ __launch_bounds__(128) void bc_norm(const bf16* __restrict__ bcdt,
                                               const float* __restrict__ Bw,
                                               const float* __restrict__ Cw,
                                               bf16* __restrict__ Bn,
                                               bf16* __restrict__ Cn) {
  __shared__ float shb[2], shc[2];
  size_t row = blockIdx.x;
  int i = threadIdx.x;
  float bv = (float)bcdt[row * 288 + i];
  float cv = (float)bcdt[row * 288 + 128 + i];
  float sb = waveReduceSum(bv * bv);
  float sc = waveReduceSum(cv * cv);
  int lane = threadIdx.x & 63, wid = threadIdx.x >> 6;
  if (lane == 0) { shb[wid] = sb; shc[wid] = sc; }
  __syncthreads();
  float tb = shb[0] + shb[1];
  float tc = shc[0] + shc[1];
  Bn[row * DS + i] = (bf16)(bv * rsqrtf(tb / DS + 1e-5f) * Bw[i]);
  Cn[row * DS + i] = (bf16)(cv * rsqrtf(tc / DS + 1e-5f) * Cw[i]);
}

// ---------------- chunk states via MFMA (bf16 output) ----------------
__global__ __launch_bounds__(256) void ssd_states(const bf16* __restrict__ Xt,
                                                  const bf16* __restrict__ Btr,
                                                  const float* __restrict__ ddc,
                                                  bf16* __restrict__ states) {
  __shared__ bf16 Xs[64 * 72];    // [p][s]
  __shared__ bf16 Bs[128 * 72];   // [n][s]
  int bid = blockIdx.x;           // (b*NC + c)*NH + h
  int h = bid % NH;
  int c = (bid / NH) % NC;
  int b = bid / (NH * NC);
  int tid = threadIdx.x, lane = tid & 63, w = tid >> 6;
  int fr = lane & 15, fq = lane >> 4;
  const size_t xbase = (size_t)(b * NH + h) * HD * S_ + c * 64;
  const size_t dbase = (size_t)(b * NH + h) * S_ + c * 64;
#pragma unroll
  for (int i = 0; i < 2; i++) {
    int cid = tid + i * 256; int p = cid >> 3, sc = (cid & 7) * 8;
    bf16x8 xv = *(const bf16x8*)(Xt + xbase + (size_t)p * S_ + sc);
    f32x4 d0 = *(const f32x4*)(ddc + dbase + sc);
    f32x4 d1 = *(const f32x4*)(ddc + dbase + sc + 4);
    bf16x8 o;
#pragma unroll
    for (int j = 0; j < 4; j++) { o[j] = (bf16)((float)xv[j] * d0[j]); o[4 + j] = (bf16)((float)xv[4 + j] * d1[j]); }
    *(bf16x8*)(Xs + p * 72 + sc) = o;
  }
  const size_t bbase = (size_t)b * 128 * S_ + c * 64;
#pragma unroll
  for (int i = 0; i < 4; i++) {
    int cid = tid + i * 256; int n = cid >> 3, sc = (cid & 7) * 8;
    *(bf16x8*)(Bs + n * 72 + sc) = *(const bf16x8*)(Btr + bbase + (size_t)n * S_ + sc);
  }
  __syncthreads();
  f32x4 acc[4][2] = {};
#pragma unroll
  for (int ks = 0; ks < 2; ks++) {
    bf16x8 a[4], bb[2];
#pragma unroll
    for (int pt = 0; pt < 4; pt++) a[pt] = *(const bf16x8*)(Xs + (pt * 16 + fr) * 72 + ks * 32 + fq * 8);
#pragma unroll
    for (int n2 = 0; n2 < 2; n2++) bb[n2] = *(const bf16x8*)(Bs + ((2 * w + n2) * 16 + fr) * 72 + ks * 32 + fq * 8);
#pragma unroll
    for (int pt = 0; pt < 4; pt++)
#pragma unroll
      for (int n2 = 0; n2 < 2; n2++)
        acc[pt][n2] = __builtin_amdgcn_mfma_f32_16x16x32_bf16(a[pt], bb[n2], acc[pt][n2], 0, 0, 0);
  }
  bf16* outp = states + (size_t)bid * 8192;
#pragma unroll
  for (int pt = 0; pt < 4; pt++)
#pragma unroll
    for (int n2 = 0; n2 < 2; n2++) {
      int n = (2 * w + n2) * 16 + fr;
#pragma unroll
      for (int r = 0; r < 4; r++)
        outp[(size_t)(pt * 16 + fq * 4 + r) * 128 + n] = (bf16)acc[pt][n2][r];
    }
}

// ---------------- inter-chunk scan (in place, bf16 storage, f32 math) ----------------
__global__ __launch_bounds__(256) void ssd_scan(bf16* __restrict__ states,
                                                const float* __restrict__ T) {
  __shared__ float eT[NC];
  int part = blockIdx.x & 7;
  int bh = blockIdx.x >> 3;
  int b = bh / NH, h = bh % NH;
  if (threadIdx.x < NC) eT[threadIdx.x] = __expf(T[(size_t)(b * NH + h) * NC + threadIdx.x]);
  __syncthreads();
  const size_t cstride = (size_t)NH * HD * DS;
  size_t base = ((size_t)b * NC * NH + h) * (HD * DS);
#pragma unroll
  for (int j = 0; j < 4; j++) {
    int e = part * 1024 + threadIdx.x + j * 256;
    float carry = 0.f;
    size_t idx = base + e;
    for (int c = 0; c < NC; c++) {
      float sv = (float)states[idx];
      states[idx] = (bf16)carry;
      carry = sv + eT[c] * carry;
      idx += cstride;
    }
  }
}

// ---------------- fused SSD output: Ydiag + Yoff + D-skip + gate (all MFMA) ----------------
__global__ __launch_bounds__(256) void ssd_out(const bf16* __restrict__ Cn,
                                               const bf16* __restrict__ Bn,
                                               const bf16* __restrict__ Xt,
                                               const bf16* __restrict__ Zt,
                                               const float* __restrict__ dt_c,
                                               const float* __restrict__ ac_c,
                                               const bf16* __restrict__ states,
                                               const float* __restrict__ Dp,
                                               bf16* __restrict__ ybf) {
  __shared__ bf16 Cs[64 * 136];
  __shared__ bf16 BNs[64 * 136];
  __shared__ bf16 Xs[64 * 72];
  __shared__ bf16 G[64 * 72];
  __shared__ float acs[64];
  int bid = blockIdx.x;
  int h = bid % NH;
  int c = (bid / NH) % NC;
  int b = bid / (NH * NC);
  int tid = threadIdx.x, lane = tid & 63, w = tid >> 6;
  int fr = lane & 15, fq = lane >> 4;
  size_t row0 = (size_t)b * S_ + c * 64;
  const size_t abase = (size_t)(b * NH + h) * S_ + c * 64;
  if (tid < 64) acs[tid] = ac_c[abase + tid];
#pragma unroll
  for (int i = 0; i < 4; i++) {
    int cid = tid + i * 256; int l = cid >> 4, nc = (cid & 15) * 8;
    float e = __expf(ac_c[abase + l]);
    bf16x8 cv = *(const bf16x8*)(Cn + (row0 + l) * DS + nc);
    bf16x8 o;
#pragma unroll
    for (int j = 0; j < 8; j++) o[j] = (bf16)((float)cv[j] * e);
    *(bf16x8*)(Cs + l * 136 + nc) = o;
    *(bf16x8*)(BNs + l * 136 + nc) = *(const bf16x8*)(Bn + (row0 + l) * DS + nc);
  }
  const size_t xbase = (size_t)(b * NH + h) * HD * S_ + c * 64;
#pragma unroll
  for (int i = 0; i < 2; i++) {
    int cid = tid + i * 256; int p = cid >> 3, sc = (cid & 7) * 8;
    bf16x8 xv = *(const bf16x8*)(Xt + xbase + (size_t)p * S_ + sc);
    f32x4 d0 = *(const f32x4*)(dt_c + abase + sc);
    f32x4 d1 = *(const f32x4*)(dt_c + abase + sc + 4);
    bf16x8 o;
#pragma unroll
    for (int j = 0; j < 4; j++) { o[j] = (bf16)((float)xv[j] * d0[j]); o[4 + j] = (bf16)((float)xv[4 + j] * d1[j]); }
    *(bf16x8*)(Xs + p * 72 + sc) = o;
  }
  __syncthreads();
  bf16x8 ca[4];
#pragma unroll
  for (int ks = 0; ks < 4; ks++) ca[ks] = *(const bf16x8*)(Cs + (w * 16 + fr) * 136 + ks * 32 + fq * 8);
  f32x4 cb[4] = {};
  for (int st = 0; st <= w; st++)
#pragma unroll
    for (int ks = 0; ks < 4; ks++)
      cb[st] = __builtin_amdgcn_mfma_f32_16x16x32_bf16(ca[ks],
                 *(const bf16x8*)(BNs + (st * 16 + fr) * 136 + ks * 32 + fq * 8), cb[st], 0, 0, 0);
#pragma unroll
  for (int st = 0; st < 4; st++) {
    float es = (st <= w) ? __expf(-acs[st * 16 + fr]) : 0.f;
#pragma unroll
    for (int r = 0; r < 4; r++) {
      int lloc = fq * 4 + r;
      float g = 0.f;
      if (st < w) g = cb[st][r] * es;
      else if (st == w) g = (lloc >= fr) ? cb[st][r] * es : 0.f;
      G[(w * 16 + lloc) * 72 + st * 16 + fr] = (bf16)g;
    }
  }
  f32x4 acc[4] = {};
  {
    bf16x8 ga0 = *(const bf16x8*)(G + (w * 16 + fr) * 72 + fq * 8);
    bf16x8 ga1 = *(const bf16x8*)(G + (w * 16 + fr) * 72 + 32 + fq * 8);
#pragma unroll
    for (int pt = 0; pt < 4; pt++) {
      acc[pt] = __builtin_amdgcn_mfma_f32_16x16x32_bf16(ga0,
                  *(const bf16x8*)(Xs + (pt * 16 + fr) * 72 + fq * 8), acc[pt], 0, 0, 0);
      acc[pt] = __builtin_amdgcn_mfma_f32_16x16x32_bf16(ga1,
                  *(const bf16x8*)(Xs + (pt * 16 + fr) * 72 + 32 + fq * 8), acc[pt], 0, 0, 0);
    }
  }
  __syncthreads();
  const bf16* stp = states + (size_t)bid * 8192;
#pragma unroll
  for (int i = 0; i < 4; i++) {
    int cid = tid + i * 256; int p = cid >> 4, nc = (cid & 15) * 8;
    *(bf16x8*)(BNs + p * 136 + nc) = *(const bf16x8*)(stp + (size_t)p * 128 + nc);
  }
  __syncthreads();
#pragma unroll
  for (int pt = 0; pt < 4; pt++)
#pragma unroll
    for (int ks = 0; ks < 4; ks++)
      acc[pt] = __builtin_amdgcn_mfma_f32_16x16x32_bf16(ca[ks],
                  *(const bf16x8*)(BNs + (pt * 16 + fr) * 136 + ks * 32 + fq * 8), acc[pt], 0, 0, 0);
  float dph = Dp[h];
#pragma unroll
  for (int pt = 0; pt < 4; pt++) {
    int p = pt * 16 + fr;
    size_t tb = (xbase + (size_t)p * S_) + w * 16 + fq * 4;
    bf16x4 xs4 = *(const bf16x4*)(Xt + tb);
    bf16x4 z4  = *(const bf16x4*)(Zt + tb);
#pragma unroll
    for (int r = 0; r < 4; r++) {
      int l = w * 16 + fq * 4 + r;
      float yv = acc[pt][r] + (float)xs4[r] * dph;
      float z = (float)z4[r];
      yv *= z / (1.f + __expf(-z));
      ybf[((row0 + l) * NH + h) * HD + p] = (bf16)yv;
    }
  }
}

// ---------------- split-S MFMA flash attention (fixed-max softmax -> partials sum) ----------------
// Single-buffered K/V (LDS 36.9 KB -> 4 blocks/CU); prefetch issued after the
// second barrier so loads overlap compute and drain at next iter's first barrier.
#define KSTR 72
#define PSTR 72
__global__ __launch_bounds__(256) void attn_mfma(const bf16* __restrict__ q,
                                                 const bf16* __restrict__ k,
                                                 const bf16* __restrict__ vtr,
                                                 bf16* __restrict__ Po,
                                                 float* __restrict__ Ls) {
  __shared__ bf16 Ks[64 * KSTR];
  __shared__ bf16 Vs[64 * KSTR];
  __shared__ bf16 Pl[4][32 * PSTR];
  int c = 39 - blockIdx.x;                 // full 8-iter chunks first
  int g = (c < 4) ? 0 : (c < 12) ? 1 : (c < 24) ? 2 : 3;
  int gbase = (g == 0) ? 0 : (g == 1) ? 4 : (g == 2) ? 12 : 24;
  int d = c - gbase;
  int qt = 4 * g + d / (g + 1);
  int sk = d % (g + 1);
  int h = blockIdx.y, b = blockIdx.z;
  int kvh = h >> 2;
  int tid = threadIdx.x, lane = tid & 63, w = tid >> 6;
  int fr = lane & 15, fq = lane >> 4;
  const float SC = 0.18033688011112042f;   // 0.125 * log2(e)
  const float M2 = 62.0f;
  int kt0 = sk * 8;
  int ktend = min(kt0 + 8, 2 * qt + 2);
  int qbase = qt * 128 + w * 32;           // wave's first q row
  int qmaxw = qbase + 31;
  bf16x8 bq[2][2];
#pragma unroll
  for (int qc = 0; qc < 2; qc++)
#pragma unroll
    for (int ks = 0; ks < 2; ks++)
      bq[qc][ks] = *(const bf16x8*)(q + (size_t)(b * S_ + qbase + qc * 16 + fr) * (HATT * HD)
                                      + h * HD + ks * 32 + fq * 8);
  int sr = tid >> 3, sc8 = (tid & 7) * 8;
  const bf16* kg = k + ((size_t)(b * S_) + sr) * (KVH * HD) + kvh * HD + sc8;
  const bf16* vg = vtr + ((size_t)(b * KVH + kvh) * HD + sr) * S_ + sc8;
  bf16x8 krg0, krg1, vrg0, vrg1;
  {
    const bf16* kp = kg + (size_t)kt0 * 64 * (KVH * HD);
    const bf16* vp = vg + (size_t)kt0 * 64;
    krg0 = *(const bf16x8*)(kp);
    krg1 = *(const bf16x8*)(kp + (size_t)32 * (KVH * HD));
    vrg0 = *(const bf16x8*)(vp);
    vrg1 = *(const bf16x8*)(vp + (size_t)32 * S_);
  }
  float lsum[2] = {0.f, 0.f};
  f32x4 yacc[2][4] = {};
  bf16* Plw = Pl[w];
  for (int kt = kt0; kt < ktend; kt++) {
    __syncthreads();   // previous iteration's LDS reads complete
    *(bf16x8*)(&Ks[sr * KSTR + sc8]) = krg0;
    *(bf16x8*)(&Ks[(sr + 32) * KSTR + sc8]) = krg1;
    *(bf16x8*)(&Vs[sr * KSTR + sc8]) = vrg0;
    *(bf16x8*)(&Vs[(sr + 32) * KSTR + sc8]) = vrg1;
    __syncthreads();   // tile visible
    // prefetch next tile AFTER the barrier: loads overlap compute below
    if ((kt + 1) < ktend) {
      const bf16* kp = kg + (size_t)(kt + 1) * 64 * (KVH * HD);
      const bf16* vp = vg + (size_t)(kt + 1) * 64;
      krg0 = *(const bf16x8*)(kp);
      krg1 = *(const bf16x8*)(kp + (size_t)32 * (KVH * HD));
      vrg0 = *(const bf16x8*)(vp);
      vrg1 = *(const bf16x8*)(vp + (size_t)32 * S_);
    }
    if (kt * 64 <= qmaxw) {
      bool nomask = (kt * 64 + 63) <= qbase;
      if (nomask) {
#pragma unroll
        for (int mi = 0; mi < 4; mi++) {
          const bf16* krow = &Ks[(mi * 16 + fr) * KSTR];
          bf16x8 ak0 = *(const bf16x8*)(krow + fq * 8);
          bf16x8 ak1 = *(const bf16x8*)(krow + 32 + fq * 8);
#pragma unroll
          for (int qc = 0; qc < 2; qc++) {
            f32x4 s = {};
            s = __builtin_amdgcn_mfma_f32_16x16x32_bf16(ak0, bq[qc][0], s, 0, 0, 0);
            s = __builtin_amdgcn_mfma_f32_16x16x32_bf16(ak1, bq[qc][1], s, 0, 0, 0);
            bf16x4 pk;
#pragma unroll
            for (int r = 0; r < 4; r++) {
              float p = __builtin_amdgcn_exp2f(s[r] * SC - M2);
              lsum[qc] += p;
              pk[r] = (bf16)p;
            }
            *(bf16x4*)(Plw + (qc * 16 + fr) * PSTR + mi * 16 + fq * 4) = pk;
          }
        }
      } else {
#pragma unroll
        for (int mi = 0; mi < 4; mi++) {
          int s0 = kt * 64 + mi * 16;
          if (s0 > qmaxw) {
            bf16x4 zz = {};
#pragma unroll
            for (int qc = 0; qc < 2; qc++)
              *(bf16x4*)(Plw + (qc * 16 + fr) * PSTR + mi * 16 + fq * 4) = zz;
          } else {
            const bf16* krow = &Ks[(mi * 16 + fr) * KSTR];
            bf16x8 ak0 = *(const bf16x8*)(krow + fq * 8);
            bf16x8 ak1 = *(const bf16x8*)(krow + 32 + fq * 8);
#pragma unroll
            for (int qc = 0; qc < 2; qc++) {
              f32x4 s = {};
              s = __builtin_amdgcn_mfma_f32_16x16x32_bf16(ak0, bq[qc][0], s, 0, 0, 0);
              s = __builtin_amdgcn_mfma_f32_16x16x32_bf16(ak1, bq[qc][1], s, 0, 0, 0);
              int qq = qbase + qc * 16 + fr;
              bf16x4 pk;
#pragma unroll
              for (int r = 0; r < 4; r++) {
                int sp = s0 + fq * 4 + r;
                float p = (sp <= qq) ? __builtin_amdgcn_exp2f(s[r] * SC - M2) : 0.f;
                lsum[qc] += p;
                pk[r] = (bf16)p;
              }
              *(bf16x4*)(Plw + (qc * 16 + fr) * PSTR + mi * 16 + fq * 4) = pk;
            }
          }
        }
      }
#pragma unroll
      for (int ks2 = 0; ks2 < 2; ks2++) {
        bf16x8 bp[2];
#pragma unroll
        for (int qc = 0; qc < 2; qc++)
          bp[qc] = *(const bf16x8*)(Plw + (qc * 16 + fr) * PSTR + ks2 * 32 + fq * 8);
#pragma unroll
        for (int pi = 0; pi < 4; pi++) {
          bf16x8 av = *(const bf16x8*)(&Vs[(pi * 16 + fr) * KSTR + ks2 * 32 + fq * 8]);
#pragma unroll
          for (int qc = 0; qc < 2; qc++)
            yacc[qc][pi] = __builtin_amdgcn_mfma_f32_16x16x32_bf16(av, bp[qc], yacc[qc][pi], 0, 0, 0);
        }
      }
    }
  }
#pragma unroll
  for (int qc = 0; qc < 2; qc++) {
    lsum[qc] += __shfl_xor(lsum[qc], 16, 64);
    lsum[qc] += __shfl_xor(lsum[qc], 32, 64);
    int qrow = qt * 128 + w * 32 + qc * 16 + fr;
    if (fq == 0)
      Ls[((size_t)(b * 16 + h) * 2048 + qrow) * 4 + sk] = lsum[qc];
    bf16* pop = Po + ((((size_t)(b * 16 + h) * 16 + qt) * 4 + sk) * 128
                       + w * 32 + qc * 16 + fr) * 64 + fq * 4;
#pragma unroll
    for (int pi = 0; pi < 4; pi++) {
      bf16x4 o;
#pragma unroll
      for (int r = 0; r < 4; r++) o[r] = (bf16)yacc[qc][pi][r];
      *(bf16x4*)(pop + pi * 16) = o;
    }
  }
}

// ---------------- attention partial combine + normalize -> y2 bf16 ----------------
__global__ __launch_bounds__(256) void attn_red(const bf16* __restrict__ Po,
                                                const float* __restrict__ Ls,
                                                bf16* __restrict__ y2) {
  int row = blockIdx.x;            // 0..4095
  int b = row >> 11;
  int qrow = row & 2047;
  int qt = qrow >> 7, r = qrow & 127;
  int nch = (qt >> 2) + 1;
  int t = threadIdx.x;
  int h = t >> 4, e4 = (t & 15) << 2;
  const float* lp = Ls + ((size_t)(b * 16 + h) * 2048 + qrow) * 4;
  float ls = 0.f;
  f32x4 acc = {};
  for (int sk = 0; sk < nch; sk++) {
    ls += lp[sk];
    const bf16* pp = Po + ((((size_t)(b * 16 + h) * 16 + qt) * 4 + sk) * 128 + r) * 64 + e4;
    bf16x4 v = *(const bf16x4*)(pp);
#pragma unroll
    for (int j = 0; j < 4; j++) acc[j] += (float)v[j];
  }
  float inv = 1.f / ls;
  bf16x4 o;
#pragma unroll
  for (int j = 0; j < 4; j++) o[j] = (bf16)(acc[j] * inv);
  *(bf16x4*)(y2 + (size_t)row * 1024 + h * 64 + e4) = o;
}

// ---------------- workspace layout (byte offsets) ----------------
constexpr size_t OFF_WIN  = 0;                   // bf16 4480x1024
constexpr size_t OFF_WOUT = 9175040;             // bf16 1024x2048
constexpr size_t OFF_WQKV = 13369344;            // bf16 1536x1024 (q|k|v rows)
constexpr size_t OFF_WCP  = 16515072;            // bf16 1024x1024
constexpr size_t OFF_WFC  = 18612224;            // bf16 3072x1024
constexpr size_t OFF_WPR  = 24903680;            // bf16 1024x3072
constexpr size_t OFF_HBF  = 31195136;            // bf16 4096x1024
constexpr size_t OFF_BCDT = 39583744;            // bf16 4096x288; reused: Ls f32 (1 MiB)
constexpr size_t OFF_XT   = 41943040;            // bf16 [b][h][p][sg] (16.7 MB)
constexpr size_t OFF_ZT   = 58720256;            // bf16 [b][h][p][sg] (16.7 MB)
constexpr size_t OFF_DTC  = 75497472;            // f32 [b][h][sg]
constexpr size_t OFF_DDC  = 76546048;            // f32
constexpr size_t OFF_ACC  = 77594624;            // f32
constexpr size_t OFF_T    = 78643200;            // f32 2048
constexpr size_t OFF_BN   = 78651392;            // bf16 4096x128
constexpr size_t OFF_CN   = 79699968;            // bf16 4096x128
constexpr size_t OFF_BTR  = 80748544;            // bf16 [b][n][sg]
constexpr size_t OFF_ST   = 81797120;            // bf16 states (33.5 MB); reused: Po bf16 32 MiB
constexpr size_t OFF_YBF  = 148905984;           // bf16 4096x2048
constexpr size_t OFF_X1   = 165683200;           // f32 4096x1024 (end 182,460,416)
// phase-2 aliases
constexpr size_t OFF_P    = OFF_ST;              // bf16 split-K partials (<= 25.2 MB)
constexpr size_t OFF_PO   = OFF_ST;              // bf16 attn partials [b][h][qt][4][128][64] = 32 MiB
constexpr size_t OFF_LS   = OFF_BCDT;            // f32 attn lsums [b][h][2048][4] = 1 MiB
constexpr size_t OFF_QB   = OFF_XT;              // bf16 4096x1024 (8.4 MB)
constexpr size_t OFF_KB   = OFF_XT + 8388608;    // bf16 4096x256
constexpr size_t OFF_VB   = OFF_XT + 10485760;   // bf16 4096x256
constexpr size_t OFF_VTR  = OFF_XT + 12582912;   // bf16 [b][kvh][p][sg]
constexpr size_t OFF_Y2   = OFF_ZT;              // bf16 4096x1024
constexpr size_t OFF_X2   = 50331648;            // f32 4096x1024 (over dead kb/vb/vtr/y2)
constexpr size_t OFF_MLP  = 132128768;           // bf16 4096x3072 (over dead regions)

extern "C" void kernel_launch(void* const* d_in, const int* in_sizes, int n_in,
                              void* d_out, int out_size, void* d_ws, size_t ws_size,
                              hipStream_t stream) {
  (void)in_sizes; (void)n_in; (void)out_size; (void)ws_size;
  const float* x        = (const float*)d_in[0];
  const float* mnorm_w  = (const float*)d_in[1];
  const float* in_w     = (const float*)d_in[2];
  const float* out_w    = (const float*)d_in[3];
  const float* Dp       = (const float*)d_in[4];
  const float* dt_bias  = (const float*)d_in[5];
  const float* A_log    = (const float*)d_in[6];
  const float* Bn_w     = (const float*)d_in[7];
  const float* Cn_w     = (const float*)d_in[8];
  const float* ln1_w    = (const float*)d_in[9];
  const float* ln1_b    = (const float*)d_in[10];
  const float* cq_w     = (const float*)d_in[11];
  const float* ck_w     = (const float*)d_in[12];
  const float* cv_w     = (const float*)d_in[13];
  const float* cproj_w  = (const float*)d_in[14];
  const float* q_gain   = (const float*)d_in[15];
  const float* ln2_w    = (const float*)d_in[16];
  const float* ln2_b    = (const float*)d_in[17];
  const float* fc_w     = (const float*)d_in[18];
  const float* proj_w   = (const float*)d_in[19];
  float* out = (float*)d_out;
  char* W8 = (char*)d_ws;

  bf16* w_in   = (bf16*)(W8 + OFF_WIN);
  bf16* w_out  = (bf16*)(W8 + OFF_WOUT);
  bf16* w_qkv  = (bf16*)(W8 + OFF_WQKV);
  bf16* w_cp   = (bf16*)(W8 + OFF_WCP);
  bf16* w_fc   = (bf16*)(W8 + OFF_WFC);
  bf16* w_pr   = (bf16*)(W8 + OFF_WPR);
  bf16* h_bf   = (bf16*)(W8 + OFF_HBF);
  bf16* bcdt   = (bf16*)(W8 + OFF_BCDT);
  bf16* Xt     = (bf16*)(W8 + OFF_XT);
  bf16* Zt     = (bf16*)(W8 + OFF_ZT);
  float* dt_c  = (float*)(W8 + OFF_DTC);
  float* ddc   = (float*)(W8 + OFF_DDC);
  float* ac_c  = (float*)(W8 + OFF_ACC);
  float* Tb    = (float*)(W8 + OFF_T);
  bf16* Bn     = (bf16*)(W8 + OFF_BN);
  bf16* Cn     = (bf16*)(W8 + OFF_CN);
  bf16* Btr    = (bf16*)(W8 + OFF_BTR);
  bf16* st     = (bf16*)(W8 + OFF_ST);
  bf16* ybf    = (bf16*)(W8 + OFF_YBF);
  float* x1    = (float*)(W8 + OFF_X1);
  bf16* Pbuf   = (bf16*)(W8 + OFF_P);
  bf16* Po     = (bf16*)(W8 + OFF_PO);
  float* Ls    = (float*)(W8 + OFF_LS);
  bf16* qbf    = (bf16*)(W8 + OFF_QB);
  bf16* kbf    = (bf16*)(W8 + OFF_KB);
  bf16* vbf    = (bf16*)(W8 + OFF_VB);
  bf16* vtr    = (bf16*)(W8 + OFF_VTR);
  bf16* y2     = (bf16*)(W8 + OFF_Y2);
  float* x2    = (float*)(W8 + OFF_X2);
  bf16* mlp    = (bf16*)(W8 + OFF_MLP);

  // ---- weight casts (single launch; q/k/v cast into adjacent rows of w_qkv) ----
  CastArgs ca;
  ca.seg[0] = { in_w,    w_in,            4489216, 4587520, 0     };
  ca.seg[1] = { out_w,   w_out,           2097152, 2097152, 4480  };
  ca.seg[2] = { cq_w,    w_qkv,           1048576, 1048576, 6528  };
  ca.seg[3] = { ck_w,    w_qkv + 1048576,  262144,  262144, 7552  };
  ca.seg[4] = { cv_w,    w_qkv + 1310720,  262144,  262144, 7808  };
  ca.seg[5] = { cproj_w, w_cp,            1048576, 1048576, 8064  };
  ca.seg[6] = { fc_w,    w_fc,            3145728, 3145728, 9088  };
  ca.seg[7] = { proj_w,  w_pr,            3145728, 3145728, 12160 };
  castw_all<<<15232, 256, 0, stream>>>(ca);

  const size_t PS  = (size_t)ROWS * 1024;   // partial stride (elements) for N=1024 GEMMs

  // ---- mamba block ----
  rmsnorm_k<<<ROWS, 256, 0, stream>>>(x, mnorm_w, h_bf, D_);
  gemm_inproj<<<32 * 35, 256, 0, stream>>>(h_bf, w_in, Zt, Xt, bcdt);
  ssd_prep<<<B_ * NH * NC, 64, 0, stream>>>(bcdt, dt_bias, A_log, dt_c, ddc, ac_c, Tb);
  bc_norm<<<ROWS, 128, 0, stream>>>(bcdt, Bn_w, Cn_w, Bn, Cn);
  t64<<<2 * 2 * 32, 256, 0, stream>>>(Bn, Btr, 128, (size_t)2048 * 128, (size_t)128 * 2048, 2);
  ssd_states<<<B_ * NC * NH, 256, 0, stream>>>(Xt, Btr, ddc, st);
  ssd_scan<<<B_ * NH * 8, 256, 0, stream>>>(st, Tb);
  ssd_out<<<B_ * NC * NH, 256, 0, stream>>>(Cn, Bn, Xt, Zt, dt_c, ac_c, st, Dp, ybf);
  // out_proj: split-K=2 then fused reduce+residual+LN1
  gemm_sk<<<dim3(32 * 8, 1, 2), 256, 0, stream>>>(ybf, w_out, Pbuf, ROWS, D_, DI, 1024);
  reduce_ln2<<<ROWS, 256, 0, stream>>>(Pbuf, Pbuf + PS, x, ln1_w, ln1_b, x1, h_bf);

  // ---- attention block ----
  gemm_sk<<<dim3(32 * 12, 1, 2), 256, 0, stream>>>(h_bf, w_qkv, Pbuf, ROWS, 1536, D_, 512);
  reduce_qkv<<<ROWS, 256, 0, stream>>>(Pbuf, q_gain, qbf, kbf, vbf);
  t64<<<2 * 4 * 32, 256, 0, stream>>>(vbf, vtr, 256, (size_t)2048 * 256, (size_t)256 * 2048, 4);
  attn_mfma<<<dim3(40, HATT, B_), 256, 0, stream>>>(qbf, kbf, vtr, Po, Ls);
  attn_red<<<ROWS, 256, 0, stream>>>(Po, Ls, y2);
  gemm_sk<<<dim3(32 * 8, 1, 2), 256, 0, stream>>>(y2, w_cp, Pbuf, ROWS, D_, D_, 512);
  reduce_ln2<<<ROWS, 256, 0, stream>>>(Pbuf, Pbuf + PS, x1, ln2_w, ln2_b, x2, h_bf);

  // ---- MLP ----
  gemm_mfma<1, bf16><<<32 * 24, 256, 0, stream>>>(h_bf, w_fc, nullptr, mlp, ROWS, MLP, D_);
  gemm_sk<<<dim3(32 * 8, 1, 3), 256, 0, stream>>>(mlp, w_pr, Pbuf, ROWS, D_, MLP, 1024);
  reduce_out3<<<ROWS, 256, 0, stream>>>(Pbuf, Pbuf + PS, Pbuf + 2 * PS, x2, out);
}